// Round 2
// baseline (1209.235 us; speedup 1.0000x reference)
//
#include <hip/hip_runtime.h>
#include <cstdint>
#include <cstddef>

#define NEG_SLOPE 0.2f

// ---------------------------------------------------------------- sentinel
__global__ void sentinel_kernel(float* __restrict__ out, int n) {
    int i = blockIdx.x * blockDim.x + threadIdx.x;
    if (i < n) out[i] = 12345.0f;
}

// ---------------------------------------------------------------- CSR build
__global__ void count_deg_kernel(const int* __restrict__ dst, int* __restrict__ deg, int ne) {
    int e = blockIdx.x * blockDim.x + threadIdx.x;
    if (e < ne) atomicAdd(&deg[dst[e]], 1);
}

__global__ void scan_kernel(const int* __restrict__ deg, int* __restrict__ off, int n) {
    __shared__ int wsum[16];
    __shared__ int carry_s;
    const int tid = threadIdx.x, lane = tid & 63, wid = tid >> 6;
    if (tid == 0) carry_s = 0;
    __syncthreads();
    for (int base = 0; base < n; base += 1024) {
        int i = base + tid;
        int v = (i < n) ? deg[i] : 0;
        int incl = v;
        #pragma unroll
        for (int o = 1; o < 64; o <<= 1) {
            int t = __shfl_up(incl, o);
            if (lane >= o) incl += t;
        }
        if (lane == 63) wsum[wid] = incl;
        __syncthreads();
        if (tid < 16) {
            int wv = wsum[tid];
            int winc = wv;
            #pragma unroll
            for (int o = 1; o < 16; o <<= 1) {
                int t = __shfl_up(winc, o);
                if (tid >= o) winc += t;
            }
            wsum[tid] = winc - wv;   // exclusive wave prefix
        }
        __syncthreads();
        int carry = carry_s;
        int excl = carry + wsum[wid] + incl - v;
        if (i < n) off[i] = excl;
        __syncthreads();
        if (tid == 1023) carry_s = excl + v;   // running inclusive total
        __syncthreads();
    }
    if (threadIdx.x == 0) off[n] = carry_s;
}

__global__ void scatter_kernel(const int* __restrict__ src, const int* __restrict__ dst,
                               const int* __restrict__ off, int* __restrict__ cursor,
                               int* __restrict__ csr, int ne) {
    int e = blockIdx.x * blockDim.x + threadIdx.x;
    if (e < ne) {
        int d = dst[e];
        int p = off[d] + atomicAdd(&cursor[d], 1);
        csr[p] = src[e];
    }
}

// ------------------------------------------------------- weight concat pack
__global__ void pack_w_kernel(const float* __restrict__ Wl, const float* __restrict__ Wr,
                              float* __restrict__ Wc, int COUT, int CIN) {
    int i = blockIdx.x * blockDim.x + threadIdx.x;
    int tot = COUT * 2 * CIN;
    if (i >= tot) return;
    int o = i / (2 * CIN), k = i % (2 * CIN);
    Wc[i] = (k < CIN) ? Wl[o * CIN + k] : Wr[o * CIN + (k - CIN)];
}

// ------------------------------------------------------- mean aggregation
// one wave per node; lanes = channels; mean[n] = mean over in-neighbors of h
template<int CIN>
__global__ void agg_kernel(const float* __restrict__ h, const int* __restrict__ off,
                           const int* __restrict__ csr, float* __restrict__ mean, int n_nodes) {
    int wave = blockIdx.x * (blockDim.x >> 6) + (threadIdx.x >> 6);
    int lane = threadIdx.x & 63;
    if (wave >= n_nodes) return;
    constexpr int R = (CIN + 63) / 64;
    float acc[R];
    #pragma unroll
    for (int r = 0; r < R; ++r) acc[r] = 0.f;
    int e0 = off[wave], e1 = off[wave + 1];
    for (int e = e0; e < e1; ++e) {
        int s = csr[e];
        const float* hp = h + (size_t)s * CIN;
        #pragma unroll
        for (int r = 0; r < R; ++r) {
            int c = lane + 64 * r;
            if (c < CIN) acc[r] += hp[c];
        }
    }
    float inv = (e1 > e0) ? 1.f / (float)(e1 - e0) : 0.f;
    float* mp = mean + (size_t)wave * CIN;
    #pragma unroll
    for (int r = 0; r < R; ++r) {
        int c = lane + 64 * r;
        if (c < CIN) mp[c] = acc[r] * inv;
    }
}

// ------------------------------------------------------------ cat-GEMM
// C[M][N] = act(cat(AL,AR)[M][K] @ W[N][K]^T + bias)
// AL/AR each row-major [M][CIN], K = 2*CIN (or AR=null, CIN=K, plain GEMM)
#define BM 128
#define BN 64
#define BK 16

template<bool RELU>
__global__ __launch_bounds__(256) void gemm_cat_kernel(
        const float* __restrict__ AL, const float* __restrict__ AR,
        const float* __restrict__ W, const float* __restrict__ bias,
        float* __restrict__ C, int M, int N, int K, int CIN) {
    __shared__ float As[BK][BM + 4];
    __shared__ float Bs[BK][BN + 4];
    const int row0 = blockIdx.x * BM;
    const int col0 = blockIdx.y * BN;
    const int tid = threadIdx.x;
    const int ttm = tid & 15, ttn = tid >> 4;

    float acc[8][4];
    #pragma unroll
    for (int i = 0; i < 8; ++i)
        #pragma unroll
        for (int j = 0; j < 4; ++j) acc[i][j] = 0.f;

    for (int k0 = 0; k0 < K; k0 += BK) {
        for (int i = tid; i < BM * BK; i += 256) {
            int m = i >> 4, k = i & 15;
            int r = row0 + m, kk = k0 + k;
            float v = 0.f;
            if (r < M && kk < K)
                v = (kk < CIN) ? AL[(size_t)r * CIN + kk]
                               : AR[(size_t)r * CIN + (kk - CIN)];
            As[k][m] = v;
        }
        for (int i = tid; i < BN * BK; i += 256) {
            int n = i >> 4, k = i & 15;
            int c = col0 + n, kk = k0 + k;
            Bs[k][n] = (c < N && kk < K) ? W[(size_t)c * K + kk] : 0.f;
        }
        __syncthreads();
        #pragma unroll
        for (int k = 0; k < BK; ++k) {
            float4 a0 = *(const float4*)&As[k][ttm * 8];
            float4 a1 = *(const float4*)&As[k][ttm * 8 + 4];
            float4 b0 = *(const float4*)&Bs[k][ttn * 4];
            float av[8] = {a0.x, a0.y, a0.z, a0.w, a1.x, a1.y, a1.z, a1.w};
            float bv[4] = {b0.x, b0.y, b0.z, b0.w};
            #pragma unroll
            for (int i = 0; i < 8; ++i)
                #pragma unroll
                for (int j = 0; j < 4; ++j)
                    acc[i][j] += av[i] * bv[j];
        }
        __syncthreads();
    }

    float bv[4];
    #pragma unroll
    for (int j = 0; j < 4; ++j) bv[j] = bias[col0 + ttn * 4 + j];
    #pragma unroll
    for (int i = 0; i < 8; ++i) {
        int r = row0 + ttm * 8 + i;
        if (r < M) {
            float t0 = acc[i][0] + bv[0];
            float t1 = acc[i][1] + bv[1];
            float t2 = acc[i][2] + bv[2];
            float t3 = acc[i][3] + bv[3];
            if (RELU) {
                t0 = t0 > 0.f ? t0 : t0 * NEG_SLOPE;
                t1 = t1 > 0.f ? t1 : t1 * NEG_SLOPE;
                t2 = t2 > 0.f ? t2 : t2 * NEG_SLOPE;
                t3 = t3 > 0.f ? t3 : t3 * NEG_SLOPE;
            }
            float4 v; v.x = t0; v.y = t1; v.z = t2; v.w = t3;
            *(float4*)&C[(size_t)r * N + col0 + ttn * 4] = v;
        }
    }
}

// ---------------------------------------- fused layer-3 GEMM + mean/max pool
// one block per (graph, 64-col tile); rows = the graph's npg(=50) nodes.
// gout[g][0:256] = mean over nodes, gout[g][256:512] = max over nodes.
__global__ __launch_bounds__(256) void gemm_pool_kernel(
        const float* __restrict__ AL, const float* __restrict__ AR,
        const float* __restrict__ W, const float* __restrict__ bias,
        float* __restrict__ gout, int npg, int CIN, int NCH) {
    __shared__ float As[BK][64 + 4];
    __shared__ float Bs[BK][64 + 4];
    __shared__ float redS[16][64 + 4];
    __shared__ float redM[16][64 + 4];
    const int g = blockIdx.x;
    const int col0 = blockIdx.y * 64;
    const int K = 2 * CIN;
    const int tid = threadIdx.x;
    const int ttm = tid & 15, ttn = tid >> 4;
    const size_t rowbase = (size_t)g * npg;

    float acc[4][4];
    #pragma unroll
    for (int i = 0; i < 4; ++i)
        #pragma unroll
        for (int j = 0; j < 4; ++j) acc[i][j] = 0.f;

    for (int k0 = 0; k0 < K; k0 += BK) {
        for (int i = tid; i < 64 * BK; i += 256) {
            int m = i >> 4, k = i & 15;
            int kk = k0 + k;
            float v = 0.f;
            if (m < npg) {
                size_t r = rowbase + m;
                v = (kk < CIN) ? AL[r * CIN + kk] : AR[r * CIN + (kk - CIN)];
            }
            As[k][m] = v;
        }
        for (int i = tid; i < 64 * BK; i += 256) {
            int n = i >> 4, k = i & 15;
            Bs[k][n] = W[(size_t)(col0 + n) * K + k0 + k];
        }
        __syncthreads();
        #pragma unroll
        for (int k = 0; k < BK; ++k) {
            float4 a0 = *(const float4*)&As[k][ttm * 4];
            float4 b0 = *(const float4*)&Bs[k][ttn * 4];
            float av[4] = {a0.x, a0.y, a0.z, a0.w};
            float bv[4] = {b0.x, b0.y, b0.z, b0.w};
            #pragma unroll
            for (int i = 0; i < 4; ++i)
                #pragma unroll
                for (int j = 0; j < 4; ++j)
                    acc[i][j] += av[i] * bv[j];
        }
        __syncthreads();
    }

    // bias + lrelu + per-thread partial mean/max over its (<=4) valid rows
    float lsum[4], lmax[4];
    #pragma unroll
    for (int j = 0; j < 4; ++j) { lsum[j] = 0.f; lmax[j] = -__builtin_huge_valf(); }
    #pragma unroll
    for (int i = 0; i < 4; ++i) {
        int m = ttm * 4 + i;
        if (m < npg) {
            #pragma unroll
            for (int j = 0; j < 4; ++j) {
                float t = acc[i][j] + bias[col0 + ttn * 4 + j];
                t = t > 0.f ? t : t * NEG_SLOPE;
                lsum[j] += t;
                lmax[j] = fmaxf(lmax[j], t);
            }
        }
    }
    #pragma unroll
    for (int j = 0; j < 4; ++j) {
        redS[ttm][ttn * 4 + j] = lsum[j];
        redM[ttm][ttn * 4 + j] = lmax[j];
    }
    __syncthreads();
    #pragma unroll
    for (int s = 8; s > 0; s >>= 1) {
        if (ttm < s) {
            #pragma unroll
            for (int j = 0; j < 4; ++j) {
                int c = ttn * 4 + j;
                redS[ttm][c] += redS[ttm + s][c];
                redM[ttm][c] = fmaxf(redM[ttm][c], redM[ttm + s][c]);
            }
        }
        __syncthreads();
    }
    if (ttm == 0) {
        float invn = 1.f / (float)npg;
        #pragma unroll
        for (int j = 0; j < 4; ++j) {
            int c = ttn * 4 + j;
            gout[(size_t)g * (2 * NCH) + col0 + c] = redS[0][c] * invn;
            gout[(size_t)g * (2 * NCH) + NCH + col0 + c] = redM[0][c];
        }
    }
}

// ------------------------------------------------------- final 64->1 layer
__global__ void final_kernel(const float* __restrict__ c2, const float* __restrict__ Wc3,
                             const float* __restrict__ bc3, float* __restrict__ out, int G) {
    int g = blockIdx.x * (blockDim.x >> 6) + (threadIdx.x >> 6);
    int lane = threadIdx.x & 63;
    if (g >= G) return;
    float v = c2[(size_t)g * 64 + lane] * Wc3[lane];
    #pragma unroll
    for (int o = 32; o > 0; o >>= 1) v += __shfl_down(v, o);
    if (lane == 0) out[g] = v + bc3[0];
}

// ---------------------------------------------------------------- launcher
extern "C" void kernel_launch(void* const* d_in, const int* in_sizes, int n_in,
                              void* d_out, int out_size, void* d_ws, size_t ws_size,
                              hipStream_t stream) {
    const float* x   = (const float*)d_in[0];
    const int* ei    = (const int*)d_in[1];
    const float* W1l = (const float*)d_in[4];
    const float* b1  = (const float*)d_in[5];
    const float* W1r = (const float*)d_in[6];
    const float* W2l = (const float*)d_in[7];
    const float* b2  = (const float*)d_in[8];
    const float* W2r = (const float*)d_in[9];
    const float* W3l = (const float*)d_in[10];
    const float* b3  = (const float*)d_in[11];
    const float* W3r = (const float*)d_in[12];
    const float* Wc1 = (const float*)d_in[13];
    const float* bc1 = (const float*)d_in[14];
    const float* Wc2 = (const float*)d_in[15];
    const float* bc2 = (const float*)d_in[16];
    const float* Wc3 = (const float*)d_in[17];
    const float* bc3 = (const float*)d_in[18];
    float* out = (float*)d_out;

    const int nodes = in_sizes[0] / 5;      // 100000
    const int ne    = in_sizes[1] / 2;      // 1600000
    const int G     = out_size;             // 2000
    const int npg   = nodes / G;            // 50

    // ---- workspace layout (256B aligned), peak ~118 MB
    char* ws = (char*)d_ws;
    size_t pos = 0;
    auto take = [&](size_t bytes) -> char* {
        char* p = ws + pos;
        pos += (bytes + 255) & ~(size_t)255;
        return p;
    };
    int* deg     = (int*)take((size_t)nodes * 4);
    int* cursor  = (int*)take((size_t)nodes * 4);
    int* off     = (int*)take((size_t)(nodes + 1) * 4);
    int* csr     = (int*)take((size_t)ne * 4);
    float* Wcat1 = (float*)take((size_t)64 * 10 * 4);
    float* Wcat2 = (float*)take((size_t)128 * 128 * 4);
    float* Wcat3 = (float*)take((size_t)256 * 256 * 4);
    float* gbuf  = (float*)take((size_t)G * 512 * 4);
    float* c1    = (float*)take((size_t)G * 128 * 4);
    float* c2    = (float*)take((size_t)G * 64 * 4);
    // contiguous region reused: [meanx | mean1 | h1] (53.2MB) -> later mean2 (51.2MB)
    float* meanx = (float*)take((size_t)nodes * 5 * 4);
    float* mean1 = (float*)take((size_t)nodes * 64 * 4);
    float* h1    = (float*)take((size_t)nodes * 64 * 4);
    float* h2    = (float*)take((size_t)nodes * 128 * 4);
    float* mean2 = meanx;   // aliases dead meanx/mean1/h1 after L2 GEMM

    if (pos > ws_size) {   // workspace too small: emit sentinel instead of crashing
        sentinel_kernel<<<(G + 255) / 256, 256, 0, stream>>>(out, G);
        return;
    }

    const int* src = ei;
    const int* dst = ei + ne;

    hipMemsetAsync(deg, 0, (size_t)nodes * 4, stream);
    hipMemsetAsync(cursor, 0, (size_t)nodes * 4, stream);

    int eb = (ne + 255) / 256;
    count_deg_kernel<<<eb, 256, 0, stream>>>(dst, deg, ne);
    scan_kernel<<<1, 1024, 0, stream>>>(deg, off, nodes);
    scatter_kernel<<<eb, 256, 0, stream>>>(src, dst, off, cursor, csr, ne);

    pack_w_kernel<<<(64 * 10 + 255) / 256, 256, 0, stream>>>(W1l, W1r, Wcat1, 64, 5);
    pack_w_kernel<<<(128 * 128 + 255) / 256, 256, 0, stream>>>(W2l, W2r, Wcat2, 128, 64);
    pack_w_kernel<<<(256 * 256 + 255) / 256, 256, 0, stream>>>(W3l, W3r, Wcat3, 256, 128);

    int ab = (nodes + 3) / 4;   // one node per wave, 4 waves/block

    // ---- layer 1: [mean(x)|x] (K=10) -> 64
    agg_kernel<5><<<ab, 256, 0, stream>>>(x, off, csr, meanx, nodes);
    {
        dim3 g((nodes + BM - 1) / BM, 64 / BN);
        gemm_cat_kernel<true><<<g, 256, 0, stream>>>(meanx, x, Wcat1, b1, h1, nodes, 64, 10, 5);
    }
    // ---- layer 2: [mean(h1)|h1] (K=128) -> 128
    agg_kernel<64><<<ab, 256, 0, stream>>>(h1, off, csr, mean1, nodes);
    {
        dim3 g((nodes + BM - 1) / BM, 128 / BN);
        gemm_cat_kernel<true><<<g, 256, 0, stream>>>(mean1, h1, Wcat2, b2, h2, nodes, 128, 128, 64);
    }
    // ---- layer 3: [mean(h2)|h2] (K=256) -> 256, fused with mean/max pool
    agg_kernel<128><<<ab, 256, 0, stream>>>(h2, off, csr, mean2, nodes);
    {
        dim3 g(G, 256 / 64);
        gemm_pool_kernel<<<g, 256, 0, stream>>>(mean2, h2, Wcat3, b3, gbuf, npg, 128, 256);
    }
    // ---- classifier: 512 -> 128 -> 64 -> 1
    {
        dim3 g((G + BM - 1) / BM, 128 / BN);
        gemm_cat_kernel<true><<<g, 256, 0, stream>>>(gbuf, nullptr, Wc1, bc1, c1, G, 128, 512, 512);
    }
    {
        dim3 g((G + BM - 1) / BM, 64 / BN);
        gemm_cat_kernel<true><<<g, 256, 0, stream>>>(c1, nullptr, Wc2, bc2, c2, G, 64, 128, 128);
    }
    final_kernel<<<(G + 3) / 4, 256, 0, stream>>>(c2, Wc3, bc3, out, G);
}

// Round 3
// 922.061 us; speedup vs baseline: 1.3114x; 1.3114x over previous
//
#include <hip/hip_runtime.h>
#include <cstdint>
#include <cstddef>

#define NEG_SLOPE 0.2f

// ---------------------------------------------------------------- sentinel
__global__ void sentinel_kernel(float* __restrict__ out, int n) {
    int i = blockIdx.x * blockDim.x + threadIdx.x;
    if (i < n) out[i] = 12345.0f;
}

// ---------------------------------------------------------------- CSR build
__global__ void count_deg_kernel(const int* __restrict__ dst, int* __restrict__ deg, int ne) {
    int e = blockIdx.x * blockDim.x + threadIdx.x;
    if (e < ne) atomicAdd(&deg[dst[e]], 1);
}

__global__ void scan_kernel(const int* __restrict__ deg, int* __restrict__ off, int n) {
    __shared__ int wsum[16];
    __shared__ int carry_s;
    const int tid = threadIdx.x, lane = tid & 63, wid = tid >> 6;
    if (tid == 0) carry_s = 0;
    __syncthreads();
    for (int base = 0; base < n; base += 1024) {
        int i = base + tid;
        int v = (i < n) ? deg[i] : 0;
        int incl = v;
        #pragma unroll
        for (int o = 1; o < 64; o <<= 1) {
            int t = __shfl_up(incl, o);
            if (lane >= o) incl += t;
        }
        if (lane == 63) wsum[wid] = incl;
        __syncthreads();
        if (tid < 16) {
            int wv = wsum[tid];
            int winc = wv;
            #pragma unroll
            for (int o = 1; o < 16; o <<= 1) {
                int t = __shfl_up(winc, o);
                if (tid >= o) winc += t;
            }
            wsum[tid] = winc - wv;   // exclusive wave prefix
        }
        __syncthreads();
        int carry = carry_s;
        int excl = carry + wsum[wid] + incl - v;
        if (i < n) off[i] = excl;
        __syncthreads();
        if (tid == 1023) carry_s = excl + v;   // running inclusive total
        __syncthreads();
    }
    if (threadIdx.x == 0) off[n] = carry_s;
}

__global__ void scatter_kernel(const int* __restrict__ src, const int* __restrict__ dst,
                               const int* __restrict__ off, int* __restrict__ cursor,
                               int* __restrict__ csr, int ne) {
    int e = blockIdx.x * blockDim.x + threadIdx.x;
    if (e < ne) {
        int d = dst[e];
        int p = off[d] + atomicAdd(&cursor[d], 1);
        csr[p] = src[e];
    }
}

// ------------------------------------------------------- weight packs
// old layout: Wc[n][k] (cat along k)
__global__ void pack_w_kernel(const float* __restrict__ Wl, const float* __restrict__ Wr,
                              float* __restrict__ Wc, int COUT, int CIN) {
    int i = blockIdx.x * blockDim.x + threadIdx.x;
    int tot = COUT * 2 * CIN;
    if (i >= tot) return;
    int o = i / (2 * CIN), k = i % (2 * CIN);
    Wc[i] = (k < CIN) ? Wl[o * CIN + k] : Wr[o * CIN + (k - CIN)];
}

// transposed: Wt[k][n], K = 2*CIN
__global__ void pack_wt_kernel(const float* __restrict__ Wl, const float* __restrict__ Wr,
                               float* __restrict__ Wt, int COUT, int CIN) {
    int i = blockIdx.x * blockDim.x + threadIdx.x;
    int K = 2 * CIN;
    if (i >= K * COUT) return;
    int k = i / COUT, n = i % COUT;
    Wt[i] = (k < CIN) ? Wl[n * CIN + k] : Wr[n * CIN + (k - CIN)];
}

// ------------------------------------------------------- mean aggregation
// scalar path (CIN=5)
template<int CIN>
__global__ void agg_kernel(const float* __restrict__ h, const int* __restrict__ off,
                           const int* __restrict__ csr, float* __restrict__ mean, int n_nodes) {
    int wave = blockIdx.x * (blockDim.x >> 6) + (threadIdx.x >> 6);
    int lane = threadIdx.x & 63;
    if (wave >= n_nodes) return;
    constexpr int R = (CIN + 63) / 64;
    float acc[R];
    #pragma unroll
    for (int r = 0; r < R; ++r) acc[r] = 0.f;
    int e0 = off[wave], e1 = off[wave + 1];
    for (int e = e0; e < e1; ++e) {
        int s = csr[e];
        const float* hp = h + (size_t)s * CIN;
        #pragma unroll
        for (int r = 0; r < R; ++r) {
            int c = lane + 64 * r;
            if (c < CIN) acc[r] += hp[c];
        }
    }
    float inv = (e1 > e0) ? 1.f / (float)(e1 - e0) : 0.f;
    float* mp = mean + (size_t)wave * CIN;
    #pragma unroll
    for (int r = 0; r < R; ++r) {
        int c = lane + 64 * r;
        if (c < CIN) mp[c] = acc[r] * inv;
    }
}

// vectorized path (CIN = 64 or 128): float4 per lane, multiple edges per wave-iter
template<int CIN>
__global__ void agg_vec_kernel(const float* __restrict__ h, const int* __restrict__ off,
                               const int* __restrict__ csr, float* __restrict__ mean,
                               int n_nodes) {
    constexpr int LPR = CIN / 4;        // lanes per row (16 or 32)
    constexpr int SLOTS = 64 / LPR;     // concurrent edges (4 or 2)
    int wave = blockIdx.x * (blockDim.x >> 6) + (threadIdx.x >> 6);
    int lane = threadIdx.x & 63;
    if (wave >= n_nodes) return;
    int slot = lane / LPR, cg = lane % LPR;
    int e0 = off[wave], cnt = off[wave + 1] - e0;
    float4 acc = {0.f, 0.f, 0.f, 0.f};
    for (int i = slot; i < cnt; i += SLOTS) {
        int s = csr[e0 + i];
        float4 v = *(const float4*)(h + (size_t)s * CIN + cg * 4);
        acc.x += v.x; acc.y += v.y; acc.z += v.z; acc.w += v.w;
    }
    #pragma unroll
    for (int o = LPR; o < 64; o <<= 1) {
        acc.x += __shfl_xor(acc.x, o);
        acc.y += __shfl_xor(acc.y, o);
        acc.z += __shfl_xor(acc.z, o);
        acc.w += __shfl_xor(acc.w, o);
    }
    if (slot == 0) {
        float inv = (cnt > 0) ? 1.f / (float)cnt : 0.f;
        float4 r = {acc.x * inv, acc.y * inv, acc.z * inv, acc.w * inv};
        *(float4*)(mean + (size_t)wave * CIN + cg * 4) = r;
    }
}

// ------------------------------------------------------------ cat-GEMM (old, small cases)
#define BM 128
#define BN 64
#define BK 16

template<bool RELU>
__global__ __launch_bounds__(256) void gemm_cat_kernel(
        const float* __restrict__ AL, const float* __restrict__ AR,
        const float* __restrict__ W, const float* __restrict__ bias,
        float* __restrict__ C, int M, int N, int K, int CIN) {
    __shared__ float As[BK][BM + 4];
    __shared__ float Bs[BK][BN + 4];
    const int row0 = blockIdx.x * BM;
    const int col0 = blockIdx.y * BN;
    const int tid = threadIdx.x;
    const int ttm = tid & 15, ttn = tid >> 4;

    float acc[8][4];
    #pragma unroll
    for (int i = 0; i < 8; ++i)
        #pragma unroll
        for (int j = 0; j < 4; ++j) acc[i][j] = 0.f;

    for (int k0 = 0; k0 < K; k0 += BK) {
        for (int i = tid; i < BM * BK; i += 256) {
            int m = i >> 4, k = i & 15;
            int r = row0 + m, kk = k0 + k;
            float v = 0.f;
            if (r < M && kk < K)
                v = (kk < CIN) ? AL[(size_t)r * CIN + kk]
                               : AR[(size_t)r * CIN + (kk - CIN)];
            As[k][m] = v;
        }
        for (int i = tid; i < BN * BK; i += 256) {
            int n = i >> 4, k = i & 15;
            int c = col0 + n, kk = k0 + k;
            Bs[k][n] = (c < N && kk < K) ? W[(size_t)c * K + kk] : 0.f;
        }
        __syncthreads();
        #pragma unroll
        for (int k = 0; k < BK; ++k) {
            float4 a0 = *(const float4*)&As[k][ttm * 8];
            float4 a1 = *(const float4*)&As[k][ttm * 8 + 4];
            float4 b0 = *(const float4*)&Bs[k][ttn * 4];
            float av[8] = {a0.x, a0.y, a0.z, a0.w, a1.x, a1.y, a1.z, a1.w};
            float bv[4] = {b0.x, b0.y, b0.z, b0.w};
            #pragma unroll
            for (int i = 0; i < 8; ++i)
                #pragma unroll
                for (int j = 0; j < 4; ++j)
                    acc[i][j] += av[i] * bv[j];
        }
        __syncthreads();
    }

    float bv[4];
    #pragma unroll
    for (int j = 0; j < 4; ++j) bv[j] = bias[col0 + ttn * 4 + j];
    #pragma unroll
    for (int i = 0; i < 8; ++i) {
        int r = row0 + ttm * 8 + i;
        if (r < M) {
            float t0 = acc[i][0] + bv[0];
            float t1 = acc[i][1] + bv[1];
            float t2 = acc[i][2] + bv[2];
            float t3 = acc[i][3] + bv[3];
            if (RELU) {
                t0 = t0 > 0.f ? t0 : t0 * NEG_SLOPE;
                t1 = t1 > 0.f ? t1 : t1 * NEG_SLOPE;
                t2 = t2 > 0.f ? t2 : t2 * NEG_SLOPE;
                t3 = t3 > 0.f ? t3 : t3 * NEG_SLOPE;
            }
            float4 v; v.x = t0; v.y = t1; v.z = t2; v.w = t3;
            *(float4*)&C[(size_t)r * N + col0 + ttn * 4] = v;
        }
    }
}

// ---------------------------------------------- 128x128 8x8 cat-GEMM (layer 2)
// C = lrelu(cat(AL,AR) @ Wt + b), Wt transposed [K][N]. Requires CIN % 16 == 0,
// N % 128 == 0, K = 2*CIN.
template<bool RELU>
__global__ __launch_bounds__(256) void gemm_cat8x8_kernel(
        const float* __restrict__ AL, const float* __restrict__ AR,
        const float* __restrict__ Wt, const float* __restrict__ bias,
        float* __restrict__ C, int M, int N, int CIN) {
    __shared__ float As[16][132];
    __shared__ float Bs[16][132];
    const int row0 = blockIdx.x * 128;
    const int n0 = blockIdx.y * 128;
    const int tid = threadIdx.x;
    const int ttm = (tid & 7) | ((tid >> 7) << 3);   // 0..15, wave-local 0..7
    const int ttn = (tid >> 3) & 15;                 // 0..15, wave-local 0..7
    const int K = 2 * CIN;

    float acc[8][8];
    #pragma unroll
    for (int i = 0; i < 8; ++i)
        #pragma unroll
        for (int j = 0; j < 8; ++j) acc[i][j] = 0.f;

    for (int k0 = 0; k0 < K; k0 += 16) {
        const float* Asrc = (k0 < CIN) ? AL : AR;
        const int kb = (k0 < CIN) ? k0 : k0 - CIN;
        #pragma unroll
        for (int it = 0; it < 2; ++it) {
            int f = tid + it * 256;
            int m = f >> 2, kq = f & 3;
            int r = row0 + m;
            float4 v = {0.f, 0.f, 0.f, 0.f};
            if (r < M) v = *(const float4*)&Asrc[(size_t)r * CIN + kb + kq * 4];
            As[kq * 4 + 0][m] = v.x;
            As[kq * 4 + 1][m] = v.y;
            As[kq * 4 + 2][m] = v.z;
            As[kq * 4 + 3][m] = v.w;
        }
        #pragma unroll
        for (int it = 0; it < 2; ++it) {
            int f = tid + it * 256;
            int k = f >> 5, n4 = f & 31;
            *(float4*)&Bs[k][n4 * 4] =
                *(const float4*)&Wt[(size_t)(k0 + k) * N + n0 + n4 * 4];
        }
        __syncthreads();
        #pragma unroll
        for (int k = 0; k < 16; ++k) {
            float4 a0 = *(const float4*)&As[k][ttm * 8];
            float4 a1 = *(const float4*)&As[k][ttm * 8 + 4];
            float4 b0 = *(const float4*)&Bs[k][ttn * 8];
            float4 b1 = *(const float4*)&Bs[k][ttn * 8 + 4];
            float av[8] = {a0.x, a0.y, a0.z, a0.w, a1.x, a1.y, a1.z, a1.w};
            float bv[8] = {b0.x, b0.y, b0.z, b0.w, b1.x, b1.y, b1.z, b1.w};
            #pragma unroll
            for (int i = 0; i < 8; ++i)
                #pragma unroll
                for (int j = 0; j < 8; ++j)
                    acc[i][j] += av[i] * bv[j];
        }
        __syncthreads();
    }

    float bvv[8];
    #pragma unroll
    for (int j = 0; j < 8; ++j) bvv[j] = bias[n0 + ttn * 8 + j];
    #pragma unroll
    for (int i = 0; i < 8; ++i) {
        int r = row0 + ttm * 8 + i;
        if (r < M) {
            float t[8];
            #pragma unroll
            for (int j = 0; j < 8; ++j) {
                float v = acc[i][j] + bvv[j];
                if (RELU) v = v > 0.f ? v : v * NEG_SLOPE;
                t[j] = v;
            }
            float4 v0 = {t[0], t[1], t[2], t[3]};
            float4 v1 = {t[4], t[5], t[6], t[7]};
            *(float4*)&C[(size_t)r * N + n0 + ttn * 8] = v0;
            *(float4*)&C[(size_t)r * N + n0 + ttn * 8 + 4] = v1;
        }
    }
}

// ---------------------------------------- fused layer-3 GEMM + mean/max pool
// one block per graph; BN = 256 (all cols); 8x8 micro-tile; A read once.
// Wt transposed [K=2*CIN][NCH]. npg <= 64.
__global__ __launch_bounds__(256) void gemm_pool2_kernel(
        const float* __restrict__ AL, const float* __restrict__ AR,
        const float* __restrict__ Wt, const float* __restrict__ bias,
        float* __restrict__ gout, int npg, int CIN, int NCH) {
    __shared__ float As[16][68];
    __shared__ float Bs[16][260];
    __shared__ float redS[8][264];
    __shared__ float redM[8][264];
    const int g = blockIdx.x;
    const int tid = threadIdx.x;
    const int ttm = tid & 7;        // row group (wave-local 0..7)
    const int ttn = tid >> 3;       // col group 0..31 (wave-local 0..7)
    const int K = 2 * CIN;

    float acc[8][8];
    #pragma unroll
    for (int i = 0; i < 8; ++i)
        #pragma unroll
        for (int j = 0; j < 8; ++j) acc[i][j] = 0.f;

    for (int k0 = 0; k0 < K; k0 += 16) {
        const float* Asrc = (k0 < CIN) ? AL : AR;
        const int kb = (k0 < CIN) ? k0 : k0 - CIN;
        {
            int m = tid >> 2, kq = tid & 3;
            float4 v = {0.f, 0.f, 0.f, 0.f};
            if (m < npg)
                v = *(const float4*)&Asrc[((size_t)g * npg + m) * CIN + kb + kq * 4];
            As[kq * 4 + 0][m] = v.x;
            As[kq * 4 + 1][m] = v.y;
            As[kq * 4 + 2][m] = v.z;
            As[kq * 4 + 3][m] = v.w;
        }
        #pragma unroll
        for (int it = 0; it < 4; ++it) {
            int f = tid + it * 256;
            int k = f >> 6, n4 = f & 63;
            *(float4*)&Bs[k][n4 * 4] =
                *(const float4*)&Wt[(size_t)(k0 + k) * NCH + n4 * 4];
        }
        __syncthreads();
        #pragma unroll
        for (int k = 0; k < 16; ++k) {
            float4 a0 = *(const float4*)&As[k][ttm * 8];
            float4 a1 = *(const float4*)&As[k][ttm * 8 + 4];
            float4 b0 = *(const float4*)&Bs[k][ttn * 8];
            float4 b1 = *(const float4*)&Bs[k][ttn * 8 + 4];
            float av[8] = {a0.x, a0.y, a0.z, a0.w, a1.x, a1.y, a1.z, a1.w};
            float bv[8] = {b0.x, b0.y, b0.z, b0.w, b1.x, b1.y, b1.z, b1.w};
            #pragma unroll
            for (int i = 0; i < 8; ++i)
                #pragma unroll
                for (int j = 0; j < 8; ++j)
                    acc[i][j] += av[i] * bv[j];
        }
        __syncthreads();
    }

    // bias + lrelu + per-thread partial mean/max over valid rows
    float bvv[8];
    #pragma unroll
    for (int j = 0; j < 8; ++j) bvv[j] = bias[ttn * 8 + j];
    float lsum[8], lmax[8];
    #pragma unroll
    for (int j = 0; j < 8; ++j) { lsum[j] = 0.f; lmax[j] = -__builtin_huge_valf(); }
    #pragma unroll
    for (int i = 0; i < 8; ++i) {
        int m = ttm * 8 + i;
        if (m < npg) {
            #pragma unroll
            for (int j = 0; j < 8; ++j) {
                float t = acc[i][j] + bvv[j];
                t = t > 0.f ? t : t * NEG_SLOPE;
                lsum[j] += t;
                lmax[j] = fmaxf(lmax[j], t);
            }
        }
    }
    #pragma unroll
    for (int j = 0; j < 8; ++j) {
        redS[ttm][ttn * 8 + j] = lsum[j];
        redM[ttm][ttn * 8 + j] = lmax[j];
    }
    __syncthreads();
    #pragma unroll
    for (int s = 4; s > 0; s >>= 1) {
        if (ttm < s) {
            #pragma unroll
            for (int j = 0; j < 8; ++j) {
                int c = ttn * 8 + j;
                redS[ttm][c] += redS[ttm + s][c];
                redM[ttm][c] = fmaxf(redM[ttm][c], redM[ttm + s][c]);
            }
        }
        __syncthreads();
    }
    if (ttm == 0) {
        float invn = 1.f / (float)npg;
        #pragma unroll
        for (int j = 0; j < 8; ++j) {
            int c = ttn * 8 + j;
            gout[(size_t)g * (2 * NCH) + c] = redS[0][c] * invn;
            gout[(size_t)g * (2 * NCH) + NCH + c] = redM[0][c];
        }
    }
}

// ------------------------------------------------------- final 64->1 layer
__global__ void final_kernel(const float* __restrict__ c2, const float* __restrict__ Wc3,
                             const float* __restrict__ bc3, float* __restrict__ out, int G) {
    int g = blockIdx.x * (blockDim.x >> 6) + (threadIdx.x >> 6);
    int lane = threadIdx.x & 63;
    if (g >= G) return;
    float v = c2[(size_t)g * 64 + lane] * Wc3[lane];
    #pragma unroll
    for (int o = 32; o > 0; o >>= 1) v += __shfl_down(v, o);
    if (lane == 0) out[g] = v + bc3[0];
}

// ---------------------------------------------------------------- launcher
extern "C" void kernel_launch(void* const* d_in, const int* in_sizes, int n_in,
                              void* d_out, int out_size, void* d_ws, size_t ws_size,
                              hipStream_t stream) {
    const float* x   = (const float*)d_in[0];
    const int* ei    = (const int*)d_in[1];
    const float* W1l = (const float*)d_in[4];
    const float* b1  = (const float*)d_in[5];
    const float* W1r = (const float*)d_in[6];
    const float* W2l = (const float*)d_in[7];
    const float* b2  = (const float*)d_in[8];
    const float* W2r = (const float*)d_in[9];
    const float* W3l = (const float*)d_in[10];
    const float* b3  = (const float*)d_in[11];
    const float* W3r = (const float*)d_in[12];
    const float* Wc1 = (const float*)d_in[13];
    const float* bc1 = (const float*)d_in[14];
    const float* Wc2 = (const float*)d_in[15];
    const float* bc2 = (const float*)d_in[16];
    const float* Wc3 = (const float*)d_in[17];
    const float* bc3 = (const float*)d_in[18];
    float* out = (float*)d_out;

    const int nodes = in_sizes[0] / 5;      // 100000
    const int ne    = in_sizes[1] / 2;      // 1600000
    const int G     = out_size;             // 2000
    const int npg   = nodes / G;            // 50

    // ---- workspace layout (256B aligned), peak ~118 MB
    char* ws = (char*)d_ws;
    size_t pos = 0;
    auto take = [&](size_t bytes) -> char* {
        char* p = ws + pos;
        pos += (bytes + 255) & ~(size_t)255;
        return p;
    };
    int* deg     = (int*)take((size_t)nodes * 4);
    int* cursor  = (int*)take((size_t)nodes * 4);
    int* off     = (int*)take((size_t)(nodes + 1) * 4);
    int* csr     = (int*)take((size_t)ne * 4);
    float* Wcat1 = (float*)take((size_t)64 * 10 * 4);
    float* Wct2  = (float*)take((size_t)128 * 128 * 4);   // transposed [K][N]
    float* Wct3  = (float*)take((size_t)256 * 256 * 4);   // transposed [K][N]
    float* gbuf  = (float*)take((size_t)G * 512 * 4);
    float* c1    = (float*)take((size_t)G * 128 * 4);
    float* c2    = (float*)take((size_t)G * 64 * 4);
    // contiguous region reused: [meanx | mean1 | h1] (53.2MB) -> later mean2 (51.2MB)
    float* meanx = (float*)take((size_t)nodes * 5 * 4);
    float* mean1 = (float*)take((size_t)nodes * 64 * 4);
    float* h1    = (float*)take((size_t)nodes * 64 * 4);
    float* h2    = (float*)take((size_t)nodes * 128 * 4);
    float* mean2 = meanx;   // aliases dead meanx/mean1/h1 after L2 GEMM

    if (pos > ws_size) {
        sentinel_kernel<<<(G + 255) / 256, 256, 0, stream>>>(out, G);
        return;
    }

    const int* src = ei;
    const int* dst = ei + ne;

    hipMemsetAsync(deg, 0, (size_t)nodes * 4, stream);
    hipMemsetAsync(cursor, 0, (size_t)nodes * 4, stream);

    int eb = (ne + 255) / 256;
    count_deg_kernel<<<eb, 256, 0, stream>>>(dst, deg, ne);
    scan_kernel<<<1, 1024, 0, stream>>>(deg, off, nodes);
    scatter_kernel<<<eb, 256, 0, stream>>>(src, dst, off, cursor, csr, ne);

    pack_w_kernel<<<(64 * 10 + 255) / 256, 256, 0, stream>>>(W1l, W1r, Wcat1, 64, 5);
    pack_wt_kernel<<<(128 * 128 + 255) / 256, 256, 0, stream>>>(W2l, W2r, Wct2, 128, 64);
    pack_wt_kernel<<<(256 * 256 + 255) / 256, 256, 0, stream>>>(W3l, W3r, Wct3, 256, 128);

    int ab = (nodes + 3) / 4;   // one node per wave, 4 waves/block

    // ---- layer 1: [mean(x)|x] (K=10) -> 64
    agg_kernel<5><<<ab, 256, 0, stream>>>(x, off, csr, meanx, nodes);
    {
        dim3 g((nodes + BM - 1) / BM, 64 / BN);
        gemm_cat_kernel<true><<<g, 256, 0, stream>>>(meanx, x, Wcat1, b1, h1, nodes, 64, 10, 5);
    }
    // ---- layer 2: [mean(h1)|h1] (K=128) -> 128
    agg_vec_kernel<64><<<ab, 256, 0, stream>>>(h1, off, csr, mean1, nodes);
    {
        dim3 g((nodes + 127) / 128, 128 / 128);
        gemm_cat8x8_kernel<true><<<g, 256, 0, stream>>>(mean1, h1, Wct2, b2, h2, nodes, 128, 64);
    }
    // ---- layer 3: [mean(h2)|h2] (K=256) -> 256, fused with mean/max pool
    agg_vec_kernel<128><<<ab, 256, 0, stream>>>(h2, off, csr, mean2, nodes);
    gemm_pool2_kernel<<<G, 256, 0, stream>>>(mean2, h2, Wct3, b3, gbuf, npg, 128, 256);

    // ---- classifier: 512 -> 128 -> 64 -> 1
    {
        dim3 g((G + BM - 1) / BM, 128 / BN);
        gemm_cat_kernel<true><<<g, 256, 0, stream>>>(gbuf, nullptr, Wc1, bc1, c1, G, 128, 512, 512);
    }
    {
        dim3 g((G + BM - 1) / BM, 64 / BN);
        gemm_cat_kernel<true><<<g, 256, 0, stream>>>(c1, nullptr, Wc2, bc2, c2, G, 64, 128, 128);
    }
    final_kernel<<<(G + 3) / 4, 256, 0, stream>>>(c2, Wc3, bc3, out, G);
}

// Round 4
// 769.721 us; speedup vs baseline: 1.5710x; 1.1979x over previous
//
#include <hip/hip_runtime.h>
#include <cstdint>
#include <cstddef>

#define NEG_SLOPE 0.2f

typedef __attribute__((ext_vector_type(8))) short bh8;     // 8 bf16 in 4 VGPRs
typedef __attribute__((ext_vector_type(16))) float f32x16; // MFMA 32x32 accumulator

// split f32 -> bf16 hi + bf16 lo (x ~= hi + lo, residual ~2^-17 relative)
__device__ inline void splitf(float x, short& hi, short& lo) {
    uint32_t u = __float_as_uint(x);
    uint32_t rh = (u + 0x7FFFu + ((u >> 16) & 1u)) & 0xFFFF0000u;
    hi = (short)(rh >> 16);
    float rem = x - __uint_as_float(rh);
    uint32_t u2 = __float_as_uint(rem);
    lo = (short)((u2 + 0x7FFFu + ((u2 >> 16) & 1u)) >> 16);
}

// ---------------------------------------------------------------- sentinel
__global__ void sentinel_kernel(float* __restrict__ out, int n) {
    int i = blockIdx.x * blockDim.x + threadIdx.x;
    if (i < n) out[i] = 12345.0f;
}

// ---------------------------------------------------------------- CSR build
__global__ void count_deg_kernel(const int* __restrict__ dst, int* __restrict__ deg, int ne) {
    int e = blockIdx.x * blockDim.x + threadIdx.x;
    if (e < ne) atomicAdd(&deg[dst[e]], 1);
}

__global__ void scan_kernel(const int* __restrict__ deg, int* __restrict__ off, int n) {
    __shared__ int wsum[16];
    __shared__ int carry_s;
    const int tid = threadIdx.x, lane = tid & 63, wid = tid >> 6;
    if (tid == 0) carry_s = 0;
    __syncthreads();
    for (int base = 0; base < n; base += 1024) {
        int i = base + tid;
        int v = (i < n) ? deg[i] : 0;
        int incl = v;
        #pragma unroll
        for (int o = 1; o < 64; o <<= 1) {
            int t = __shfl_up(incl, o);
            if (lane >= o) incl += t;
        }
        if (lane == 63) wsum[wid] = incl;
        __syncthreads();
        if (tid < 16) {
            int wv = wsum[tid];
            int winc = wv;
            #pragma unroll
            for (int o = 1; o < 16; o <<= 1) {
                int t = __shfl_up(winc, o);
                if (tid >= o) winc += t;
            }
            wsum[tid] = winc - wv;
        }
        __syncthreads();
        int carry = carry_s;
        int excl = carry + wsum[wid] + incl - v;
        if (i < n) off[i] = excl;
        __syncthreads();
        if (tid == 1023) carry_s = excl + v;
        __syncthreads();
    }
    if (threadIdx.x == 0) off[n] = carry_s;
}

__global__ void scatter_kernel(const int* __restrict__ src, const int* __restrict__ dst,
                               const int* __restrict__ off, int* __restrict__ cursor,
                               int* __restrict__ csr, int ne) {
    int e = blockIdx.x * blockDim.x + threadIdx.x;
    if (e < ne) {
        int d = dst[e];
        int p = off[d] + atomicAdd(&cursor[d], 1);
        csr[p] = src[e];
    }
}

// ------------------------------------------------------- weight packs
// f32 cat pack, [N][K] (layer-1 small GEMM)
__global__ void pack_w_kernel(const float* __restrict__ Wl, const float* __restrict__ Wr,
                              float* __restrict__ Wc, int COUT, int CIN) {
    int i = blockIdx.x * blockDim.x + threadIdx.x;
    int tot = COUT * 2 * CIN;
    if (i >= tot) return;
    int o = i / (2 * CIN), k = i % (2 * CIN);
    Wc[i] = (k < CIN) ? Wl[o * CIN + k] : Wr[o * CIN + (k - CIN)];
}

// split-bf16 pack: Whi/Wlo [COUT][K]; cat at CIN (K==CIN -> plain, Wr unused)
__global__ void pack_wsplit_kernel(const float* __restrict__ Wl, const float* __restrict__ Wr,
                                   short* __restrict__ Whi, short* __restrict__ Wlo,
                                   int COUT, int K, int CIN) {
    int i = blockIdx.x * blockDim.x + threadIdx.x;
    if (i >= COUT * K) return;
    int n = i / K, k = i % K;
    float v = (k < CIN) ? Wl[n * CIN + k] : Wr[n * CIN + (k - CIN)];
    short h, l;
    splitf(v, h, l);
    Whi[i] = h; Wlo[i] = l;
}

// ------------------------------------------------------- mean aggregation
template<int CIN>
__global__ void agg_kernel(const float* __restrict__ h, const int* __restrict__ off,
                           const int* __restrict__ csr, float* __restrict__ mean, int n_nodes) {
    int wave = blockIdx.x * (blockDim.x >> 6) + (threadIdx.x >> 6);
    int lane = threadIdx.x & 63;
    if (wave >= n_nodes) return;
    constexpr int R = (CIN + 63) / 64;
    float acc[R];
    #pragma unroll
    for (int r = 0; r < R; ++r) acc[r] = 0.f;
    int e0 = off[wave], e1 = off[wave + 1];
    for (int e = e0; e < e1; ++e) {
        int s = csr[e];
        const float* hp = h + (size_t)s * CIN;
        #pragma unroll
        for (int r = 0; r < R; ++r) {
            int c = lane + 64 * r;
            if (c < CIN) acc[r] += hp[c];
        }
    }
    float inv = (e1 > e0) ? 1.f / (float)(e1 - e0) : 0.f;
    float* mp = mean + (size_t)wave * CIN;
    #pragma unroll
    for (int r = 0; r < R; ++r) {
        int c = lane + 64 * r;
        if (c < CIN) mp[c] = acc[r] * inv;
    }
}

template<int CIN>
__global__ void agg_vec_kernel(const float* __restrict__ h, const int* __restrict__ off,
                               const int* __restrict__ csr, float* __restrict__ mean,
                               int n_nodes) {
    constexpr int LPR = CIN / 4;
    constexpr int SLOTS = 64 / LPR;
    int wave = blockIdx.x * (blockDim.x >> 6) + (threadIdx.x >> 6);
    int lane = threadIdx.x & 63;
    if (wave >= n_nodes) return;
    int slot = lane / LPR, cg = lane % LPR;
    int e0 = off[wave], cnt = off[wave + 1] - e0;
    float4 acc = {0.f, 0.f, 0.f, 0.f};
    for (int i = slot; i < cnt; i += SLOTS) {
        int s = csr[e0 + i];
        float4 v = *(const float4*)(h + (size_t)s * CIN + cg * 4);
        acc.x += v.x; acc.y += v.y; acc.z += v.z; acc.w += v.w;
    }
    #pragma unroll
    for (int o = LPR; o < 64; o <<= 1) {
        acc.x += __shfl_xor(acc.x, o);
        acc.y += __shfl_xor(acc.y, o);
        acc.z += __shfl_xor(acc.z, o);
        acc.w += __shfl_xor(acc.w, o);
    }
    if (slot == 0) {
        float inv = (cnt > 0) ? 1.f / (float)cnt : 0.f;
        float4 r = {acc.x * inv, acc.y * inv, acc.z * inv, acc.w * inv};
        *(float4*)(mean + (size_t)wave * CIN + cg * 4) = r;
    }
}

// ------------------------------------------------------------ f32 cat-GEMM (small)
#define BM 128
#define BN 64
#define BK 16

template<bool RELU>
__global__ __launch_bounds__(256) void gemm_cat_kernel(
        const float* __restrict__ AL, const float* __restrict__ AR,
        const float* __restrict__ W, const float* __restrict__ bias,
        float* __restrict__ C, int M, int N, int K, int CIN) {
    __shared__ float As[BK][BM + 4];
    __shared__ float Bs[BK][BN + 4];
    const int row0 = blockIdx.x * BM;
    const int col0 = blockIdx.y * BN;
    const int tid = threadIdx.x;
    const int ttm = tid & 15, ttn = tid >> 4;

    float acc[8][4];
    #pragma unroll
    for (int i = 0; i < 8; ++i)
        #pragma unroll
        for (int j = 0; j < 4; ++j) acc[i][j] = 0.f;

    for (int k0 = 0; k0 < K; k0 += BK) {
        for (int i = tid; i < BM * BK; i += 256) {
            int m = i >> 4, k = i & 15;
            int r = row0 + m, kk = k0 + k;
            float v = 0.f;
            if (r < M && kk < K)
                v = (kk < CIN) ? AL[(size_t)r * CIN + kk]
                               : AR[(size_t)r * CIN + (kk - CIN)];
            As[k][m] = v;
        }
        for (int i = tid; i < BN * BK; i += 256) {
            int n = i >> 4, k = i & 15;
            int c = col0 + n, kk = k0 + k;
            Bs[k][n] = (c < N && kk < K) ? W[(size_t)c * K + kk] : 0.f;
        }
        __syncthreads();
        #pragma unroll
        for (int k = 0; k < BK; ++k) {
            float4 a0 = *(const float4*)&As[k][ttm * 8];
            float4 a1 = *(const float4*)&As[k][ttm * 8 + 4];
            float4 b0 = *(const float4*)&Bs[k][ttn * 4];
            float av[8] = {a0.x, a0.y, a0.z, a0.w, a1.x, a1.y, a1.z, a1.w};
            float bv[4] = {b0.x, b0.y, b0.z, b0.w};
            #pragma unroll
            for (int i = 0; i < 8; ++i)
                #pragma unroll
                for (int j = 0; j < 4; ++j)
                    acc[i][j] += av[i] * bv[j];
        }
        __syncthreads();
    }

    float bv[4];
    #pragma unroll
    for (int j = 0; j < 4; ++j) bv[j] = bias[col0 + ttn * 4 + j];
    #pragma unroll
    for (int i = 0; i < 8; ++i) {
        int r = row0 + ttm * 8 + i;
        if (r < M) {
            float t0 = acc[i][0] + bv[0];
            float t1 = acc[i][1] + bv[1];
            float t2 = acc[i][2] + bv[2];
            float t3 = acc[i][3] + bv[3];
            if (RELU) {
                t0 = t0 > 0.f ? t0 : t0 * NEG_SLOPE;
                t1 = t1 > 0.f ? t1 : t1 * NEG_SLOPE;
                t2 = t2 > 0.f ? t2 : t2 * NEG_SLOPE;
                t3 = t3 > 0.f ? t3 : t3 * NEG_SLOPE;
            }
            float4 v; v.x = t0; v.y = t1; v.z = t2; v.w = t3;
            *(float4*)&C[(size_t)r * N + col0 + ttn * 4] = v;
        }
    }
}

// ------------------------------------- split-bf16 MFMA cat-GEMM (N=128/block)
// C = lrelu(cat(AL,AR) @ W^T + b); Whi/Wlo bf16 [N][K]; K%32==0, CIN%16==0.
// block 256 thr = 4 waves; tile 128x128; wave w: rowtile w (32 rows) x 4 coltiles.
__global__ __launch_bounds__(256) void gemm_cat_mfma_kernel(
        const float* __restrict__ AL, const float* __restrict__ AR,
        const short* __restrict__ Whi, const short* __restrict__ Wlo,
        const float* __restrict__ bias, float* __restrict__ C,
        int M, int N, int K, int CIN) {
    __shared__ short AsH[128][40], AsL[128][40];
    __shared__ short BsH[128][40], BsL[128][40];
    const int row0 = blockIdx.x * 128;
    const int n0 = blockIdx.y * 128;
    const int tid = threadIdx.x;
    const int w = tid >> 6;
    const int lane31 = tid & 31, lhalf = (tid & 63) >> 5;

    f32x16 acc[4];
    #pragma unroll
    for (int ci = 0; ci < 4; ++ci)
        #pragma unroll
        for (int r = 0; r < 16; ++r) acc[ci][r] = 0.f;

    for (int k0 = 0; k0 < K; k0 += 32) {
        const float* Asrc = (k0 < CIN) ? AL : AR;
        const int kb = (k0 < CIN) ? k0 : k0 - CIN;
        {   // stage A: 128 rows x 32 k, split hi/lo
            int row = tid >> 1, kq = (tid & 1) * 16;
            int r = row0 + row;
            float vv[16];
            #pragma unroll
            for (int i = 0; i < 16; ++i) vv[i] = 0.f;
            if (r < M) {
                const float* p = &Asrc[(size_t)r * CIN + kb + kq];
                #pragma unroll
                for (int q = 0; q < 4; ++q) {
                    float4 v = ((const float4*)p)[q];
                    vv[q * 4 + 0] = v.x; vv[q * 4 + 1] = v.y;
                    vv[q * 4 + 2] = v.z; vv[q * 4 + 3] = v.w;
                }
            }
            #pragma unroll
            for (int half = 0; half < 2; ++half) {
                bh8 h8, l8;
                #pragma unroll
                for (int i = 0; i < 8; ++i) {
                    short a, b;
                    splitf(vv[half * 8 + i], a, b);
                    h8[i] = a; l8[i] = b;
                }
                *(bh8*)&AsH[row][kq + half * 8] = h8;
                *(bh8*)&AsL[row][kq + half * 8] = l8;
            }
        }
        {   // stage B: 128 n x 32 k (already bf16 in global)
            int n = tid & 127, half = tid >> 7;
            const short* src = half ? Wlo : Whi;
            const uint4* p = (const uint4*)&src[(size_t)(n0 + n) * K + k0];
            if (half) {
                #pragma unroll
                for (int q = 0; q < 4; ++q) *(uint4*)&BsL[n][q * 8] = p[q];
            } else {
                #pragma unroll
                for (int q = 0; q < 4; ++q) *(uint4*)&BsH[n][q * 8] = p[q];
            }
        }
        __syncthreads();
        #pragma unroll
        for (int ks = 0; ks < 2; ++ks) {
            int kofs = ks * 16 + lhalf * 8;
            bh8 aH = *(bh8*)&AsH[w * 32 + lane31][kofs];
            bh8 aL = *(bh8*)&AsL[w * 32 + lane31][kofs];
            #pragma unroll
            for (int ci = 0; ci < 4; ++ci) {
                bh8 bH = *(bh8*)&BsH[ci * 32 + lane31][kofs];
                bh8 bL = *(bh8*)&BsL[ci * 32 + lane31][kofs];
                acc[ci] = __builtin_amdgcn_mfma_f32_32x32x16_bf16(aH, bH, acc[ci], 0, 0, 0);
                acc[ci] = __builtin_amdgcn_mfma_f32_32x32x16_bf16(aH, bL, acc[ci], 0, 0, 0);
                acc[ci] = __builtin_amdgcn_mfma_f32_32x32x16_bf16(aL, bH, acc[ci], 0, 0, 0);
            }
        }
        __syncthreads();
    }

    #pragma unroll
    for (int ci = 0; ci < 4; ++ci) {
        int col = n0 + ci * 32 + lane31;
        float b = bias[col];
        #pragma unroll
        for (int r = 0; r < 16; ++r) {
            int row = row0 + w * 32 + (r & 3) + 8 * (r >> 2) + 4 * lhalf;
            if (row < M) {
                float v = acc[ci][r] + b;
                v = v > 0.f ? v : v * NEG_SLOPE;
                C[(size_t)row * N + col] = v;
            }
        }
    }
}

// ---------------------- split-bf16 MFMA fused layer-3 GEMM + mean/max pool
// one block per graph (npg<=64 rows padded to 64); N=256 cols; K=2*CIN=256.
__global__ __launch_bounds__(256) void gemm_pool_mfma_kernel(
        const float* __restrict__ AL, const float* __restrict__ AR,
        const short* __restrict__ Whi, const short* __restrict__ Wlo,
        const float* __restrict__ bias, float* __restrict__ gout,
        int npg, int CIN, int NCH) {
    __shared__ short AsH[64][40], AsL[64][40];
    __shared__ short BsH[256][40], BsL[256][40];
    __shared__ float redS[2][256], redM[2][256];
    const int g = blockIdx.x;
    const int K = 2 * CIN;
    const int tid = threadIdx.x;
    const int w = tid >> 6;
    const int lane31 = tid & 31, lhalf = (tid & 63) >> 5;
    const int rt = w & 1, ctbase = (w >> 1) * 4;

    f32x16 acc[4];
    #pragma unroll
    for (int ci = 0; ci < 4; ++ci)
        #pragma unroll
        for (int r = 0; r < 16; ++r) acc[ci][r] = 0.f;

    for (int k0 = 0; k0 < K; k0 += 32) {
        const float* Asrc = (k0 < CIN) ? AL : AR;
        const int kb = (k0 < CIN) ? k0 : k0 - CIN;
        {   // stage A: 64 rows x 32 k
            int row = tid >> 2, kq = (tid & 3) * 8;
            float vv[8];
            #pragma unroll
            for (int i = 0; i < 8; ++i) vv[i] = 0.f;
            if (row < npg) {
                const float* p = &Asrc[((size_t)g * npg + row) * CIN + kb + kq];
                #pragma unroll
                for (int q = 0; q < 2; ++q) {
                    float4 v = ((const float4*)p)[q];
                    vv[q * 4 + 0] = v.x; vv[q * 4 + 1] = v.y;
                    vv[q * 4 + 2] = v.z; vv[q * 4 + 3] = v.w;
                }
            }
            bh8 h8, l8;
            #pragma unroll
            for (int i = 0; i < 8; ++i) {
                short a, b;
                splitf(vv[i], a, b);
                h8[i] = a; l8[i] = b;
            }
            *(bh8*)&AsH[row][kq] = h8;
            *(bh8*)&AsL[row][kq] = l8;
        }
        {   // stage B: 256 n x 32 k
            int n = tid;
            const uint4* ph = (const uint4*)&Whi[(size_t)n * K + k0];
            const uint4* pl = (const uint4*)&Wlo[(size_t)n * K + k0];
            #pragma unroll
            for (int q = 0; q < 4; ++q) {
                *(uint4*)&BsH[n][q * 8] = ph[q];
                *(uint4*)&BsL[n][q * 8] = pl[q];
            }
        }
        __syncthreads();
        #pragma unroll
        for (int ks = 0; ks < 2; ++ks) {
            int kofs = ks * 16 + lhalf * 8;
            bh8 aH = *(bh8*)&AsH[rt * 32 + lane31][kofs];
            bh8 aL = *(bh8*)&AsL[rt * 32 + lane31][kofs];
            #pragma unroll
            for (int ci = 0; ci < 4; ++ci) {
                bh8 bH = *(bh8*)&BsH[(ctbase + ci) * 32 + lane31][kofs];
                bh8 bL = *(bh8*)&BsL[(ctbase + ci) * 32 + lane31][kofs];
                acc[ci] = __builtin_amdgcn_mfma_f32_32x32x16_bf16(aH, bH, acc[ci], 0, 0, 0);
                acc[ci] = __builtin_amdgcn_mfma_f32_32x32x16_bf16(aH, bL, acc[ci], 0, 0, 0);
                acc[ci] = __builtin_amdgcn_mfma_f32_32x32x16_bf16(aL, bH, acc[ci], 0, 0, 0);
            }
        }
        __syncthreads();
    }

    // bias + lrelu + pool (mask pad rows)
    #pragma unroll
    for (int ci = 0; ci < 4; ++ci) {
        int col = (ctbase + ci) * 32 + lane31;
        float b = bias[col];
        float ls = 0.f, lm = -__builtin_huge_valf();
        #pragma unroll
        for (int r = 0; r < 16; ++r) {
            int row = rt * 32 + (r & 3) + 8 * (r >> 2) + 4 * lhalf;
            if (row < npg) {
                float v = acc[ci][r] + b;
                v = v > 0.f ? v : v * NEG_SLOPE;
                ls += v;
                lm = fmaxf(lm, v);
            }
        }
        ls += __shfl_xor(ls, 32);
        lm = fmaxf(lm, __shfl_xor(lm, 32));
        if (lhalf == 0) { redS[rt][col] = ls; redM[rt][col] = lm; }
    }
    __syncthreads();
    {
        int c = tid;
        float s = redS[0][c] + redS[1][c];
        float m = fmaxf(redM[0][c], redM[1][c]);
        gout[(size_t)g * (2 * NCH) + c] = s / (float)npg;
        gout[(size_t)g * (2 * NCH) + NCH + c] = m;
    }
}

// ------------------------------------------------------- final 64->1 layer
__global__ void final_kernel(const float* __restrict__ c2, const float* __restrict__ Wc3,
                             const float* __restrict__ bc3, float* __restrict__ out, int G) {
    int g = blockIdx.x * (blockDim.x >> 6) + (threadIdx.x >> 6);
    int lane = threadIdx.x & 63;
    if (g >= G) return;
    float v = c2[(size_t)g * 64 + lane] * Wc3[lane];
    #pragma unroll
    for (int o = 32; o > 0; o >>= 1) v += __shfl_down(v, o);
    if (lane == 0) out[g] = v + bc3[0];
}

// ---------------------------------------------------------------- launcher
extern "C" void kernel_launch(void* const* d_in, const int* in_sizes, int n_in,
                              void* d_out, int out_size, void* d_ws, size_t ws_size,
                              hipStream_t stream) {
    const float* x   = (const float*)d_in[0];
    const int* ei    = (const int*)d_in[1];
    const float* W1l = (const float*)d_in[4];
    const float* b1  = (const float*)d_in[5];
    const float* W1r = (const float*)d_in[6];
    const float* W2l = (const float*)d_in[7];
    const float* b2  = (const float*)d_in[8];
    const float* W2r = (const float*)d_in[9];
    const float* W3l = (const float*)d_in[10];
    const float* b3  = (const float*)d_in[11];
    const float* W3r = (const float*)d_in[12];
    const float* Wc1 = (const float*)d_in[13];
    const float* bc1 = (const float*)d_in[14];
    const float* Wc2 = (const float*)d_in[15];
    const float* bc2 = (const float*)d_in[16];
    const float* Wc3 = (const float*)d_in[17];
    const float* bc3 = (const float*)d_in[18];
    float* out = (float*)d_out;

    const int nodes = in_sizes[0] / 5;      // 100000
    const int ne    = in_sizes[1] / 2;      // 1600000
    const int G     = out_size;             // 2000
    const int npg   = nodes / G;            // 50

    char* ws = (char*)d_ws;
    size_t pos = 0;
    auto take = [&](size_t bytes) -> char* {
        char* p = ws + pos;
        pos += (bytes + 255) & ~(size_t)255;
        return p;
    };
    int* deg     = (int*)take((size_t)nodes * 4);
    int* cursor  = (int*)take((size_t)nodes * 4);
    int* off     = (int*)take((size_t)(nodes + 1) * 4);
    int* csr     = (int*)take((size_t)ne * 4);
    float* Wcat1 = (float*)take((size_t)64 * 10 * 4);
    short* Whi2  = (short*)take((size_t)128 * 128 * 2);
    short* Wlo2  = (short*)take((size_t)128 * 128 * 2);
    short* Whi3  = (short*)take((size_t)256 * 256 * 2);
    short* Wlo3  = (short*)take((size_t)256 * 256 * 2);
    short* WhiC  = (short*)take((size_t)128 * 512 * 2);
    short* WloC  = (short*)take((size_t)128 * 512 * 2);
    float* gbuf  = (float*)take((size_t)G * 512 * 4);
    float* c1    = (float*)take((size_t)G * 128 * 4);
    float* c2    = (float*)take((size_t)G * 64 * 4);
    // reused region: [meanx | mean1 | h1] (53.2MB) -> later mean2 (51.2MB)
    float* meanx = (float*)take((size_t)nodes * 5 * 4);
    float* mean1 = (float*)take((size_t)nodes * 64 * 4);
    float* h1    = (float*)take((size_t)nodes * 64 * 4);
    float* h2    = (float*)take((size_t)nodes * 128 * 4);
    float* mean2 = meanx;

    if (pos > ws_size) {
        sentinel_kernel<<<(G + 255) / 256, 256, 0, stream>>>(out, G);
        return;
    }

    const int* src = ei;
    const int* dst = ei + ne;

    hipMemsetAsync(deg, 0, (size_t)nodes * 4, stream);
    hipMemsetAsync(cursor, 0, (size_t)nodes * 4, stream);

    int eb = (ne + 255) / 256;
    count_deg_kernel<<<eb, 256, 0, stream>>>(dst, deg, ne);
    scan_kernel<<<1, 1024, 0, stream>>>(deg, off, nodes);
    scatter_kernel<<<eb, 256, 0, stream>>>(src, dst, off, cursor, csr, ne);

    pack_w_kernel<<<(64 * 10 + 255) / 256, 256, 0, stream>>>(W1l, W1r, Wcat1, 64, 5);
    pack_wsplit_kernel<<<(128 * 128 + 255) / 256, 256, 0, stream>>>(W2l, W2r, Whi2, Wlo2, 128, 128, 64);
    pack_wsplit_kernel<<<(256 * 256 + 255) / 256, 256, 0, stream>>>(W3l, W3r, Whi3, Wlo3, 256, 256, 128);
    pack_wsplit_kernel<<<(128 * 512 + 255) / 256, 256, 0, stream>>>(Wc1, Wc1, WhiC, WloC, 128, 512, 512);

    int ab = (nodes + 3) / 4;

    // ---- layer 1: [mean(x)|x] (K=10) -> 64  (f32 path, tiny K)
    agg_kernel<5><<<ab, 256, 0, stream>>>(x, off, csr, meanx, nodes);
    {
        dim3 g((nodes + BM - 1) / BM, 64 / BN);
        gemm_cat_kernel<true><<<g, 256, 0, stream>>>(meanx, x, Wcat1, b1, h1, nodes, 64, 10, 5);
    }
    // ---- layer 2: [mean(h1)|h1] (K=128) -> 128  (split-bf16 MFMA)
    agg_vec_kernel<64><<<ab, 256, 0, stream>>>(h1, off, csr, mean1, nodes);
    {
        dim3 g((nodes + 127) / 128, 1);
        gemm_cat_mfma_kernel<<<g, 256, 0, stream>>>(mean1, h1, Whi2, Wlo2, b2, h2,
                                                    nodes, 128, 128, 64);
    }
    // ---- layer 3: [mean(h2)|h2] (K=256) -> 256, fused pool (split-bf16 MFMA)
    agg_vec_kernel<128><<<ab, 256, 0, stream>>>(h2, off, csr, mean2, nodes);
    gemm_pool_mfma_kernel<<<G, 256, 0, stream>>>(mean2, h2, Whi3, Wlo3, b3, gbuf,
                                                 npg, 128, 256);
    // ---- classifier: 512 -> 128 (MFMA) -> 64 (f32) -> 1
    {
        dim3 g((G + 127) / 128, 1);
        gemm_cat_mfma_kernel<<<g, 256, 0, stream>>>(gbuf, gbuf, WhiC, WloC, bc1, c1,
                                                    G, 128, 512, 512);
    }
    {
        dim3 g((G + BM - 1) / BM, 64 / BN);
        gemm_cat_kernel<true><<<g, 256, 0, stream>>>(c1, nullptr, Wc2, bc2, c2, G, 64, 128, 128);
    }
    final_kernel<<<(G + 3) / 4, 256, 0, stream>>>(c2, Wc3, bc3, out, G);
}

// Round 5
// 734.571 us; speedup vs baseline: 1.6462x; 1.0479x over previous
//
#include <hip/hip_runtime.h>
#include <cstdint>
#include <cstddef>

#define NEG_SLOPE 0.2f

typedef __attribute__((ext_vector_type(8))) short bh8;     // 8 bf16 in 4 VGPRs
typedef __attribute__((ext_vector_type(16))) float f32x16; // MFMA 32x32 accumulator

// split f32 -> bf16 hi + bf16 lo (x ~= hi + lo, residual ~2^-17 relative)
__device__ inline void splitf(float x, short& hi, short& lo) {
    uint32_t u = __float_as_uint(x);
    uint32_t rh = (u + 0x7FFFu + ((u >> 16) & 1u)) & 0xFFFF0000u;
    hi = (short)(rh >> 16);
    float rem = x - __uint_as_float(rh);
    uint32_t u2 = __float_as_uint(rem);
    lo = (short)((u2 + 0x7FFFu + ((u2 >> 16) & 1u)) >> 16);
}

// ---------------------------------------------------------------- sentinel
__global__ void sentinel_kernel(float* __restrict__ out, int n) {
    int i = blockIdx.x * blockDim.x + threadIdx.x;
    if (i < n) out[i] = 12345.0f;
}

// ------------------------------------------------- CSR build (bucketed)
// bucket = dst >> 9 (512 nodes per bucket)
#define HIST_CH 8192
__global__ void bucket_hist_kernel(const int* __restrict__ dst, int* __restrict__ deg,
                                   int* __restrict__ bcnt, int ne, int nb) {
    __shared__ int hist[256];
    const int tid = threadIdx.x;
    hist[tid] = 0;
    __syncthreads();
    int e0 = blockIdx.x * HIST_CH;
    for (int i = tid; i < HIST_CH; i += 256) {
        int e = e0 + i;
        if (e < ne) {
            int d = dst[e];
            atomicAdd(&deg[d], 1);
            atomicAdd(&hist[d >> 9], 1);
        }
    }
    __syncthreads();
    if (tid < nb && hist[tid] > 0) atomicAdd(&bcnt[tid], hist[tid]);
}

__global__ void scan_kernel(const int* __restrict__ deg, int* __restrict__ off, int n) {
    __shared__ int wsum[16];
    __shared__ int carry_s;
    const int tid = threadIdx.x, lane = tid & 63, wid = tid >> 6;
    if (tid == 0) carry_s = 0;
    __syncthreads();
    for (int base = 0; base < n; base += 1024) {
        int i = base + tid;
        int v = (i < n) ? deg[i] : 0;
        int incl = v;
        #pragma unroll
        for (int o = 1; o < 64; o <<= 1) {
            int t = __shfl_up(incl, o);
            if (lane >= o) incl += t;
        }
        if (lane == 63) wsum[wid] = incl;
        __syncthreads();
        if (tid < 16) {
            int wv = wsum[tid];
            int winc = wv;
            #pragma unroll
            for (int o = 1; o < 16; o <<= 1) {
                int t = __shfl_up(winc, o);
                if (tid >= o) winc += t;
            }
            wsum[tid] = winc - wv;
        }
        __syncthreads();
        int carry = carry_s;
        int excl = carry + wsum[wid] + incl - v;
        if (i < n) off[i] = excl;
        __syncthreads();
        if (tid == 1023) carry_s = excl + v;
        __syncthreads();
    }
    if (threadIdx.x == 0) off[n] = carry_s;
}

// scatter (src,dst) pairs into bucket-major staging, bucket-contiguous writes
#define SCAT_CH 4096
__global__ void bucket_scatter_kernel(const int* __restrict__ src, const int* __restrict__ dst,
                                      const int* __restrict__ boff, int* __restrict__ bcur,
                                      uint2* __restrict__ pairs, int ne, int nb) {
    __shared__ int hist[256], lcur[256], gbase[256];
    const int tid = threadIdx.x;
    hist[tid] = 0; lcur[tid] = 0;
    __syncthreads();
    int e0 = blockIdx.x * SCAT_CH;
    for (int i = tid; i < SCAT_CH; i += 256) {
        int e = e0 + i;
        if (e < ne) atomicAdd(&hist[dst[e] >> 9], 1);
    }
    __syncthreads();
    if (tid < nb) {
        int h = hist[tid];
        gbase[tid] = (h > 0) ? (boff[tid] + atomicAdd(&bcur[tid], h)) : 0;
    }
    __syncthreads();
    for (int i = tid; i < SCAT_CH; i += 256) {
        int e = e0 + i;
        if (e < ne) {
            int d = dst[e];
            int b = d >> 9;
            int r = atomicAdd(&lcur[b], 1);
            uint2 p; p.x = (unsigned)src[e]; p.y = (unsigned)d;
            pairs[gbase[b] + r] = p;
        }
    }
}

// one block per bucket: exact-CSR scatter within an L2-resident 32KB span
__global__ void final_scatter_kernel(const uint2* __restrict__ pairs,
                                     const int* __restrict__ boff, const int* __restrict__ off,
                                     int* __restrict__ cursor, int* __restrict__ csr) {
    int b = blockIdx.x;
    int s = boff[b], t = boff[b + 1];
    for (int i = s + threadIdx.x; i < t; i += blockDim.x) {
        uint2 p = pairs[i];
        int d = (int)p.y;
        int pos = off[d] + atomicAdd(&cursor[d], 1);
        csr[pos] = (int)p.x;
    }
}

// ------------------------------------------------------- weight packs
__global__ void pack_w_kernel(const float* __restrict__ Wl, const float* __restrict__ Wr,
                              float* __restrict__ Wc, int COUT, int CIN) {
    int i = blockIdx.x * blockDim.x + threadIdx.x;
    int tot = COUT * 2 * CIN;
    if (i >= tot) return;
    int o = i / (2 * CIN), k = i % (2 * CIN);
    Wc[i] = (k < CIN) ? Wl[o * CIN + k] : Wr[o * CIN + (k - CIN)];
}

__global__ void pack_wsplit_kernel(const float* __restrict__ Wl, const float* __restrict__ Wr,
                                   short* __restrict__ Whi, short* __restrict__ Wlo,
                                   int COUT, int K, int CIN) {
    int i = blockIdx.x * blockDim.x + threadIdx.x;
    if (i >= COUT * K) return;
    int n = i / K, k = i % K;
    float v = (k < CIN) ? Wl[n * CIN + k] : Wr[n * CIN + (k - CIN)];
    short h, l;
    splitf(v, h, l);
    Whi[i] = h; Wlo[i] = l;
}

// ------------------------------------------------------- mean aggregation
template<int CIN>
__global__ void agg_kernel(const float* __restrict__ h, const int* __restrict__ off,
                           const int* __restrict__ csr, float* __restrict__ mean, int n_nodes) {
    int wave = blockIdx.x * (blockDim.x >> 6) + (threadIdx.x >> 6);
    int lane = threadIdx.x & 63;
    if (wave >= n_nodes) return;
    constexpr int R = (CIN + 63) / 64;
    float acc[R];
    #pragma unroll
    for (int r = 0; r < R; ++r) acc[r] = 0.f;
    int e0 = off[wave], e1 = off[wave + 1];
    for (int e = e0; e < e1; ++e) {
        int s = csr[e];
        const float* hp = h + (size_t)s * CIN;
        #pragma unroll
        for (int r = 0; r < R; ++r) {
            int c = lane + 64 * r;
            if (c < CIN) acc[r] += hp[c];
        }
    }
    float inv = (e1 > e0) ? 1.f / (float)(e1 - e0) : 0.f;
    float* mp = mean + (size_t)wave * CIN;
    #pragma unroll
    for (int r = 0; r < R; ++r) {
        int c = lane + 64 * r;
        if (c < CIN) mp[c] = acc[r] * inv;
    }
}

// 64 channels per wave; 16 lanes x float4; 4 edges in flight per wave
template<int CIN>
__global__ void agg_vec2_kernel(const float* __restrict__ h, const int* __restrict__ off,
                                const int* __restrict__ csr, float* __restrict__ mean,
                                int n_nodes) {
    constexpr int HALVES = CIN / 64;
    int wid = blockIdx.x * (blockDim.x >> 6) + (threadIdx.x >> 6);
    int lane = threadIdx.x & 63;
    if (wid >= n_nodes * HALVES) return;
    int node = (HALVES == 1) ? wid : (wid >> 1);
    int half = (HALVES == 1) ? 0 : (wid & 1);
    int slot = lane >> 4, cg = lane & 15;
    int e0 = off[node], cnt = off[node + 1] - e0;
    float4 acc = {0.f, 0.f, 0.f, 0.f};
    for (int i = slot; i < cnt; i += 4) {
        int s = csr[e0 + i];
        float4 v = *(const float4*)(h + (size_t)s * CIN + half * 64 + cg * 4);
        acc.x += v.x; acc.y += v.y; acc.z += v.z; acc.w += v.w;
    }
    #pragma unroll
    for (int o = 16; o < 64; o <<= 1) {
        acc.x += __shfl_xor(acc.x, o);
        acc.y += __shfl_xor(acc.y, o);
        acc.z += __shfl_xor(acc.z, o);
        acc.w += __shfl_xor(acc.w, o);
    }
    if (slot == 0) {
        float inv = (cnt > 0) ? 1.f / (float)cnt : 0.f;
        float4 r = {acc.x * inv, acc.y * inv, acc.z * inv, acc.w * inv};
        *(float4*)(mean + (size_t)node * CIN + half * 64 + cg * 4) = r;
    }
}

// ------------------------------------------------------------ f32 cat-GEMM (small)
#define BM 128
#define BN 64
#define BK 16

template<bool RELU>
__global__ __launch_bounds__(256) void gemm_cat_kernel(
        const float* __restrict__ AL, const float* __restrict__ AR,
        const float* __restrict__ W, const float* __restrict__ bias,
        float* __restrict__ C, int M, int N, int K, int CIN) {
    __shared__ float As[BK][BM + 4];
    __shared__ float Bs[BK][BN + 4];
    const int row0 = blockIdx.x * BM;
    const int col0 = blockIdx.y * BN;
    const int tid = threadIdx.x;
    const int ttm = tid & 15, ttn = tid >> 4;

    float acc[8][4];
    #pragma unroll
    for (int i = 0; i < 8; ++i)
        #pragma unroll
        for (int j = 0; j < 4; ++j) acc[i][j] = 0.f;

    for (int k0 = 0; k0 < K; k0 += BK) {
        for (int i = tid; i < BM * BK; i += 256) {
            int m = i >> 4, k = i & 15;
            int r = row0 + m, kk = k0 + k;
            float v = 0.f;
            if (r < M && kk < K)
                v = (kk < CIN) ? AL[(size_t)r * CIN + kk]
                               : AR[(size_t)r * CIN + (kk - CIN)];
            As[k][m] = v;
        }
        for (int i = tid; i < BN * BK; i += 256) {
            int n = i >> 4, k = i & 15;
            int c = col0 + n, kk = k0 + k;
            Bs[k][n] = (c < N && kk < K) ? W[(size_t)c * K + kk] : 0.f;
        }
        __syncthreads();
        #pragma unroll
        for (int k = 0; k < BK; ++k) {
            float4 a0 = *(const float4*)&As[k][ttm * 8];
            float4 a1 = *(const float4*)&As[k][ttm * 8 + 4];
            float4 b0 = *(const float4*)&Bs[k][ttn * 4];
            float av[8] = {a0.x, a0.y, a0.z, a0.w, a1.x, a1.y, a1.z, a1.w};
            float bv[4] = {b0.x, b0.y, b0.z, b0.w};
            #pragma unroll
            for (int i = 0; i < 8; ++i)
                #pragma unroll
                for (int j = 0; j < 4; ++j)
                    acc[i][j] += av[i] * bv[j];
        }
        __syncthreads();
    }

    float bv[4];
    #pragma unroll
    for (int j = 0; j < 4; ++j) bv[j] = bias[col0 + ttn * 4 + j];
    #pragma unroll
    for (int i = 0; i < 8; ++i) {
        int r = row0 + ttm * 8 + i;
        if (r < M) {
            float t0 = acc[i][0] + bv[0];
            float t1 = acc[i][1] + bv[1];
            float t2 = acc[i][2] + bv[2];
            float t3 = acc[i][3] + bv[3];
            if (RELU) {
                t0 = t0 > 0.f ? t0 : t0 * NEG_SLOPE;
                t1 = t1 > 0.f ? t1 : t1 * NEG_SLOPE;
                t2 = t2 > 0.f ? t2 : t2 * NEG_SLOPE;
                t3 = t3 > 0.f ? t3 : t3 * NEG_SLOPE;
            }
            float4 v; v.x = t0; v.y = t1; v.z = t2; v.w = t3;
            *(float4*)&C[(size_t)r * N + col0 + ttn * 4] = v;
        }
    }
}

// ------------------------------------- split-bf16 MFMA cat-GEMM (N=128/block)
__global__ __launch_bounds__(256) void gemm_cat_mfma_kernel(
        const float* __restrict__ AL, const float* __restrict__ AR,
        const short* __restrict__ Whi, const short* __restrict__ Wlo,
        const float* __restrict__ bias, float* __restrict__ C,
        int M, int N, int K, int CIN) {
    __shared__ short AsH[128][40], AsL[128][40];
    __shared__ short BsH[128][40], BsL[128][40];
    const int row0 = blockIdx.x * 128;
    const int n0 = blockIdx.y * 128;
    const int tid = threadIdx.x;
    const int w = tid >> 6;
    const int lane31 = tid & 31, lhalf = (tid & 63) >> 5;

    f32x16 acc[4];
    #pragma unroll
    for (int ci = 0; ci < 4; ++ci)
        #pragma unroll
        for (int r = 0; r < 16; ++r) acc[ci][r] = 0.f;

    for (int k0 = 0; k0 < K; k0 += 32) {
        const float* Asrc = (k0 < CIN) ? AL : AR;
        const int kb = (k0 < CIN) ? k0 : k0 - CIN;
        {
            int row = tid >> 1, kq = (tid & 1) * 16;
            int r = row0 + row;
            float vv[16];
            #pragma unroll
            for (int i = 0; i < 16; ++i) vv[i] = 0.f;
            if (r < M) {
                const float* p = &Asrc[(size_t)r * CIN + kb + kq];
                #pragma unroll
                for (int q = 0; q < 4; ++q) {
                    float4 v = ((const float4*)p)[q];
                    vv[q * 4 + 0] = v.x; vv[q * 4 + 1] = v.y;
                    vv[q * 4 + 2] = v.z; vv[q * 4 + 3] = v.w;
                }
            }
            #pragma unroll
            for (int half = 0; half < 2; ++half) {
                bh8 h8, l8;
                #pragma unroll
                for (int i = 0; i < 8; ++i) {
                    short a, b;
                    splitf(vv[half * 8 + i], a, b);
                    h8[i] = a; l8[i] = b;
                }
                *(bh8*)&AsH[row][kq + half * 8] = h8;
                *(bh8*)&AsL[row][kq + half * 8] = l8;
            }
        }
        {
            int n = tid & 127, half = tid >> 7;
            const short* src = half ? Wlo : Whi;
            const uint4* p = (const uint4*)&src[(size_t)(n0 + n) * K + k0];
            if (half) {
                #pragma unroll
                for (int q = 0; q < 4; ++q) *(uint4*)&BsL[n][q * 8] = p[q];
            } else {
                #pragma unroll
                for (int q = 0; q < 4; ++q) *(uint4*)&BsH[n][q * 8] = p[q];
            }
        }
        __syncthreads();
        #pragma unroll
        for (int ks = 0; ks < 2; ++ks) {
            int kofs = ks * 16 + lhalf * 8;
            bh8 aH = *(bh8*)&AsH[w * 32 + lane31][kofs];
            bh8 aL = *(bh8*)&AsL[w * 32 + lane31][kofs];
            #pragma unroll
            for (int ci = 0; ci < 4; ++ci) {
                bh8 bH = *(bh8*)&BsH[ci * 32 + lane31][kofs];
                bh8 bL = *(bh8*)&BsL[ci * 32 + lane31][kofs];
                acc[ci] = __builtin_amdgcn_mfma_f32_32x32x16_bf16(aH, bH, acc[ci], 0, 0, 0);
                acc[ci] = __builtin_amdgcn_mfma_f32_32x32x16_bf16(aH, bL, acc[ci], 0, 0, 0);
                acc[ci] = __builtin_amdgcn_mfma_f32_32x32x16_bf16(aL, bH, acc[ci], 0, 0, 0);
            }
        }
        __syncthreads();
    }

    #pragma unroll
    for (int ci = 0; ci < 4; ++ci) {
        int col = n0 + ci * 32 + lane31;
        float b = bias[col];
        #pragma unroll
        for (int r = 0; r < 16; ++r) {
            int row = row0 + w * 32 + (r & 3) + 8 * (r >> 2) + 4 * lhalf;
            if (row < M) {
                float v = acc[ci][r] + b;
                v = v > 0.f ? v : v * NEG_SLOPE;
                C[(size_t)row * N + col] = v;
            }
        }
    }
}

// ---------------------- split-bf16 MFMA fused layer-3 GEMM + mean/max pool
__global__ __launch_bounds__(256) void gemm_pool_mfma_kernel(
        const float* __restrict__ AL, const float* __restrict__ AR,
        const short* __restrict__ Whi, const short* __restrict__ Wlo,
        const float* __restrict__ bias, float* __restrict__ gout,
        int npg, int CIN, int NCH) {
    __shared__ short AsH[64][40], AsL[64][40];
    __shared__ short BsH[256][40], BsL[256][40];
    __shared__ float redS[2][256], redM[2][256];
    const int g = blockIdx.x;
    const int K = 2 * CIN;
    const int tid = threadIdx.x;
    const int w = tid >> 6;
    const int lane31 = tid & 31, lhalf = (tid & 63) >> 5;
    const int rt = w & 1, ctbase = (w >> 1) * 4;

    f32x16 acc[4];
    #pragma unroll
    for (int ci = 0; ci < 4; ++ci)
        #pragma unroll
        for (int r = 0; r < 16; ++r) acc[ci][r] = 0.f;

    for (int k0 = 0; k0 < K; k0 += 32) {
        const float* Asrc = (k0 < CIN) ? AL : AR;
        const int kb = (k0 < CIN) ? k0 : k0 - CIN;
        {
            int row = tid >> 2, kq = (tid & 3) * 8;
            float vv[8];
            #pragma unroll
            for (int i = 0; i < 8; ++i) vv[i] = 0.f;
            if (row < npg) {
                const float* p = &Asrc[((size_t)g * npg + row) * CIN + kb + kq];
                #pragma unroll
                for (int q = 0; q < 2; ++q) {
                    float4 v = ((const float4*)p)[q];
                    vv[q * 4 + 0] = v.x; vv[q * 4 + 1] = v.y;
                    vv[q * 4 + 2] = v.z; vv[q * 4 + 3] = v.w;
                }
            }
            bh8 h8, l8;
            #pragma unroll
            for (int i = 0; i < 8; ++i) {
                short a, b;
                splitf(vv[i], a, b);
                h8[i] = a; l8[i] = b;
            }
            *(bh8*)&AsH[row][kq] = h8;
            *(bh8*)&AsL[row][kq] = l8;
        }
        {
            int n = tid;
            const uint4* ph = (const uint4*)&Whi[(size_t)n * K + k0];
            const uint4* pl = (const uint4*)&Wlo[(size_t)n * K + k0];
            #pragma unroll
            for (int q = 0; q < 4; ++q) {
                *(uint4*)&BsH[n][q * 8] = ph[q];
                *(uint4*)&BsL[n][q * 8] = pl[q];
            }
        }
        __syncthreads();
        #pragma unroll
        for (int ks = 0; ks < 2; ++ks) {
            int kofs = ks * 16 + lhalf * 8;
            bh8 aH = *(bh8*)&AsH[rt * 32 + lane31][kofs];
            bh8 aL = *(bh8*)&AsL[rt * 32 + lane31][kofs];
            #pragma unroll
            for (int ci = 0; ci < 4; ++ci) {
                bh8 bH = *(bh8*)&BsH[(ctbase + ci) * 32 + lane31][kofs];
                bh8 bL = *(bh8*)&BsL[(ctbase + ci) * 32 + lane31][kofs];
                acc[ci] = __builtin_amdgcn_mfma_f32_32x32x16_bf16(aH, bH, acc[ci], 0, 0, 0);
                acc[ci] = __builtin_amdgcn_mfma_f32_32x32x16_bf16(aH, bL, acc[ci], 0, 0, 0);
                acc[ci] = __builtin_amdgcn_mfma_f32_32x32x16_bf16(aL, bH, acc[ci], 0, 0, 0);
            }
        }
        __syncthreads();
    }

    #pragma unroll
    for (int ci = 0; ci < 4; ++ci) {
        int col = (ctbase + ci) * 32 + lane31;
        float b = bias[col];
        float ls = 0.f, lm = -__builtin_huge_valf();
        #pragma unroll
        for (int r = 0; r < 16; ++r) {
            int row = rt * 32 + (r & 3) + 8 * (r >> 2) + 4 * lhalf;
            if (row < npg) {
                float v = acc[ci][r] + b;
                v = v > 0.f ? v : v * NEG_SLOPE;
                ls += v;
                lm = fmaxf(lm, v);
            }
        }
        ls += __shfl_xor(ls, 32);
        lm = fmaxf(lm, __shfl_xor(lm, 32));
        if (lhalf == 0) { redS[rt][col] = ls; redM[rt][col] = lm; }
    }
    __syncthreads();
    {
        int c = tid;
        float s = redS[0][c] + redS[1][c];
        float m = fmaxf(redM[0][c], redM[1][c]);
        gout[(size_t)g * (2 * NCH) + c] = s / (float)npg;
        gout[(size_t)g * (2 * NCH) + NCH + c] = m;
    }
}

// ------------------------------------------------------- final 64->1 layer
__global__ void final_kernel(const float* __restrict__ c2, const float* __restrict__ Wc3,
                             const float* __restrict__ bc3, float* __restrict__ out, int G) {
    int g = blockIdx.x * (blockDim.x >> 6) + (threadIdx.x >> 6);
    int lane = threadIdx.x & 63;
    if (g >= G) return;
    float v = c2[(size_t)g * 64 + lane] * Wc3[lane];
    #pragma unroll
    for (int o = 32; o > 0; o >>= 1) v += __shfl_down(v, o);
    if (lane == 0) out[g] = v + bc3[0];
}

// ---------------------------------------------------------------- launcher
extern "C" void kernel_launch(void* const* d_in, const int* in_sizes, int n_in,
                              void* d_out, int out_size, void* d_ws, size_t ws_size,
                              hipStream_t stream) {
    const float* x   = (const float*)d_in[0];
    const int* ei    = (const int*)d_in[1];
    const float* W1l = (const float*)d_in[4];
    const float* b1  = (const float*)d_in[5];
    const float* W1r = (const float*)d_in[6];
    const float* W2l = (const float*)d_in[7];
    const float* b2  = (const float*)d_in[8];
    const float* W2r = (const float*)d_in[9];
    const float* W3l = (const float*)d_in[10];
    const float* b3  = (const float*)d_in[11];
    const float* W3r = (const float*)d_in[12];
    const float* Wc1 = (const float*)d_in[13];
    const float* bc1 = (const float*)d_in[14];
    const float* Wc2 = (const float*)d_in[15];
    const float* bc2 = (const float*)d_in[16];
    const float* Wc3 = (const float*)d_in[17];
    const float* bc3 = (const float*)d_in[18];
    float* out = (float*)d_out;

    const int nodes = in_sizes[0] / 5;      // 100000
    const int ne    = in_sizes[1] / 2;      // 1600000
    const int G     = out_size;             // 2000
    const int npg   = nodes / G;            // 50
    const int nb    = (nodes + 511) >> 9;   // 196 buckets (<=256)

    char* ws = (char*)d_ws;
    size_t pos = 0;
    auto take = [&](size_t bytes) -> char* {
        char* p = ws + pos;
        pos += (bytes + 255) & ~(size_t)255;
        return p;
    };
    int* deg     = (int*)take((size_t)nodes * 4);
    int* cursor  = (int*)take((size_t)nodes * 4);
    int* off     = (int*)take((size_t)(nodes + 1) * 4);
    int* csr     = (int*)take((size_t)ne * 4);
    int* bcnt    = (int*)take(256 * 4);
    int* boff    = (int*)take(257 * 4);
    int* bcur    = (int*)take(256 * 4);
    float* Wcat1 = (float*)take((size_t)64 * 10 * 4);
    short* Whi2  = (short*)take((size_t)128 * 128 * 2);
    short* Wlo2  = (short*)take((size_t)128 * 128 * 2);
    short* Whi3  = (short*)take((size_t)256 * 256 * 2);
    short* Wlo3  = (short*)take((size_t)256 * 256 * 2);
    short* WhiC  = (short*)take((size_t)128 * 512 * 2);
    short* WloC  = (short*)take((size_t)128 * 512 * 2);
    float* gbuf  = (float*)take((size_t)G * 512 * 4);
    float* c1    = (float*)take((size_t)G * 128 * 4);
    float* c2    = (float*)take((size_t)G * 64 * 4);
    // reused region: [meanx | mean1 | h1] -> pairs during CSR build, mean2 later
    float* meanx = (float*)take((size_t)nodes * 5 * 4);
    float* mean1 = (float*)take((size_t)nodes * 64 * 4);
    float* h1    = (float*)take((size_t)nodes * 64 * 4);
    float* h2    = (float*)take((size_t)nodes * 128 * 4);
    float* mean2 = meanx;
    uint2* pairs = (uint2*)meanx;   // 12.8MB, dead before meanx written

    if (pos > ws_size) {
        sentinel_kernel<<<(G + 255) / 256, 256, 0, stream>>>(out, G);
        return;
    }

    const int* src = ei;
    const int* dst = ei + ne;

    hipMemsetAsync(deg, 0, (size_t)nodes * 4, stream);
    hipMemsetAsync(cursor, 0, (size_t)nodes * 4, stream);
    hipMemsetAsync(bcnt, 0, 256 * 4, stream);
    hipMemsetAsync(bcur, 0, 256 * 4, stream);

    // ---- CSR build, bucketed
    bucket_hist_kernel<<<(ne + HIST_CH - 1) / HIST_CH, 256, 0, stream>>>(dst, deg, bcnt, ne, nb);
    scan_kernel<<<1, 1024, 0, stream>>>(deg, off, nodes);
    scan_kernel<<<1, 1024, 0, stream>>>(bcnt, boff, nb);
    bucket_scatter_kernel<<<(ne + SCAT_CH - 1) / SCAT_CH, 256, 0, stream>>>(
        src, dst, boff, bcur, pairs, ne, nb);
    final_scatter_kernel<<<nb, 512, 0, stream>>>(pairs, boff, off, cursor, csr);

    pack_w_kernel<<<(64 * 10 + 255) / 256, 256, 0, stream>>>(W1l, W1r, Wcat1, 64, 5);
    pack_wsplit_kernel<<<(128 * 128 + 255) / 256, 256, 0, stream>>>(W2l, W2r, Whi2, Wlo2, 128, 128, 64);
    pack_wsplit_kernel<<<(256 * 256 + 255) / 256, 256, 0, stream>>>(W3l, W3r, Whi3, Wlo3, 256, 256, 128);
    pack_wsplit_kernel<<<(128 * 512 + 255) / 256, 256, 0, stream>>>(Wc1, Wc1, WhiC, WloC, 128, 512, 512);

    int ab = (nodes + 3) / 4;

    // ---- layer 1: [mean(x)|x] (K=10) -> 64  (f32 path, tiny K)
    agg_kernel<5><<<ab, 256, 0, stream>>>(x, off, csr, meanx, nodes);
    {
        dim3 g((nodes + BM - 1) / BM, 64 / BN);
        gemm_cat_kernel<true><<<g, 256, 0, stream>>>(meanx, x, Wcat1, b1, h1, nodes, 64, 10, 5);
    }
    // ---- layer 2: [mean(h1)|h1] (K=128) -> 128  (split-bf16 MFMA)
    agg_vec2_kernel<64><<<ab, 256, 0, stream>>>(h1, off, csr, mean1, nodes);
    {
        dim3 g((nodes + 127) / 128, 1);
        gemm_cat_mfma_kernel<<<g, 256, 0, stream>>>(mean1, h1, Whi2, Wlo2, b2, h2,
                                                    nodes, 128, 128, 64);
    }
    // ---- layer 3: [mean(h2)|h2] (K=256) -> 256, fused pool (split-bf16 MFMA)
    agg_vec2_kernel<128><<<(nodes * 2 + 3) / 4, 256, 0, stream>>>(h2, off, csr, mean2, nodes);
    gemm_pool_mfma_kernel<<<G, 256, 0, stream>>>(mean2, h2, Whi3, Wlo3, b3, gbuf,
                                                 npg, 128, 256);
    // ---- classifier: 512 -> 128 (MFMA) -> 64 (f32) -> 1
    {
        dim3 g((G + 127) / 128, 1);
        gemm_cat_mfma_kernel<<<g, 256, 0, stream>>>(gbuf, gbuf, WhiC, WloC, bc1, c1,
                                                    G, 128, 512, 512);
    }
    {
        dim3 g((G + BM - 1) / BM, 64 / BN);
        gemm_cat_kernel<true><<<g, 256, 0, stream>>>(c1, nullptr, Wc2, bc2, c2, G, 64, 128, 128);
    }
    final_kernel<<<(G + 3) / 4, 256, 0, stream>>>(c2, Wc3, bc3, out, G);
}

// Round 6
// 660.257 us; speedup vs baseline: 1.8315x; 1.1126x over previous
//
#include <hip/hip_runtime.h>
#include <cstdint>
#include <cstddef>

#define NEG_SLOPE 0.2f

typedef __attribute__((ext_vector_type(8))) short bh8;     // 8 bf16 in 4 VGPRs
typedef __attribute__((ext_vector_type(16))) float f32x16; // MFMA 32x32 accumulator

// split f32 -> bf16 hi + bf16 lo (x ~= hi + lo, residual ~2^-17 relative)
__device__ inline void splitf(float x, short& hi, short& lo) {
    uint32_t u = __float_as_uint(x);
    uint32_t rh = (u + 0x7FFFu + ((u >> 16) & 1u)) & 0xFFFF0000u;
    hi = (short)(rh >> 16);
    float rem = x - __uint_as_float(rh);
    uint32_t u2 = __float_as_uint(rem);
    lo = (short)((u2 + 0x7FFFu + ((u2 >> 16) & 1u)) >> 16);
}

// ---------------------------------------------------------------- sentinel
__global__ void sentinel_kernel(float* __restrict__ out, int n) {
    int i = blockIdx.x * blockDim.x + threadIdx.x;
    if (i < n) out[i] = 12345.0f;
}

// ------------------------------------------------- CSR build (bucketed)
#define HIST_CH 8192
__global__ void bucket_hist_kernel(const int* __restrict__ dst, int* __restrict__ deg,
                                   int* __restrict__ bcnt, int ne, int nb) {
    __shared__ int hist[256];
    const int tid = threadIdx.x;
    hist[tid] = 0;
    __syncthreads();
    int e0 = blockIdx.x * HIST_CH;
    for (int i = tid; i < HIST_CH; i += 256) {
        int e = e0 + i;
        if (e < ne) {
            int d = dst[e];
            atomicAdd(&deg[d], 1);
            atomicAdd(&hist[d >> 9], 1);
        }
    }
    __syncthreads();
    if (tid < nb && hist[tid] > 0) atomicAdd(&bcnt[tid], hist[tid]);
}

__global__ void scan_kernel(const int* __restrict__ deg, int* __restrict__ off, int n) {
    __shared__ int wsum[16];
    __shared__ int carry_s;
    const int tid = threadIdx.x, lane = tid & 63, wid = tid >> 6;
    if (tid == 0) carry_s = 0;
    __syncthreads();
    for (int base = 0; base < n; base += 1024) {
        int i = base + tid;
        int v = (i < n) ? deg[i] : 0;
        int incl = v;
        #pragma unroll
        for (int o = 1; o < 64; o <<= 1) {
            int t = __shfl_up(incl, o);
            if (lane >= o) incl += t;
        }
        if (lane == 63) wsum[wid] = incl;
        __syncthreads();
        if (tid < 16) {
            int wv = wsum[tid];
            int winc = wv;
            #pragma unroll
            for (int o = 1; o < 16; o <<= 1) {
                int t = __shfl_up(winc, o);
                if (tid >= o) winc += t;
            }
            wsum[tid] = winc - wv;
        }
        __syncthreads();
        int carry = carry_s;
        int excl = carry + wsum[wid] + incl - v;
        if (i < n) off[i] = excl;
        __syncthreads();
        if (tid == 1023) carry_s = excl + v;
        __syncthreads();
    }
    if (threadIdx.x == 0) off[n] = carry_s;
}

#define SCAT_CH 4096
__global__ void bucket_scatter_kernel(const int* __restrict__ src, const int* __restrict__ dst,
                                      const int* __restrict__ boff, int* __restrict__ bcur,
                                      uint2* __restrict__ pairs, int ne, int nb) {
    __shared__ int hist[256], lcur[256], gbase[256];
    const int tid = threadIdx.x;
    hist[tid] = 0; lcur[tid] = 0;
    __syncthreads();
    int e0 = blockIdx.x * SCAT_CH;
    for (int i = tid; i < SCAT_CH; i += 256) {
        int e = e0 + i;
        if (e < ne) atomicAdd(&hist[dst[e] >> 9], 1);
    }
    __syncthreads();
    if (tid < nb) {
        int h = hist[tid];
        gbase[tid] = (h > 0) ? (boff[tid] + atomicAdd(&bcur[tid], h)) : 0;
    }
    __syncthreads();
    for (int i = tid; i < SCAT_CH; i += 256) {
        int e = e0 + i;
        if (e < ne) {
            int d = dst[e];
            int b = d >> 9;
            int r = atomicAdd(&lcur[b], 1);
            uint2 p; p.x = (unsigned)src[e]; p.y = (unsigned)d;
            pairs[gbase[b] + r] = p;
        }
    }
}

__global__ void final_scatter_kernel(const uint2* __restrict__ pairs,
                                     const int* __restrict__ boff, const int* __restrict__ off,
                                     int* __restrict__ cursor, int* __restrict__ csr) {
    int b = blockIdx.x;
    int s = boff[b], t = boff[b + 1];
    for (int i = s + threadIdx.x; i < t; i += blockDim.x) {
        uint2 p = pairs[i];
        int d = (int)p.y;
        int pos = off[d] + atomicAdd(&cursor[d], 1);
        csr[pos] = (int)p.x;
    }
}

// ------------------------------------------------------- weight packs
__global__ void pack_w_kernel(const float* __restrict__ Wl, const float* __restrict__ Wr,
                              float* __restrict__ Wc, int COUT, int CIN) {
    int i = blockIdx.x * blockDim.x + threadIdx.x;
    int tot = COUT * 2 * CIN;
    if (i >= tot) return;
    int o = i / (2 * CIN), k = i % (2 * CIN);
    Wc[i] = (k < CIN) ? Wl[o * CIN + k] : Wr[o * CIN + (k - CIN)];
}

__global__ void pack_wsplit_kernel(const float* __restrict__ Wl, const float* __restrict__ Wr,
                                   short* __restrict__ Whi, short* __restrict__ Wlo,
                                   int COUT, int K, int CIN) {
    int i = blockIdx.x * blockDim.x + threadIdx.x;
    if (i >= COUT * K) return;
    int n = i / K, k = i % K;
    float v = (k < CIN) ? Wl[n * CIN + k] : Wr[n * CIN + (k - CIN)];
    short h, l;
    splitf(v, h, l);
    Whi[i] = h; Wlo[i] = l;
}

// ------------------------------------------------------- mean aggregation
// CIN=5: one node/wave, 8 slots x 8 lanes (5 active), unroll x2 -> 16 edges in flight
__global__ void agg5_kernel(const float* __restrict__ x, const int* __restrict__ off,
                            const int* __restrict__ csr, float* __restrict__ mean, int n_nodes) {
    int node = blockIdx.x * (blockDim.x >> 6) + (threadIdx.x >> 6);
    int lane = threadIdx.x & 63;
    if (node >= n_nodes) return;
    int slot = lane >> 3, cg = lane & 7;
    int e0 = off[node], cnt = off[node + 1] - e0;
    float a0 = 0.f, a1 = 0.f;
    int i = slot;
    for (; i + 8 < cnt; i += 16) {
        int s0 = csr[e0 + i];
        int s1 = csr[e0 + i + 8];
        float v0 = (cg < 5) ? x[(size_t)s0 * 5 + cg] : 0.f;
        float v1 = (cg < 5) ? x[(size_t)s1 * 5 + cg] : 0.f;
        a0 += v0; a1 += v1;
    }
    for (; i < cnt; i += 8) {
        int s = csr[e0 + i];
        a0 += (cg < 5) ? x[(size_t)s * 5 + cg] : 0.f;
    }
    float acc = a0 + a1;
    #pragma unroll
    for (int o = 8; o < 64; o <<= 1) acc += __shfl_xor(acc, o);
    if (slot == 0 && cg < 5) {
        float inv = (cnt > 0) ? 1.f / (float)cnt : 0.f;
        mean[(size_t)node * 5 + cg] = acc * inv;
    }
}

// CIN=64/128: 64 ch per wave (16 lanes x float4), 4 slots, unroll x4
// -> 16 independent gathers in flight per wave
template<int CIN>
__global__ void agg_vec3_kernel(const float* __restrict__ h, const int* __restrict__ off,
                                const int* __restrict__ csr, float* __restrict__ mean,
                                int n_nodes) {
    constexpr int HALVES = CIN / 64;
    int wid = blockIdx.x * (blockDim.x >> 6) + (threadIdx.x >> 6);
    int lane = threadIdx.x & 63;
    if (wid >= n_nodes * HALVES) return;
    int node = (HALVES == 1) ? wid : (wid >> 1);
    int half = (HALVES == 1) ? 0 : (wid & 1);
    int slot = lane >> 4, cg = lane & 15;
    int e0 = off[node], cnt = off[node + 1] - e0;
    const float* hb = h + (size_t)half * 64 + cg * 4;
    float4 a0 = {0.f,0.f,0.f,0.f}, a1 = {0.f,0.f,0.f,0.f};
    float4 a2 = {0.f,0.f,0.f,0.f}, a3 = {0.f,0.f,0.f,0.f};
    int i = slot;
    for (; i + 12 < cnt; i += 16) {
        int s0 = csr[e0 + i];
        int s1 = csr[e0 + i + 4];
        int s2 = csr[e0 + i + 8];
        int s3 = csr[e0 + i + 12];
        float4 v0 = *(const float4*)(hb + (size_t)s0 * CIN);
        float4 v1 = *(const float4*)(hb + (size_t)s1 * CIN);
        float4 v2 = *(const float4*)(hb + (size_t)s2 * CIN);
        float4 v3 = *(const float4*)(hb + (size_t)s3 * CIN);
        a0.x += v0.x; a0.y += v0.y; a0.z += v0.z; a0.w += v0.w;
        a1.x += v1.x; a1.y += v1.y; a1.z += v1.z; a1.w += v1.w;
        a2.x += v2.x; a2.y += v2.y; a2.z += v2.z; a2.w += v2.w;
        a3.x += v3.x; a3.y += v3.y; a3.z += v3.z; a3.w += v3.w;
    }
    for (; i < cnt; i += 4) {
        int s = csr[e0 + i];
        float4 v = *(const float4*)(hb + (size_t)s * CIN);
        a0.x += v.x; a0.y += v.y; a0.z += v.z; a0.w += v.w;
    }
    float4 acc;
    acc.x = (a0.x + a1.x) + (a2.x + a3.x);
    acc.y = (a0.y + a1.y) + (a2.y + a3.y);
    acc.z = (a0.z + a1.z) + (a2.z + a3.z);
    acc.w = (a0.w + a1.w) + (a2.w + a3.w);
    #pragma unroll
    for (int o = 16; o < 64; o <<= 1) {
        acc.x += __shfl_xor(acc.x, o);
        acc.y += __shfl_xor(acc.y, o);
        acc.z += __shfl_xor(acc.z, o);
        acc.w += __shfl_xor(acc.w, o);
    }
    if (slot == 0) {
        float inv = (cnt > 0) ? 1.f / (float)cnt : 0.f;
        float4 r = {acc.x * inv, acc.y * inv, acc.z * inv, acc.w * inv};
        *(float4*)(mean + (size_t)node * CIN + half * 64 + cg * 4) = r;
    }
}

// ------------------------------------------------------------ f32 cat-GEMM (small)
#define BM 128
#define BN 64
#define BK 16

template<bool RELU>
__global__ __launch_bounds__(256) void gemm_cat_kernel(
        const float* __restrict__ AL, const float* __restrict__ AR,
        const float* __restrict__ W, const float* __restrict__ bias,
        float* __restrict__ C, int M, int N, int K, int CIN) {
    __shared__ float As[BK][BM + 4];
    __shared__ float Bs[BK][BN + 4];
    const int row0 = blockIdx.x * BM;
    const int col0 = blockIdx.y * BN;
    const int tid = threadIdx.x;
    const int ttm = tid & 15, ttn = tid >> 4;

    float acc[8][4];
    #pragma unroll
    for (int i = 0; i < 8; ++i)
        #pragma unroll
        for (int j = 0; j < 4; ++j) acc[i][j] = 0.f;

    for (int k0 = 0; k0 < K; k0 += BK) {
        for (int i = tid; i < BM * BK; i += 256) {
            int m = i >> 4, k = i & 15;
            int r = row0 + m, kk = k0 + k;
            float v = 0.f;
            if (r < M && kk < K)
                v = (kk < CIN) ? AL[(size_t)r * CIN + kk]
                               : AR[(size_t)r * CIN + (kk - CIN)];
            As[k][m] = v;
        }
        for (int i = tid; i < BN * BK; i += 256) {
            int n = i >> 4, k = i & 15;
            int c = col0 + n, kk = k0 + k;
            Bs[k][n] = (c < N && kk < K) ? W[(size_t)c * K + kk] : 0.f;
        }
        __syncthreads();
        #pragma unroll
        for (int k = 0; k < BK; ++k) {
            float4 a0 = *(const float4*)&As[k][ttm * 8];
            float4 a1 = *(const float4*)&As[k][ttm * 8 + 4];
            float4 b0 = *(const float4*)&Bs[k][ttn * 4];
            float av[8] = {a0.x, a0.y, a0.z, a0.w, a1.x, a1.y, a1.z, a1.w};
            float bv[4] = {b0.x, b0.y, b0.z, b0.w};
            #pragma unroll
            for (int i = 0; i < 8; ++i)
                #pragma unroll
                for (int j = 0; j < 4; ++j)
                    acc[i][j] += av[i] * bv[j];
        }
        __syncthreads();
    }

    float bv[4];
    #pragma unroll
    for (int j = 0; j < 4; ++j) bv[j] = bias[col0 + ttn * 4 + j];
    #pragma unroll
    for (int i = 0; i < 8; ++i) {
        int r = row0 + ttm * 8 + i;
        if (r < M) {
            float t0 = acc[i][0] + bv[0];
            float t1 = acc[i][1] + bv[1];
            float t2 = acc[i][2] + bv[2];
            float t3 = acc[i][3] + bv[3];
            if (RELU) {
                t0 = t0 > 0.f ? t0 : t0 * NEG_SLOPE;
                t1 = t1 > 0.f ? t1 : t1 * NEG_SLOPE;
                t2 = t2 > 0.f ? t2 : t2 * NEG_SLOPE;
                t3 = t3 > 0.f ? t3 : t3 * NEG_SLOPE;
            }
            float4 v; v.x = t0; v.y = t1; v.z = t2; v.w = t3;
            *(float4*)&C[(size_t)r * N + col0 + ttn * 4] = v;
        }
    }
}

// ------------------------------------- split-bf16 MFMA cat-GEMM (N=128/block)
__global__ __launch_bounds__(256) void gemm_cat_mfma_kernel(
        const float* __restrict__ AL, const float* __restrict__ AR,
        const short* __restrict__ Whi, const short* __restrict__ Wlo,
        const float* __restrict__ bias, float* __restrict__ C,
        int M, int N, int K, int CIN) {
    __shared__ short AsH[128][40], AsL[128][40];
    __shared__ short BsH[128][40], BsL[128][40];
    const int row0 = blockIdx.x * 128;
    const int n0 = blockIdx.y * 128;
    const int tid = threadIdx.x;
    const int w = tid >> 6;
    const int lane31 = tid & 31, lhalf = (tid & 63) >> 5;

    f32x16 acc[4];
    #pragma unroll
    for (int ci = 0; ci < 4; ++ci)
        #pragma unroll
        for (int r = 0; r < 16; ++r) acc[ci][r] = 0.f;

    for (int k0 = 0; k0 < K; k0 += 32) {
        const float* Asrc = (k0 < CIN) ? AL : AR;
        const int kb = (k0 < CIN) ? k0 : k0 - CIN;
        {
            int row = tid >> 1, kq = (tid & 1) * 16;
            int r = row0 + row;
            float vv[16];
            #pragma unroll
            for (int i = 0; i < 16; ++i) vv[i] = 0.f;
            if (r < M) {
                const float* p = &Asrc[(size_t)r * CIN + kb + kq];
                #pragma unroll
                for (int q = 0; q < 4; ++q) {
                    float4 v = ((const float4*)p)[q];
                    vv[q * 4 + 0] = v.x; vv[q * 4 + 1] = v.y;
                    vv[q * 4 + 2] = v.z; vv[q * 4 + 3] = v.w;
                }
            }
            #pragma unroll
            for (int half = 0; half < 2; ++half) {
                bh8 h8, l8;
                #pragma unroll
                for (int i = 0; i < 8; ++i) {
                    short a, b;
                    splitf(vv[half * 8 + i], a, b);
                    h8[i] = a; l8[i] = b;
                }
                *(bh8*)&AsH[row][kq + half * 8] = h8;
                *(bh8*)&AsL[row][kq + half * 8] = l8;
            }
        }
        {
            int n = tid & 127, half = tid >> 7;
            const short* src = half ? Wlo : Whi;
            const uint4* p = (const uint4*)&src[(size_t)(n0 + n) * K + k0];
            if (half) {
                #pragma unroll
                for (int q = 0; q < 4; ++q) *(uint4*)&BsL[n][q * 8] = p[q];
            } else {
                #pragma unroll
                for (int q = 0; q < 4; ++q) *(uint4*)&BsH[n][q * 8] = p[q];
            }
        }
        __syncthreads();
        #pragma unroll
        for (int ks = 0; ks < 2; ++ks) {
            int kofs = ks * 16 + lhalf * 8;
            bh8 aH = *(bh8*)&AsH[w * 32 + lane31][kofs];
            bh8 aL = *(bh8*)&AsL[w * 32 + lane31][kofs];
            #pragma unroll
            for (int ci = 0; ci < 4; ++ci) {
                bh8 bH = *(bh8*)&BsH[ci * 32 + lane31][kofs];
                bh8 bL = *(bh8*)&BsL[ci * 32 + lane31][kofs];
                acc[ci] = __builtin_amdgcn_mfma_f32_32x32x16_bf16(aH, bH, acc[ci], 0, 0, 0);
                acc[ci] = __builtin_amdgcn_mfma_f32_32x32x16_bf16(aH, bL, acc[ci], 0, 0, 0);
                acc[ci] = __builtin_amdgcn_mfma_f32_32x32x16_bf16(aL, bH, acc[ci], 0, 0, 0);
            }
        }
        __syncthreads();
    }

    #pragma unroll
    for (int ci = 0; ci < 4; ++ci) {
        int col = n0 + ci * 32 + lane31;
        float b = bias[col];
        #pragma unroll
        for (int r = 0; r < 16; ++r) {
            int row = row0 + w * 32 + (r & 3) + 8 * (r >> 2) + 4 * lhalf;
            if (row < M) {
                float v = acc[ci][r] + b;
                v = v > 0.f ? v : v * NEG_SLOPE;
                C[(size_t)row * N + col] = v;
            }
        }
    }
}

// ---------------------- split-bf16 MFMA fused layer-3 GEMM + mean/max pool
__global__ __launch_bounds__(256) void gemm_pool_mfma_kernel(
        const float* __restrict__ AL, const float* __restrict__ AR,
        const short* __restrict__ Whi, const short* __restrict__ Wlo,
        const float* __restrict__ bias, float* __restrict__ gout,
        int npg, int CIN, int NCH) {
    __shared__ short AsH[64][40], AsL[64][40];
    __shared__ short BsH[256][40], BsL[256][40];
    __shared__ float redS[2][256], redM[2][256];
    const int g = blockIdx.x;
    const int K = 2 * CIN;
    const int tid = threadIdx.x;
    const int w = tid >> 6;
    const int lane31 = tid & 31, lhalf = (tid & 63) >> 5;
    const int rt = w & 1, ctbase = (w >> 1) * 4;

    f32x16 acc[4];
    #pragma unroll
    for (int ci = 0; ci < 4; ++ci)
        #pragma unroll
        for (int r = 0; r < 16; ++r) acc[ci][r] = 0.f;

    for (int k0 = 0; k0 < K; k0 += 32) {
        const float* Asrc = (k0 < CIN) ? AL : AR;
        const int kb = (k0 < CIN) ? k0 : k0 - CIN;
        {
            int row = tid >> 2, kq = (tid & 3) * 8;
            float vv[8];
            #pragma unroll
            for (int i = 0; i < 8; ++i) vv[i] = 0.f;
            if (row < npg) {
                const float* p = &Asrc[((size_t)g * npg + row) * CIN + kb + kq];
                #pragma unroll
                for (int q = 0; q < 2; ++q) {
                    float4 v = ((const float4*)p)[q];
                    vv[q * 4 + 0] = v.x; vv[q * 4 + 1] = v.y;
                    vv[q * 4 + 2] = v.z; vv[q * 4 + 3] = v.w;
                }
            }
            bh8 h8, l8;
            #pragma unroll
            for (int i = 0; i < 8; ++i) {
                short a, b;
                splitf(vv[i], a, b);
                h8[i] = a; l8[i] = b;
            }
            *(bh8*)&AsH[row][kq] = h8;
            *(bh8*)&AsL[row][kq] = l8;
        }
        {
            int n = tid;
            const uint4* ph = (const uint4*)&Whi[(size_t)n * K + k0];
            const uint4* pl = (const uint4*)&Wlo[(size_t)n * K + k0];
            #pragma unroll
            for (int q = 0; q < 4; ++q) {
                *(uint4*)&BsH[n][q * 8] = ph[q];
                *(uint4*)&BsL[n][q * 8] = pl[q];
            }
        }
        __syncthreads();
        #pragma unroll
        for (int ks = 0; ks < 2; ++ks) {
            int kofs = ks * 16 + lhalf * 8;
            bh8 aH = *(bh8*)&AsH[rt * 32 + lane31][kofs];
            bh8 aL = *(bh8*)&AsL[rt * 32 + lane31][kofs];
            #pragma unroll
            for (int ci = 0; ci < 4; ++ci) {
                bh8 bH = *(bh8*)&BsH[(ctbase + ci) * 32 + lane31][kofs];
                bh8 bL = *(bh8*)&BsL[(ctbase + ci) * 32 + lane31][kofs];
                acc[ci] = __builtin_amdgcn_mfma_f32_32x32x16_bf16(aH, bH, acc[ci], 0, 0, 0);
                acc[ci] = __builtin_amdgcn_mfma_f32_32x32x16_bf16(aH, bL, acc[ci], 0, 0, 0);
                acc[ci] = __builtin_amdgcn_mfma_f32_32x32x16_bf16(aL, bH, acc[ci], 0, 0, 0);
            }
        }
        __syncthreads();
    }

    #pragma unroll
    for (int ci = 0; ci < 4; ++ci) {
        int col = (ctbase + ci) * 32 + lane31;
        float b = bias[col];
        float ls = 0.f, lm = -__builtin_huge_valf();
        #pragma unroll
        for (int r = 0; r < 16; ++r) {
            int row = rt * 32 + (r & 3) + 8 * (r >> 2) + 4 * lhalf;
            if (row < npg) {
                float v = acc[ci][r] + b;
                v = v > 0.f ? v : v * NEG_SLOPE;
                ls += v;
                lm = fmaxf(lm, v);
            }
        }
        ls += __shfl_xor(ls, 32);
        lm = fmaxf(lm, __shfl_xor(lm, 32));
        if (lhalf == 0) { redS[rt][col] = ls; redM[rt][col] = lm; }
    }
    __syncthreads();
    {
        int c = tid;
        float s = redS[0][c] + redS[1][c];
        float m = fmaxf(redM[0][c], redM[1][c]);
        gout[(size_t)g * (2 * NCH) + c] = s / (float)npg;
        gout[(size_t)g * (2 * NCH) + NCH + c] = m;
    }
}

// ------------------------------------------------------- final 64->1 layer
__global__ void final_kernel(const float* __restrict__ c2, const float* __restrict__ Wc3,
                             const float* __restrict__ bc3, float* __restrict__ out, int G) {
    int g = blockIdx.x * (blockDim.x >> 6) + (threadIdx.x >> 6);
    int lane = threadIdx.x & 63;
    if (g >= G) return;
    float v = c2[(size_t)g * 64 + lane] * Wc3[lane];
    #pragma unroll
    for (int o = 32; o > 0; o >>= 1) v += __shfl_down(v, o);
    if (lane == 0) out[g] = v + bc3[0];
}

// ---------------------------------------------------------------- launcher
extern "C" void kernel_launch(void* const* d_in, const int* in_sizes, int n_in,
                              void* d_out, int out_size, void* d_ws, size_t ws_size,
                              hipStream_t stream) {
    const float* x   = (const float*)d_in[0];
    const int* ei    = (const int*)d_in[1];
    const float* W1l = (const float*)d_in[4];
    const float* b1  = (const float*)d_in[5];
    const float* W1r = (const float*)d_in[6];
    const float* W2l = (const float*)d_in[7];
    const float* b2  = (const float*)d_in[8];
    const float* W2r = (const float*)d_in[9];
    const float* W3l = (const float*)d_in[10];
    const float* b3  = (const float*)d_in[11];
    const float* W3r = (const float*)d_in[12];
    const float* Wc1 = (const float*)d_in[13];
    const float* bc1 = (const float*)d_in[14];
    const float* Wc2 = (const float*)d_in[15];
    const float* bc2 = (const float*)d_in[16];
    const float* Wc3 = (const float*)d_in[17];
    const float* bc3 = (const float*)d_in[18];
    float* out = (float*)d_out;

    const int nodes = in_sizes[0] / 5;      // 100000
    const int ne    = in_sizes[1] / 2;      // 1600000
    const int G     = out_size;             // 2000
    const int npg   = nodes / G;            // 50
    const int nb    = (nodes + 511) >> 9;   // 196 buckets (<=256)

    char* ws = (char*)d_ws;
    size_t pos = 0;
    auto take = [&](size_t bytes) -> char* {
        char* p = ws + pos;
        pos += (bytes + 255) & ~(size_t)255;
        return p;
    };
    int* deg     = (int*)take((size_t)nodes * 4);
    int* cursor  = (int*)take((size_t)nodes * 4);
    int* off     = (int*)take((size_t)(nodes + 1) * 4);
    int* csr     = (int*)take((size_t)ne * 4);
    int* bcnt    = (int*)take(256 * 4);
    int* boff    = (int*)take(257 * 4);
    int* bcur    = (int*)take(256 * 4);
    float* Wcat1 = (float*)take((size_t)64 * 10 * 4);
    short* Whi2  = (short*)take((size_t)128 * 128 * 2);
    short* Wlo2  = (short*)take((size_t)128 * 128 * 2);
    short* Whi3  = (short*)take((size_t)256 * 256 * 2);
    short* Wlo3  = (short*)take((size_t)256 * 256 * 2);
    short* WhiC  = (short*)take((size_t)128 * 512 * 2);
    short* WloC  = (short*)take((size_t)128 * 512 * 2);
    float* gbuf  = (float*)take((size_t)G * 512 * 4);
    float* c1    = (float*)take((size_t)G * 128 * 4);
    float* c2    = (float*)take((size_t)G * 64 * 4);
    float* meanx = (float*)take((size_t)nodes * 5 * 4);
    float* mean1 = (float*)take((size_t)nodes * 64 * 4);
    float* h1    = (float*)take((size_t)nodes * 64 * 4);
    float* h2    = (float*)take((size_t)nodes * 128 * 4);
    float* mean2 = meanx;
    uint2* pairs = (uint2*)meanx;   // 12.8MB, dead before meanx written

    if (pos > ws_size) {
        sentinel_kernel<<<(G + 255) / 256, 256, 0, stream>>>(out, G);
        return;
    }

    const int* src = ei;
    const int* dst = ei + ne;

    hipMemsetAsync(deg, 0, (size_t)nodes * 4, stream);
    hipMemsetAsync(cursor, 0, (size_t)nodes * 4, stream);
    hipMemsetAsync(bcnt, 0, 256 * 4, stream);
    hipMemsetAsync(bcur, 0, 256 * 4, stream);

    // ---- CSR build, bucketed
    bucket_hist_kernel<<<(ne + HIST_CH - 1) / HIST_CH, 256, 0, stream>>>(dst, deg, bcnt, ne, nb);
    scan_kernel<<<1, 1024, 0, stream>>>(deg, off, nodes);
    scan_kernel<<<1, 1024, 0, stream>>>(bcnt, boff, nb);
    bucket_scatter_kernel<<<(ne + SCAT_CH - 1) / SCAT_CH, 256, 0, stream>>>(
        src, dst, boff, bcur, pairs, ne, nb);
    final_scatter_kernel<<<nb, 512, 0, stream>>>(pairs, boff, off, cursor, csr);

    pack_w_kernel<<<(64 * 10 + 255) / 256, 256, 0, stream>>>(W1l, W1r, Wcat1, 64, 5);
    pack_wsplit_kernel<<<(128 * 128 + 255) / 256, 256, 0, stream>>>(W2l, W2r, Whi2, Wlo2, 128, 128, 64);
    pack_wsplit_kernel<<<(256 * 256 + 255) / 256, 256, 0, stream>>>(W3l, W3r, Whi3, Wlo3, 256, 256, 128);
    pack_wsplit_kernel<<<(128 * 512 + 255) / 256, 256, 0, stream>>>(Wc1, Wc1, WhiC, WloC, 128, 512, 512);

    int ab = (nodes + 3) / 4;

    // ---- layer 1: [mean(x)|x] (K=10) -> 64  (f32 path, tiny K)
    agg5_kernel<<<ab, 256, 0, stream>>>(x, off, csr, meanx, nodes);
    {
        dim3 g((nodes + BM - 1) / BM, 64 / BN);
        gemm_cat_kernel<true><<<g, 256, 0, stream>>>(meanx, x, Wcat1, b1, h1, nodes, 64, 10, 5);
    }
    // ---- layer 2: [mean(h1)|h1] (K=128) -> 128  (split-bf16 MFMA)
    agg_vec3_kernel<64><<<ab, 256, 0, stream>>>(h1, off, csr, mean1, nodes);
    {
        dim3 g((nodes + 127) / 128, 1);
        gemm_cat_mfma_kernel<<<g, 256, 0, stream>>>(mean1, h1, Whi2, Wlo2, b2, h2,
                                                    nodes, 128, 128, 64);
    }
    // ---- layer 3: [mean(h2)|h2] (K=256) -> 256, fused pool (split-bf16 MFMA)
    agg_vec3_kernel<128><<<(nodes * 2 + 3) / 4, 256, 0, stream>>>(h2, off, csr, mean2, nodes);
    gemm_pool_mfma_kernel<<<G, 256, 0, stream>>>(mean2, h2, Whi3, Wlo3, b3, gbuf,
                                                 npg, 128, 256);
    // ---- classifier: 512 -> 128 (MFMA) -> 64 (f32) -> 1
    {
        dim3 g((G + 127) / 128, 1);
        gemm_cat_mfma_kernel<<<g, 256, 0, stream>>>(gbuf, gbuf, WhiC, WloC, bc1, c1,
                                                    G, 128, 512, 512);
    }
    {
        dim3 g((G + BM - 1) / BM, 64 / BN);
        gemm_cat_kernel<true><<<g, 256, 0, stream>>>(c1, nullptr, Wc2, bc2, c2, G, 64, 128, 128);
    }
    final_kernel<<<(G + 3) / 4, 256, 0, stream>>>(c2, Wc3, bc3, out, G);
}

// Round 8
// 528.302 us; speedup vs baseline: 2.2889x; 1.2498x over previous
//
#include <hip/hip_runtime.h>
#include <cstdint>
#include <cstddef>

#define NEG_SLOPE 0.2f

typedef __attribute__((ext_vector_type(8))) short bh8;     // 8 bf16 in 4 VGPRs
typedef __attribute__((ext_vector_type(16))) float f32x16; // MFMA 32x32 accumulator

// split f32 -> bf16 hi + bf16 lo (x ~= hi + lo, residual ~2^-17 relative)
__device__ inline void splitf(float x, short& hi, short& lo) {
    uint32_t u = __float_as_uint(x);
    uint32_t rh = (u + 0x7FFFu + ((u >> 16) & 1u)) & 0xFFFF0000u;
    hi = (short)(rh >> 16);
    float rem = x - __uint_as_float(rh);
    uint32_t u2 = __float_as_uint(rem);
    lo = (short)((u2 + 0x7FFFu + ((u2 >> 16) & 1u)) >> 16);
}

// ---------------------------------------------------------------- sentinel
__global__ void sentinel_kernel(float* __restrict__ out, int n) {
    int i = blockIdx.x * blockDim.x + threadIdx.x;
    if (i < n) out[i] = 12345.0f;
}

// ------------------------------------------------- CSR build v3 (bucketed)
// bucket = dst >> 9 (512 nodes); pair = (dst&511)<<17 | src  (needs nodes<2^17)
#define HIST_CH 8192
__global__ void bucket_count_kernel(const int* __restrict__ dst, int* __restrict__ bcnt,
                                    int ne, int nb) {
    __shared__ int hist[256];
    const int tid = threadIdx.x;
    hist[tid] = 0;
    __syncthreads();
    int e0 = blockIdx.x * HIST_CH;
    for (int i = tid; i < HIST_CH; i += 256) {
        int e = e0 + i;
        if (e < ne) atomicAdd(&hist[dst[e] >> 9], 1);
    }
    __syncthreads();
    if (tid < nb && hist[tid] > 0) atomicAdd(&bcnt[tid], hist[tid]);
}

// scan over <=256 bucket counts; boff[0..n], boff[n]=total
__global__ void scan256_kernel(const int* __restrict__ bcnt, int* __restrict__ boff, int n) {
    const int tid = threadIdx.x, lane = tid & 63, wid = tid >> 6;
    __shared__ int wt[4];
    int v = (tid < n) ? bcnt[tid] : 0;
    int incl = v;
    #pragma unroll
    for (int o = 1; o < 64; o <<= 1) {
        int t = __shfl_up(incl, o);
        if (lane >= o) incl += t;
    }
    if (lane == 63) wt[wid] = incl;
    __syncthreads();
    if (tid < 4) {
        int w = wt[tid], winc = w;
        #pragma unroll
        for (int o = 1; o < 4; o <<= 1) {
            int t = __shfl_up(winc, o);
            if (tid >= o) winc += t;
        }
        wt[tid] = winc - w;
    }
    __syncthreads();
    int excl = wt[wid] + incl - v;
    if (tid < n) boff[tid] = excl;
    if (tid == n - 1) boff[n] = excl + v;
}

#define SCAT_CH 4096
__global__ void bucket_scatter_kernel(const int* __restrict__ src, const int* __restrict__ dst,
                                      const int* __restrict__ boff, int* __restrict__ bcur,
                                      unsigned* __restrict__ pairs, int ne, int nb) {
    __shared__ int hist[256], lcur[256], gbase[256];
    const int tid = threadIdx.x;
    hist[tid] = 0; lcur[tid] = 0;
    __syncthreads();
    int e0 = blockIdx.x * SCAT_CH;
    for (int i = tid; i < SCAT_CH; i += 256) {
        int e = e0 + i;
        if (e < ne) atomicAdd(&hist[dst[e] >> 9], 1);
    }
    __syncthreads();
    if (tid < nb) {
        int h = hist[tid];
        gbase[tid] = (h > 0) ? (boff[tid] + atomicAdd(&bcur[tid], h)) : 0;
    }
    __syncthreads();
    for (int i = tid; i < SCAT_CH; i += 256) {
        int e = e0 + i;
        if (e < ne) {
            int d = dst[e];
            int b = d >> 9;
            int r = atomicAdd(&lcur[b], 1);
            pairs[gbase[b] + r] = ((unsigned)(d & 511) << 17) | (unsigned)src[e];
        }
    }
}

// one block per bucket: LDS counting sort -> writes off[] and exact csr[]
__global__ __launch_bounds__(512) void bucket_sort_kernel(
        const unsigned* __restrict__ pairs, const int* __restrict__ boff,
        int* __restrict__ off, int* __restrict__ csr, int n_nodes) {
    __shared__ int cnt[512], lcur[512];
    __shared__ int wt[8];
    const int b = blockIdx.x;
    const int tid = threadIdx.x, lane = tid & 63, wid = tid >> 6;
    const int s = boff[b], t = boff[b + 1];
    cnt[tid] = 0; lcur[tid] = 0;
    __syncthreads();
    for (int i = s + tid; i < t; i += 512)
        atomicAdd(&cnt[pairs[i] >> 17], 1);
    __syncthreads();
    int v = cnt[tid];
    int incl = v;
    #pragma unroll
    for (int o = 1; o < 64; o <<= 1) {
        int tt = __shfl_up(incl, o);
        if (lane >= o) incl += tt;
    }
    if (lane == 63) wt[wid] = incl;
    __syncthreads();
    if (tid < 8) {
        int w = wt[tid], winc = w;
        #pragma unroll
        for (int o = 1; o < 8; o <<= 1) {
            int tt = __shfl_up(winc, o);
            if (tid >= o) winc += tt;
        }
        wt[tid] = winc - w;
    }
    __syncthreads();
    int excl = wt[wid] + incl - v;
    __syncthreads();
    cnt[tid] = excl;     // reuse as exclusive-offset table
    int node = b * 512 + tid;
    if (node < n_nodes) off[node] = s + excl;
    if (b == 0 && tid == 0) off[n_nodes] = boff[gridDim.x];   // = ne
    __syncthreads();
    for (int i = s + tid; i < t; i += 512) {
        unsigned p = pairs[i];
        int bin = p >> 17;
        int r = atomicAdd(&lcur[bin], 1);
        csr[s + cnt[bin] + r] = (int)(p & 0x1FFFFu);
    }
}

// ------------------------------------------------------- weight packs
__global__ void pack_wsplit_kernel(const float* __restrict__ Wl, const float* __restrict__ Wr,
                                   short* __restrict__ Whi, short* __restrict__ Wlo,
                                   int COUT, int K, int CIN) {
    int i = blockIdx.x * blockDim.x + threadIdx.x;
    if (i >= COUT * K) return;
    int n = i / K, k = i % K;
    float v = (k < CIN) ? Wl[n * CIN + k] : Wr[n * CIN + (k - CIN)];
    short h, l;
    splitf(v, h, l);
    Whi[i] = h; Wlo[i] = l;
}

// ---------------------------------- fused layer 1: gather-mean + 10-wide GEMM
// one wave per node; lanes: 8 slots x 8 ch-groups for gather, then lane=out col
__global__ __launch_bounds__(256) void sage1_kernel(
        const float* __restrict__ x, const int* __restrict__ off,
        const int* __restrict__ csr, const float* __restrict__ W1l,
        const float* __restrict__ W1r, const float* __restrict__ b1,
        float* __restrict__ h1, int n_nodes) {
    __shared__ float sWl[320], sWr[320], sb[64];
    const int tid = threadIdx.x;
    for (int i = tid; i < 320; i += 256) { sWl[i] = W1l[i]; sWr[i] = W1r[i]; }  // FIX: strided
    if (tid < 64) sb[tid] = b1[tid];
    __syncthreads();
    int node = blockIdx.x * 4 + (tid >> 6);
    int lane = tid & 63;
    if (node >= n_nodes) return;
    int slot = lane >> 3, cg = lane & 7;
    int e0 = off[node], cnt = off[node + 1] - e0;
    float a0 = 0.f, a1 = 0.f;
    int i = slot;
    for (; i + 8 < cnt; i += 16) {
        int s0 = csr[e0 + i];
        int s1 = csr[e0 + i + 8];
        a0 += (cg < 5) ? x[(size_t)s0 * 5 + cg] : 0.f;
        a1 += (cg < 5) ? x[(size_t)s1 * 5 + cg] : 0.f;
    }
    for (; i < cnt; i += 8) {
        int s = csr[e0 + i];
        a0 += (cg < 5) ? x[(size_t)s * 5 + cg] : 0.f;
    }
    float acc = a0 + a1;
    #pragma unroll
    for (int o = 8; o < 64; o <<= 1) acc += __shfl_xor(acc, o);
    float inv = (cnt > 0) ? 1.f / (float)cnt : 0.f;
    float m = acc * inv;                       // lane c<5 holds mean[c]
    float xv = (lane < 5) ? x[(size_t)node * 5 + lane] : 0.f;
    float o = sb[lane];
    #pragma unroll
    for (int c = 0; c < 5; ++c) {
        o += sWl[lane * 5 + c] * __shfl(m, c);
        o += sWr[lane * 5 + c] * __shfl(xv, c);
    }
    o = o > 0.f ? o : o * NEG_SLOPE;
    h1[(size_t)node * 64 + lane] = o;
}

// ------------------------------------------------------- mean aggregation
// 32 ch per wave (8 lanes x float4), 8 slots, unroll x4 -> 32 chains in flight
template<int CIN>
__global__ void agg_vec4_kernel(const float* __restrict__ h, const int* __restrict__ off,
                                const int* __restrict__ csr, float* __restrict__ mean,
                                int n_nodes) {
    constexpr int QW = CIN / 32;    // waves per node (2 or 4)
    int wid = blockIdx.x * (blockDim.x >> 6) + (threadIdx.x >> 6);
    int lane = threadIdx.x & 63;
    if (wid >= n_nodes * QW) return;
    int node = wid / QW;
    int q = wid % QW;
    int slot = lane >> 3, cg = lane & 7;
    int e0 = off[node], cnt = off[node + 1] - e0;
    const float* hb = h + q * 32 + cg * 4;
    float4 a0 = {0.f,0.f,0.f,0.f}, a1 = {0.f,0.f,0.f,0.f};
    float4 a2 = {0.f,0.f,0.f,0.f}, a3 = {0.f,0.f,0.f,0.f};
    int i = slot;
    for (; i + 24 < cnt; i += 32) {
        int s0 = csr[e0 + i];
        int s1 = csr[e0 + i + 8];
        int s2 = csr[e0 + i + 16];
        int s3 = csr[e0 + i + 24];
        float4 v0 = *(const float4*)(hb + (size_t)s0 * CIN);
        float4 v1 = *(const float4*)(hb + (size_t)s1 * CIN);
        float4 v2 = *(const float4*)(hb + (size_t)s2 * CIN);
        float4 v3 = *(const float4*)(hb + (size_t)s3 * CIN);
        a0.x += v0.x; a0.y += v0.y; a0.z += v0.z; a0.w += v0.w;
        a1.x += v1.x; a1.y += v1.y; a1.z += v1.z; a1.w += v1.w;
        a2.x += v2.x; a2.y += v2.y; a2.z += v2.z; a2.w += v2.w;
        a3.x += v3.x; a3.y += v3.y; a3.z += v3.z; a3.w += v3.w;
    }
    for (; i < cnt; i += 8) {
        int s = csr[e0 + i];
        float4 v = *(const float4*)(hb + (size_t)s * CIN);
        a0.x += v.x; a0.y += v.y; a0.z += v.z; a0.w += v.w;
    }
    float4 acc;
    acc.x = (a0.x + a1.x) + (a2.x + a3.x);
    acc.y = (a0.y + a1.y) + (a2.y + a3.y);
    acc.z = (a0.z + a1.z) + (a2.z + a3.z);
    acc.w = (a0.w + a1.w) + (a2.w + a3.w);
    #pragma unroll
    for (int o = 8; o < 64; o <<= 1) {
        acc.x += __shfl_xor(acc.x, o);
        acc.y += __shfl_xor(acc.y, o);
        acc.z += __shfl_xor(acc.z, o);
        acc.w += __shfl_xor(acc.w, o);
    }
    if (slot == 0) {
        float inv = (cnt > 0) ? 1.f / (float)cnt : 0.f;
        float4 r = {acc.x * inv, acc.y * inv, acc.z * inv, acc.w * inv};
        *(float4*)(mean + (size_t)node * CIN + q * 32 + cg * 4) = r;
    }
}

// ------------------------------------------------------------ f32 cat-GEMM (small)
#define BM 128
#define BN 64
#define BK 16

template<bool RELU>
__global__ __launch_bounds__(256) void gemm_cat_kernel(
        const float* __restrict__ AL, const float* __restrict__ AR,
        const float* __restrict__ W, const float* __restrict__ bias,
        float* __restrict__ C, int M, int N, int K, int CIN) {
    __shared__ float As[BK][BM + 4];
    __shared__ float Bs[BK][BN + 4];
    const int row0 = blockIdx.x * BM;
    const int col0 = blockIdx.y * BN;
    const int tid = threadIdx.x;
    const int ttm = tid & 15, ttn = tid >> 4;

    float acc[8][4];
    #pragma unroll
    for (int i = 0; i < 8; ++i)
        #pragma unroll
        for (int j = 0; j < 4; ++j) acc[i][j] = 0.f;

    for (int k0 = 0; k0 < K; k0 += BK) {
        for (int i = tid; i < BM * BK; i += 256) {
            int m = i >> 4, k = i & 15;
            int r = row0 + m, kk = k0 + k;
            float v = 0.f;
            if (r < M && kk < K)
                v = (kk < CIN) ? AL[(size_t)r * CIN + kk]
                               : AR[(size_t)r * CIN + (kk - CIN)];
            As[k][m] = v;
        }
        for (int i = tid; i < BN * BK; i += 256) {
            int n = i >> 4, k = i & 15;
            int c = col0 + n, kk = k0 + k;
            Bs[k][n] = (c < N && kk < K) ? W[(size_t)c * K + kk] : 0.f;
        }
        __syncthreads();
        #pragma unroll
        for (int k = 0; k < BK; ++k) {
            float4 a0 = *(const float4*)&As[k][ttm * 8];
            float4 a1 = *(const float4*)&As[k][ttm * 8 + 4];
            float4 b0 = *(const float4*)&Bs[k][ttn * 4];
            float av[8] = {a0.x, a0.y, a0.z, a0.w, a1.x, a1.y, a1.z, a1.w};
            float bv[4] = {b0.x, b0.y, b0.z, b0.w};
            #pragma unroll
            for (int i = 0; i < 8; ++i)
                #pragma unroll
                for (int j = 0; j < 4; ++j)
                    acc[i][j] += av[i] * bv[j];
        }
        __syncthreads();
    }

    float bv[4];
    #pragma unroll
    for (int j = 0; j < 4; ++j) bv[j] = bias[col0 + ttn * 4 + j];
    #pragma unroll
    for (int i = 0; i < 8; ++i) {
        int r = row0 + ttm * 8 + i;
        if (r < M) {
            float t0 = acc[i][0] + bv[0];
            float t1 = acc[i][1] + bv[1];
            float t2 = acc[i][2] + bv[2];
            float t3 = acc[i][3] + bv[3];
            if (RELU) {
                t0 = t0 > 0.f ? t0 : t0 * NEG_SLOPE;
                t1 = t1 > 0.f ? t1 : t1 * NEG_SLOPE;
                t2 = t2 > 0.f ? t2 : t2 * NEG_SLOPE;
                t3 = t3 > 0.f ? t3 : t3 * NEG_SLOPE;
            }
            float4 v; v.x = t0; v.y = t1; v.z = t2; v.w = t3;
            *(float4*)&C[(size_t)r * N + col0 + ttn * 4] = v;
        }
    }
}

// ------------------------------------- split-bf16 MFMA cat-GEMM (N=128/block)
__global__ __launch_bounds__(256) void gemm_cat_mfma_kernel(
        const float* __restrict__ AL, const float* __restrict__ AR,
        const short* __restrict__ Whi, const short* __restrict__ Wlo,
        const float* __restrict__ bias, float* __restrict__ C,
        int M, int N, int K, int CIN) {
    __shared__ short AsH[128][40], AsL[128][40];
    __shared__ short BsH[128][40], BsL[128][40];
    const int row0 = blockIdx.x * 128;
    const int n0 = blockIdx.y * 128;
    const int tid = threadIdx.x;
    const int w = tid >> 6;
    const int lane31 = tid & 31, lhalf = (tid & 63) >> 5;

    f32x16 acc[4];
    #pragma unroll
    for (int ci = 0; ci < 4; ++ci)
        #pragma unroll
        for (int r = 0; r < 16; ++r) acc[ci][r] = 0.f;

    for (int k0 = 0; k0 < K; k0 += 32) {
        const float* Asrc = (k0 < CIN) ? AL : AR;
        const int kb = (k0 < CIN) ? k0 : k0 - CIN;
        {
            int row = tid >> 1, kq = (tid & 1) * 16;
            int r = row0 + row;
            float vv[16];
            #pragma unroll
            for (int i = 0; i < 16; ++i) vv[i] = 0.f;
            if (r < M) {
                const float* p = &Asrc[(size_t)r * CIN + kb + kq];
                #pragma unroll
                for (int q = 0; q < 4; ++q) {
                    float4 v = ((const float4*)p)[q];
                    vv[q * 4 + 0] = v.x; vv[q * 4 + 1] = v.y;
                    vv[q * 4 + 2] = v.z; vv[q * 4 + 3] = v.w;
                }
            }
            #pragma unroll
            for (int half = 0; half < 2; ++half) {
                bh8 h8, l8;
                #pragma unroll
                for (int i = 0; i < 8; ++i) {
                    short a, b;
                    splitf(vv[half * 8 + i], a, b);
                    h8[i] = a; l8[i] = b;
                }
                *(bh8*)&AsH[row][kq + half * 8] = h8;
                *(bh8*)&AsL[row][kq + half * 8] = l8;
            }
        }
        {
            int n = tid & 127, half = tid >> 7;
            const short* src = half ? Wlo : Whi;
            const uint4* p = (const uint4*)&src[(size_t)(n0 + n) * K + k0];
            if (half) {
                #pragma unroll
                for (int q = 0; q < 4; ++q) *(uint4*)&BsL[n][q * 8] = p[q];
            } else {
                #pragma unroll
                for (int q = 0; q < 4; ++q) *(uint4*)&BsH[n][q * 8] = p[q];
            }
        }
        __syncthreads();
        #pragma unroll
        for (int ks = 0; ks < 2; ++ks) {
            int kofs = ks * 16 + lhalf * 8;
            bh8 aH = *(bh8*)&AsH[w * 32 + lane31][kofs];
            bh8 aL = *(bh8*)&AsL[w * 32 + lane31][kofs];
            #pragma unroll
            for (int ci = 0; ci < 4; ++ci) {
                bh8 bH = *(bh8*)&BsH[ci * 32 + lane31][kofs];
                bh8 bL = *(bh8*)&BsL[ci * 32 + lane31][kofs];
                acc[ci] = __builtin_amdgcn_mfma_f32_32x32x16_bf16(aH, bH, acc[ci], 0, 0, 0);
                acc[ci] = __builtin_amdgcn_mfma_f32_32x32x16_bf16(aH, bL, acc[ci], 0, 0, 0);
                acc[ci] = __builtin_amdgcn_mfma_f32_32x32x16_bf16(aL, bH, acc[ci], 0, 0, 0);
            }
        }
        __syncthreads();
    }

    #pragma unroll
    for (int ci = 0; ci < 4; ++ci) {
        int col = n0 + ci * 32 + lane31;
        float b = bias[col];
        #pragma unroll
        for (int r = 0; r < 16; ++r) {
            int row = row0 + w * 32 + (r & 3) + 8 * (r >> 2) + 4 * lhalf;
            if (row < M) {
                float v = acc[ci][r] + b;
                v = v > 0.f ? v : v * NEG_SLOPE;
                C[(size_t)row * N + col] = v;
            }
        }
    }
}

// ---------------------- split-bf16 MFMA fused layer-3 GEMM + mean/max pool
__global__ __launch_bounds__(256) void gemm_pool_mfma_kernel(
        const float* __restrict__ AL, const float* __restrict__ AR,
        const short* __restrict__ Whi, const short* __restrict__ Wlo,
        const float* __restrict__ bias, float* __restrict__ gout,
        int npg, int CIN, int NCH) {
    __shared__ short AsH[64][40], AsL[64][40];
    __shared__ short BsH[256][40], BsL[256][40];
    __shared__ float redS[2][256], redM[2][256];
    const int g = blockIdx.x;
    const int K = 2 * CIN;
    const int tid = threadIdx.x;
    const int w = tid >> 6;
    const int lane31 = tid & 31, lhalf = (tid & 63) >> 5;
    const int rt = w & 1, ctbase = (w >> 1) * 4;

    f32x16 acc[4];
    #pragma unroll
    for (int ci = 0; ci < 4; ++ci)
        #pragma unroll
        for (int r = 0; r < 16; ++r) acc[ci][r] = 0.f;

    for (int k0 = 0; k0 < K; k0 += 32) {
        const float* Asrc = (k0 < CIN) ? AL : AR;
        const int kb = (k0 < CIN) ? k0 : k0 - CIN;
        {
            int row = tid >> 2, kq = (tid & 3) * 8;
            float vv[8];
            #pragma unroll
            for (int i = 0; i < 8; ++i) vv[i] = 0.f;
            if (row < npg) {
                const float* p = &Asrc[((size_t)g * npg + row) * CIN + kb + kq];
                #pragma unroll
                for (int q = 0; q < 2; ++q) {
                    float4 v = ((const float4*)p)[q];
                    vv[q * 4 + 0] = v.x; vv[q * 4 + 1] = v.y;
                    vv[q * 4 + 2] = v.z; vv[q * 4 + 3] = v.w;
                }
            }
            bh8 h8, l8;
            #pragma unroll
            for (int i = 0; i < 8; ++i) {
                short a, b;
                splitf(vv[i], a, b);
                h8[i] = a; l8[i] = b;
            }
            *(bh8*)&AsH[row][kq] = h8;
            *(bh8*)&AsL[row][kq] = l8;
        }
        {
            int n = tid;
            const uint4* ph = (const uint4*)&Whi[(size_t)n * K + k0];
            const uint4* pl = (const uint4*)&Wlo[(size_t)n * K + k0];
            #pragma unroll
            for (int q = 0; q < 4; ++q) {
                *(uint4*)&BsH[n][q * 8] = ph[q];
                *(uint4*)&BsL[n][q * 8] = pl[q];
            }
        }
        __syncthreads();
        #pragma unroll
        for (int ks = 0; ks < 2; ++ks) {
            int kofs = ks * 16 + lhalf * 8;
            bh8 aH = *(bh8*)&AsH[rt * 32 + lane31][kofs];
            bh8 aL = *(bh8*)&AsL[rt * 32 + lane31][kofs];
            #pragma unroll
            for (int ci = 0; ci < 4; ++ci) {
                bh8 bH = *(bh8*)&BsH[(ctbase + ci) * 32 + lane31][kofs];
                bh8 bL = *(bh8*)&BsL[(ctbase + ci) * 32 + lane31][kofs];
                acc[ci] = __builtin_amdgcn_mfma_f32_32x32x16_bf16(aH, bH, acc[ci], 0, 0, 0);
                acc[ci] = __builtin_amdgcn_mfma_f32_32x32x16_bf16(aH, bL, acc[ci], 0, 0, 0);
                acc[ci] = __builtin_amdgcn_mfma_f32_32x32x16_bf16(aL, bH, acc[ci], 0, 0, 0);
            }
        }
        __syncthreads();
    }

    #pragma unroll
    for (int ci = 0; ci < 4; ++ci) {
        int col = (ctbase + ci) * 32 + lane31;
        float b = bias[col];
        float ls = 0.f, lm = -__builtin_huge_valf();
        #pragma unroll
        for (int r = 0; r < 16; ++r) {
            int row = rt * 32 + (r & 3) + 8 * (r >> 2) + 4 * lhalf;
            if (row < npg) {
                float v = acc[ci][r] + b;
                v = v > 0.f ? v : v * NEG_SLOPE;
                ls += v;
                lm = fmaxf(lm, v);
            }
        }
        ls += __shfl_xor(ls, 32);
        lm = fmaxf(lm, __shfl_xor(lm, 32));
        if (lhalf == 0) { redS[rt][col] = ls; redM[rt][col] = lm; }
    }
    __syncthreads();
    {
        int c = tid;
        float s = redS[0][c] + redS[1][c];
        float m = fmaxf(redM[0][c], redM[1][c]);
        gout[(size_t)g * (2 * NCH) + c] = s / (float)npg;
        gout[(size_t)g * (2 * NCH) + NCH + c] = m;
    }
}

// ------------------------------------------------------- final 64->1 layer
__global__ void final_kernel(const float* __restrict__ c2, const float* __restrict__ Wc3,
                             const float* __restrict__ bc3, float* __restrict__ out, int G) {
    int g = blockIdx.x * (blockDim.x >> 6) + (threadIdx.x >> 6);
    int lane = threadIdx.x & 63;
    if (g >= G) return;
    float v = c2[(size_t)g * 64 + lane] * Wc3[lane];
    #pragma unroll
    for (int o = 32; o > 0; o >>= 1) v += __shfl_down(v, o);
    if (lane == 0) out[g] = v + bc3[0];
}

// ---------------------------------------------------------------- launcher
extern "C" void kernel_launch(void* const* d_in, const int* in_sizes, int n_in,
                              void* d_out, int out_size, void* d_ws, size_t ws_size,
                              hipStream_t stream) {
    const float* x   = (const float*)d_in[0];
    const int* ei    = (const int*)d_in[1];
    const float* W1l = (const float*)d_in[4];
    const float* b1  = (const float*)d_in[5];
    const float* W1r = (const float*)d_in[6];
    const float* W2l = (const float*)d_in[7];
    const float* b2  = (const float*)d_in[8];
    const float* W2r = (const float*)d_in[9];
    const float* W3l = (const float*)d_in[10];
    const float* b3  = (const float*)d_in[11];
    const float* W3r = (const float*)d_in[12];
    const float* Wc1 = (const float*)d_in[13];
    const float* bc1 = (const float*)d_in[14];
    const float* Wc2 = (const float*)d_in[15];
    const float* bc2 = (const float*)d_in[16];
    const float* Wc3 = (const float*)d_in[17];
    const float* bc3 = (const float*)d_in[18];
    float* out = (float*)d_out;

    const int nodes = in_sizes[0] / 5;      // 100000  (< 2^17 for packed pairs)
    const int ne    = in_sizes[1] / 2;      // 1600000
    const int G     = out_size;             // 2000
    const int npg   = nodes / G;            // 50
    const int nb    = (nodes + 511) >> 9;   // 196 buckets (<=256)

    char* ws = (char*)d_ws;
    size_t pos = 0;
    auto take = [&](size_t bytes) -> char* {
        char* p = ws + pos;
        pos += (bytes + 255) & ~(size_t)255;
        return p;
    };
    int* off     = (int*)take((size_t)(nodes + 1) * 4);
    int* csr     = (int*)take((size_t)ne * 4);
    int* bcnt    = (int*)take(256 * 4);
    int* boff    = (int*)take(257 * 4);
    int* bcur    = (int*)take(256 * 4);
    short* Whi2  = (short*)take((size_t)128 * 128 * 2);
    short* Wlo2  = (short*)take((size_t)128 * 128 * 2);
    short* Whi3  = (short*)take((size_t)256 * 256 * 2);
    short* Wlo3  = (short*)take((size_t)256 * 256 * 2);
    short* WhiC  = (short*)take((size_t)128 * 512 * 2);
    short* WloC  = (short*)take((size_t)128 * 512 * 2);
    float* gbuf  = (float*)take((size_t)G * 512 * 4);
    float* c1    = (float*)take((size_t)G * 128 * 4);
    float* c2    = (float*)take((size_t)G * 64 * 4);
    // reused region: [mean1 | h1] (51.2MB): pairs during CSR build, mean2 after L2 GEMM
    float* mean1 = (float*)take((size_t)nodes * 64 * 4);
    float* h1    = (float*)take((size_t)nodes * 64 * 4);
    float* h2    = (float*)take((size_t)nodes * 128 * 4);
    float* mean2 = mean1;               // 51.2MB alias over dead mean1|h1
    unsigned* pairs = (unsigned*)mean1; // 6.4MB alias, dead before mean1 written

    if (pos > ws_size) {
        sentinel_kernel<<<(G + 255) / 256, 256, 0, stream>>>(out, G);
        return;
    }

    const int* src = ei;
    const int* dst = ei + ne;

    hipMemsetAsync(bcnt, 0, 256 * 4, stream);
    hipMemsetAsync(bcur, 0, 256 * 4, stream);

    // ---- CSR build v3
    bucket_count_kernel<<<(ne + HIST_CH - 1) / HIST_CH, 256, 0, stream>>>(dst, bcnt, ne, nb);
    scan256_kernel<<<1, 256, 0, stream>>>(bcnt, boff, nb);
    bucket_scatter_kernel<<<(ne + SCAT_CH - 1) / SCAT_CH, 256, 0, stream>>>(
        src, dst, boff, bcur, pairs, ne, nb);
    bucket_sort_kernel<<<nb, 512, 0, stream>>>(pairs, boff, off, csr, nodes);

    pack_wsplit_kernel<<<(128 * 128 + 255) / 256, 256, 0, stream>>>(W2l, W2r, Whi2, Wlo2, 128, 128, 64);
    pack_wsplit_kernel<<<(256 * 256 + 255) / 256, 256, 0, stream>>>(W3l, W3r, Whi3, Wlo3, 256, 256, 128);
    pack_wsplit_kernel<<<(128 * 512 + 255) / 256, 256, 0, stream>>>(Wc1, Wc1, WhiC, WloC, 128, 512, 512);

    // ---- layer 1 fused: h1 = lrelu(W1l·mean(x) + W1r·x + b1)
    sage1_kernel<<<(nodes + 3) / 4, 256, 0, stream>>>(x, off, csr, W1l, W1r, b1, h1, nodes);

    // ---- layer 2: [mean(h1)|h1] (K=128) -> 128  (split-bf16 MFMA)
    agg_vec4_kernel<64><<<(nodes * 2 + 3) / 4, 256, 0, stream>>>(h1, off, csr, mean1, nodes);
    {
        dim3 g((nodes + 127) / 128, 1);
        gemm_cat_mfma_kernel<<<g, 256, 0, stream>>>(mean1, h1, Whi2, Wlo2, b2, h2,
                                                    nodes, 128, 128, 64);
    }
    // ---- layer 3: [mean(h2)|h2] (K=256) -> 256, fused pool (split-bf16 MFMA)
    agg_vec4_kernel<128><<<(nodes * 4 + 3) / 4, 256, 0, stream>>>(h2, off, csr, mean2, nodes);
    gemm_pool_mfma_kernel<<<G, 256, 0, stream>>>(mean2, h2, Whi3, Wlo3, b3, gbuf,
                                                 npg, 128, 256);
    // ---- classifier: 512 -> 128 (MFMA) -> 64 (f32) -> 1
    {
        dim3 g((G + 127) / 128, 1);
        gemm_cat_mfma_kernel<<<g, 256, 0, stream>>>(gbuf, gbuf, WhiC, WloC, bc1, c1,
                                                    G, 128, 512, 512);
    }
    {
        dim3 g((G + BM - 1) / BM, 64 / BN);
        gemm_cat_kernel<true><<<g, 256, 0, stream>>>(c1, nullptr, Wc2, bc2, c2, G, 64, 128, 128);
    }
    final_kernel<<<(G + 3) / 4, 256, 0, stream>>>(c2, Wc3, bc3, out, G);
}

// Round 9
// 467.822 us; speedup vs baseline: 2.5848x; 1.1293x over previous
//
#include <hip/hip_runtime.h>
#include <cstdint>
#include <cstddef>

#define NEG_SLOPE 0.2f

typedef __attribute__((ext_vector_type(8))) short bh8;     // 8 bf16 in 4 VGPRs
typedef __attribute__((ext_vector_type(16))) float f32x16; // MFMA 32x32 accumulator

// split f32 -> bf16 hi + bf16 lo (x ~= hi + lo, residual ~2^-17 relative)
__device__ inline void splitf(float x, short& hi, short& lo) {
    uint32_t u = __float_as_uint(x);
    uint32_t rh = (u + 0x7FFFu + ((u >> 16) & 1u)) & 0xFFFF0000u;
    hi = (short)(rh >> 16);
    float rem = x - __uint_as_float(rh);
    uint32_t u2 = __float_as_uint(rem);
    lo = (short)((u2 + 0x7FFFu + ((u2 >> 16) & 1u)) >> 16);
}

// ---------------------------------------------------------------- sentinel
__global__ void sentinel_kernel(float* __restrict__ out, int n) {
    int i = blockIdx.x * blockDim.x + threadIdx.x;
    if (i < n) out[i] = 12345.0f;
}

// ------------------------------------------------- CSR build v3 (bucketed)
// bucket = dst >> 9 (512 nodes); pair = (dst&511)<<17 | src  (needs nodes<2^17)
#define HIST_CH 8192
__global__ void bucket_count_kernel(const int* __restrict__ dst, int* __restrict__ bcnt,
                                    int ne, int nb) {
    __shared__ int hist[256];
    const int tid = threadIdx.x;
    hist[tid] = 0;
    __syncthreads();
    int e0 = blockIdx.x * HIST_CH;
    for (int i = tid; i < HIST_CH; i += 256) {
        int e = e0 + i;
        if (e < ne) atomicAdd(&hist[dst[e] >> 9], 1);
    }
    __syncthreads();
    if (tid < nb && hist[tid] > 0) atomicAdd(&bcnt[tid], hist[tid]);
}

// scan over <=256 bucket counts; boff[0..n], boff[n]=total
__global__ void scan256_kernel(const int* __restrict__ bcnt, int* __restrict__ boff, int n) {
    const int tid = threadIdx.x, lane = tid & 63, wid = tid >> 6;
    __shared__ int wt[4];
    int v = (tid < n) ? bcnt[tid] : 0;
    int incl = v;
    #pragma unroll
    for (int o = 1; o < 64; o <<= 1) {
        int t = __shfl_up(incl, o);
        if (lane >= o) incl += t;
    }
    if (lane == 63) wt[wid] = incl;
    __syncthreads();
    if (tid < 4) {
        int w = wt[tid], winc = w;
        #pragma unroll
        for (int o = 1; o < 4; o <<= 1) {
            int t = __shfl_up(winc, o);
            if (tid >= o) winc += t;
        }
        wt[tid] = winc - w;
    }
    __syncthreads();
    int excl = wt[wid] + incl - v;
    if (tid < n) boff[tid] = excl;
    if (tid == n - 1) boff[n] = excl + v;
}

#define SCAT_CH 4096
__global__ void bucket_scatter_kernel(const int* __restrict__ src, const int* __restrict__ dst,
                                      const int* __restrict__ boff, int* __restrict__ bcur,
                                      unsigned* __restrict__ pairs, int ne, int nb) {
    __shared__ int hist[256], lcur[256], gbase[256];
    const int tid = threadIdx.x;
    hist[tid] = 0; lcur[tid] = 0;
    __syncthreads();
    int e0 = blockIdx.x * SCAT_CH;
    for (int i = tid; i < SCAT_CH; i += 256) {
        int e = e0 + i;
        if (e < ne) atomicAdd(&hist[dst[e] >> 9], 1);
    }
    __syncthreads();
    if (tid < nb) {
        int h = hist[tid];
        gbase[tid] = (h > 0) ? (boff[tid] + atomicAdd(&bcur[tid], h)) : 0;
    }
    __syncthreads();
    for (int i = tid; i < SCAT_CH; i += 256) {
        int e = e0 + i;
        if (e < ne) {
            int d = dst[e];
            int b = d >> 9;
            int r = atomicAdd(&lcur[b], 1);
            pairs[gbase[b] + r] = ((unsigned)(d & 511) << 17) | (unsigned)src[e];
        }
    }
}

// one block per bucket: LDS counting sort -> writes off[] and exact csr[]
__global__ __launch_bounds__(512) void bucket_sort_kernel(
        const unsigned* __restrict__ pairs, const int* __restrict__ boff,
        int* __restrict__ off, int* __restrict__ csr, int n_nodes) {
    __shared__ int cnt[512], lcur[512];
    __shared__ int wt[8];
    const int b = blockIdx.x;
    const int tid = threadIdx.x, lane = tid & 63, wid = tid >> 6;
    const int s = boff[b], t = boff[b + 1];
    cnt[tid] = 0; lcur[tid] = 0;
    __syncthreads();
    for (int i = s + tid; i < t; i += 512)
        atomicAdd(&cnt[pairs[i] >> 17], 1);
    __syncthreads();
    int v = cnt[tid];
    int incl = v;
    #pragma unroll
    for (int o = 1; o < 64; o <<= 1) {
        int tt = __shfl_up(incl, o);
        if (lane >= o) incl += tt;
    }
    if (lane == 63) wt[wid] = incl;
    __syncthreads();
    if (tid < 8) {
        int w = wt[tid], winc = w;
        #pragma unroll
        for (int o = 1; o < 8; o <<= 1) {
            int tt = __shfl_up(winc, o);
            if (tid >= o) winc += tt;
        }
        wt[tid] = winc - w;
    }
    __syncthreads();
    int excl = wt[wid] + incl - v;
    __syncthreads();
    cnt[tid] = excl;     // reuse as exclusive-offset table
    int node = b * 512 + tid;
    if (node < n_nodes) off[node] = s + excl;
    if (b == 0 && tid == 0) off[n_nodes] = boff[gridDim.x];   // = ne
    __syncthreads();
    for (int i = s + tid; i < t; i += 512) {
        unsigned p = pairs[i];
        int bin = p >> 17;
        int r = atomicAdd(&lcur[bin], 1);
        csr[s + cnt[bin] + r] = (int)(p & 0x1FFFFu);
    }
}

// ------------------------------------------------------- weight packs
__global__ void pack_wsplit_kernel(const float* __restrict__ Wl, const float* __restrict__ Wr,
                                   short* __restrict__ Whi, short* __restrict__ Wlo,
                                   int COUT, int K, int CIN) {
    int i = blockIdx.x * blockDim.x + threadIdx.x;
    if (i >= COUT * K) return;
    int n = i / K, k = i % K;
    float v = (k < CIN) ? Wl[n * CIN + k] : Wr[n * CIN + (k - CIN)];
    short h, l;
    splitf(v, h, l);
    Whi[i] = h; Wlo[i] = l;
}

// ---------------------------------- fused layer 1: gather-mean + 10-wide GEMM
__global__ __launch_bounds__(256) void sage1_kernel(
        const float* __restrict__ x, const int* __restrict__ off,
        const int* __restrict__ csr, const float* __restrict__ W1l,
        const float* __restrict__ W1r, const float* __restrict__ b1,
        float* __restrict__ h1, int n_nodes) {
    __shared__ float sWl[320], sWr[320], sb[64];
    const int tid = threadIdx.x;
    for (int i = tid; i < 320; i += 256) { sWl[i] = W1l[i]; sWr[i] = W1r[i]; }
    if (tid < 64) sb[tid] = b1[tid];
    __syncthreads();
    int node = blockIdx.x * 4 + (tid >> 6);
    int lane = tid & 63;
    if (node >= n_nodes) return;
    int slot = lane >> 3, cg = lane & 7;
    int e0 = off[node], cnt = off[node + 1] - e0;
    float a0 = 0.f, a1 = 0.f;
    int i = slot;
    for (; i + 8 < cnt; i += 16) {
        int s0 = csr[e0 + i];
        int s1 = csr[e0 + i + 8];
        a0 += (cg < 5) ? x[(size_t)s0 * 5 + cg] : 0.f;
        a1 += (cg < 5) ? x[(size_t)s1 * 5 + cg] : 0.f;
    }
    for (; i < cnt; i += 8) {
        int s = csr[e0 + i];
        a0 += (cg < 5) ? x[(size_t)s * 5 + cg] : 0.f;
    }
    float acc = a0 + a1;
    #pragma unroll
    for (int o = 8; o < 64; o <<= 1) acc += __shfl_xor(acc, o);
    float inv = (cnt > 0) ? 1.f / (float)cnt : 0.f;
    float m = acc * inv;
    float xv = (lane < 5) ? x[(size_t)node * 5 + lane] : 0.f;
    float o = sb[lane];
    #pragma unroll
    for (int c = 0; c < 5; ++c) {
        o += sWl[lane * 5 + c] * __shfl(m, c);
        o += sWr[lane * 5 + c] * __shfl(xv, c);
    }
    o = o > 0.f ? o : o * NEG_SLOPE;
    h1[(size_t)node * 64 + lane] = o;
}

// ------------------------------------------------------- mean aggregation
// 64 ch per wave (16 lanes x float4), 4 slots, unroll x4 -> 16 chains in flight
// (proven optimum: 32 chains/wave regressed — path-BW-bound past this point)
template<int CIN>
__global__ void agg_vec3_kernel(const float* __restrict__ h, const int* __restrict__ off,
                                const int* __restrict__ csr, float* __restrict__ mean,
                                int n_nodes) {
    constexpr int HALVES = CIN / 64;
    int wid = blockIdx.x * (blockDim.x >> 6) + (threadIdx.x >> 6);
    int lane = threadIdx.x & 63;
    if (wid >= n_nodes * HALVES) return;
    int node = (HALVES == 1) ? wid : (wid >> 1);
    int half = (HALVES == 1) ? 0 : (wid & 1);
    int slot = lane >> 4, cg = lane & 15;
    int e0 = off[node], cnt = off[node + 1] - e0;
    const float* hb = h + (size_t)half * 64 + cg * 4;
    float4 a0 = {0.f,0.f,0.f,0.f}, a1 = {0.f,0.f,0.f,0.f};
    float4 a2 = {0.f,0.f,0.f,0.f}, a3 = {0.f,0.f,0.f,0.f};
    int i = slot;
    for (; i + 12 < cnt; i += 16) {
        int s0 = csr[e0 + i];
        int s1 = csr[e0 + i + 4];
        int s2 = csr[e0 + i + 8];
        int s3 = csr[e0 + i + 12];
        float4 v0 = *(const float4*)(hb + (size_t)s0 * CIN);
        float4 v1 = *(const float4*)(hb + (size_t)s1 * CIN);
        float4 v2 = *(const float4*)(hb + (size_t)s2 * CIN);
        float4 v3 = *(const float4*)(hb + (size_t)s3 * CIN);
        a0.x += v0.x; a0.y += v0.y; a0.z += v0.z; a0.w += v0.w;
        a1.x += v1.x; a1.y += v1.y; a1.z += v1.z; a1.w += v1.w;
        a2.x += v2.x; a2.y += v2.y; a2.z += v2.z; a2.w += v2.w;
        a3.x += v3.x; a3.y += v3.y; a3.z += v3.z; a3.w += v3.w;
    }
    for (; i < cnt; i += 4) {
        int s = csr[e0 + i];
        float4 v = *(const float4*)(hb + (size_t)s * CIN);
        a0.x += v.x; a0.y += v.y; a0.z += v.z; a0.w += v.w;
    }
    float4 acc;
    acc.x = (a0.x + a1.x) + (a2.x + a3.x);
    acc.y = (a0.y + a1.y) + (a2.y + a3.y);
    acc.z = (a0.z + a1.z) + (a2.z + a3.z);
    acc.w = (a0.w + a1.w) + (a2.w + a3.w);
    #pragma unroll
    for (int o = 16; o < 64; o <<= 1) {
        acc.x += __shfl_xor(acc.x, o);
        acc.y += __shfl_xor(acc.y, o);
        acc.z += __shfl_xor(acc.z, o);
        acc.w += __shfl_xor(acc.w, o);
    }
    if (slot == 0) {
        float inv = (cnt > 0) ? 1.f / (float)cnt : 0.f;
        float4 r = {acc.x * inv, acc.y * inv, acc.z * inv, acc.w * inv};
        *(float4*)(mean + (size_t)node * CIN + half * 64 + cg * 4) = r;
    }
}

// ------------------------------------------------------------ f32 cat-GEMM (small)
#define BM 128
#define BN 64
#define BK 16

template<bool RELU>
__global__ __launch_bounds__(256) void gemm_cat_kernel(
        const float* __restrict__ AL, const float* __restrict__ AR,
        const float* __restrict__ W, const float* __restrict__ bias,
        float* __restrict__ C, int M, int N, int K, int CIN) {
    __shared__ float As[BK][BM + 4];
    __shared__ float Bs[BK][BN + 4];
    const int row0 = blockIdx.x * BM;
    const int col0 = blockIdx.y * BN;
    const int tid = threadIdx.x;
    const int ttm = tid & 15, ttn = tid >> 4;

    float acc[8][4];
    #pragma unroll
    for (int i = 0; i < 8; ++i)
        #pragma unroll
        for (int j = 0; j < 4; ++j) acc[i][j] = 0.f;

    for (int k0 = 0; k0 < K; k0 += BK) {
        for (int i = tid; i < BM * BK; i += 256) {
            int m = i >> 4, k = i & 15;
            int r = row0 + m, kk = k0 + k;
            float v = 0.f;
            if (r < M && kk < K)
                v = (kk < CIN) ? AL[(size_t)r * CIN + kk]
                               : AR[(size_t)r * CIN + (kk - CIN)];
            As[k][m] = v;
        }
        for (int i = tid; i < BN * BK; i += 256) {
            int n = i >> 4, k = i & 15;
            int c = col0 + n, kk = k0 + k;
            Bs[k][n] = (c < N && kk < K) ? W[(size_t)c * K + kk] : 0.f;
        }
        __syncthreads();
        #pragma unroll
        for (int k = 0; k < BK; ++k) {
            float4 a0 = *(const float4*)&As[k][ttm * 8];
            float4 a1 = *(const float4*)&As[k][ttm * 8 + 4];
            float4 b0 = *(const float4*)&Bs[k][ttn * 4];
            float av[8] = {a0.x, a0.y, a0.z, a0.w, a1.x, a1.y, a1.z, a1.w};
            float bv[4] = {b0.x, b0.y, b0.z, b0.w};
            #pragma unroll
            for (int i = 0; i < 8; ++i)
                #pragma unroll
                for (int j = 0; j < 4; ++j)
                    acc[i][j] += av[i] * bv[j];
        }
        __syncthreads();
    }

    float bv[4];
    #pragma unroll
    for (int j = 0; j < 4; ++j) bv[j] = bias[col0 + ttn * 4 + j];
    #pragma unroll
    for (int i = 0; i < 8; ++i) {
        int r = row0 + ttm * 8 + i;
        if (r < M) {
            float t0 = acc[i][0] + bv[0];
            float t1 = acc[i][1] + bv[1];
            float t2 = acc[i][2] + bv[2];
            float t3 = acc[i][3] + bv[3];
            if (RELU) {
                t0 = t0 > 0.f ? t0 : t0 * NEG_SLOPE;
                t1 = t1 > 0.f ? t1 : t1 * NEG_SLOPE;
                t2 = t2 > 0.f ? t2 : t2 * NEG_SLOPE;
                t3 = t3 > 0.f ? t3 : t3 * NEG_SLOPE;
            }
            float4 v; v.x = t0; v.y = t1; v.z = t2; v.w = t3;
            *(float4*)&C[(size_t)r * N + col0 + ttn * 4] = v;
        }
    }
}

// ------------------------------------- split-bf16 MFMA cat-GEMM (N=128/block)
__global__ __launch_bounds__(256) void gemm_cat_mfma_kernel(
        const float* __restrict__ AL, const float* __restrict__ AR,
        const short* __restrict__ Whi, const short* __restrict__ Wlo,
        const float* __restrict__ bias, float* __restrict__ C,
        int M, int N, int K, int CIN) {
    __shared__ short AsH[128][40], AsL[128][40];
    __shared__ short BsH[128][40], BsL[128][40];
    const int row0 = blockIdx.x * 128;
    const int n0 = blockIdx.y * 128;
    const int tid = threadIdx.x;
    const int w = tid >> 6;
    const int lane31 = tid & 31, lhalf = (tid & 63) >> 5;

    f32x16 acc[4];
    #pragma unroll
    for (int ci = 0; ci < 4; ++ci)
        #pragma unroll
        for (int r = 0; r < 16; ++r) acc[ci][r] = 0.f;

    for (int k0 = 0; k0 < K; k0 += 32) {
        const float* Asrc = (k0 < CIN) ? AL : AR;
        const int kb = (k0 < CIN) ? k0 : k0 - CIN;
        {
            int row = tid >> 1, kq = (tid & 1) * 16;
            int r = row0 + row;
            float vv[16];
            #pragma unroll
            for (int i = 0; i < 16; ++i) vv[i] = 0.f;
            if (r < M) {
                const float* p = &Asrc[(size_t)r * CIN + kb + kq];
                #pragma unroll
                for (int q = 0; q < 4; ++q) {
                    float4 v = ((const float4*)p)[q];
                    vv[q * 4 + 0] = v.x; vv[q * 4 + 1] = v.y;
                    vv[q * 4 + 2] = v.z; vv[q * 4 + 3] = v.w;
                }
            }
            #pragma unroll
            for (int half = 0; half < 2; ++half) {
                bh8 h8, l8;
                #pragma unroll
                for (int i = 0; i < 8; ++i) {
                    short a, b;
                    splitf(vv[half * 8 + i], a, b);
                    h8[i] = a; l8[i] = b;
                }
                *(bh8*)&AsH[row][kq + half * 8] = h8;
                *(bh8*)&AsL[row][kq + half * 8] = l8;
            }
        }
        {
            int n = tid & 127, half = tid >> 7;
            const short* src = half ? Wlo : Whi;
            const uint4* p = (const uint4*)&src[(size_t)(n0 + n) * K + k0];
            if (half) {
                #pragma unroll
                for (int q = 0; q < 4; ++q) *(uint4*)&BsL[n][q * 8] = p[q];
            } else {
                #pragma unroll
                for (int q = 0; q < 4; ++q) *(uint4*)&BsH[n][q * 8] = p[q];
            }
        }
        __syncthreads();
        #pragma unroll
        for (int ks = 0; ks < 2; ++ks) {
            int kofs = ks * 16 + lhalf * 8;
            bh8 aH = *(bh8*)&AsH[w * 32 + lane31][kofs];
            bh8 aL = *(bh8*)&AsL[w * 32 + lane31][kofs];
            #pragma unroll
            for (int ci = 0; ci < 4; ++ci) {
                bh8 bH = *(bh8*)&BsH[ci * 32 + lane31][kofs];
                bh8 bL = *(bh8*)&BsL[ci * 32 + lane31][kofs];
                acc[ci] = __builtin_amdgcn_mfma_f32_32x32x16_bf16(aH, bH, acc[ci], 0, 0, 0);
                acc[ci] = __builtin_amdgcn_mfma_f32_32x32x16_bf16(aH, bL, acc[ci], 0, 0, 0);
                acc[ci] = __builtin_amdgcn_mfma_f32_32x32x16_bf16(aL, bH, acc[ci], 0, 0, 0);
            }
        }
        __syncthreads();
    }

    #pragma unroll
    for (int ci = 0; ci < 4; ++ci) {
        int col = n0 + ci * 32 + lane31;
        float b = bias[col];
        #pragma unroll
        for (int r = 0; r < 16; ++r) {
            int row = row0 + w * 32 + (r & 3) + 8 * (r >> 2) + 4 * lhalf;
            if (row < M) {
                float v = acc[ci][r] + b;
                v = v > 0.f ? v : v * NEG_SLOPE;
                C[(size_t)row * N + col] = v;
            }
        }
    }
}

// ------------- split-bf16 MFMA fused layer-3 GEMM + pool, 2 graphs per block
// 512 thr = 8 waves; A-tile 128 rows = 2 graphs (each padded to 64);
// wave w: row-tile rt=w&3 (32 rows), col-group cb=(w>>2)*4 (4 of 8 col-tiles).
__global__ __launch_bounds__(512) void gemm_pool_mfma2_kernel(
        const float* __restrict__ AL, const float* __restrict__ AR,
        const short* __restrict__ Whi, const short* __restrict__ Wlo,
        const float* __restrict__ bias, float* __restrict__ gout,
        int npg, int CIN, int NCH) {
    __shared__ short AsH[128][40], AsL[128][40];
    __shared__ short BsH[256][40], BsL[256][40];
    __shared__ float redS[4][258], redM[4][258];
    const int g2 = blockIdx.x * 2;
    const int K = 2 * CIN;
    const int tid = threadIdx.x;
    const int w = tid >> 6;
    const int lane31 = tid & 31, lhalf = (tid & 63) >> 5;
    const int rt = w & 3, cb = (w >> 2) * 4;

    f32x16 acc[4];
    #pragma unroll
    for (int ci = 0; ci < 4; ++ci)
        #pragma unroll
        for (int r = 0; r < 16; ++r) acc[ci][r] = 0.f;

    for (int k0 = 0; k0 < K; k0 += 32) {
        const float* Asrc = (k0 < CIN) ? AL : AR;
        const int kb = (k0 < CIN) ? k0 : k0 - CIN;
        {   // stage A: 128 rows (2 graphs x 64-pad) x 32 k; 512 thr x 8 floats
            int row = tid >> 2, kq = (tid & 3) * 8;
            int grow = row >> 6, r = row & 63;
            float vv[8];
            #pragma unroll
            for (int i = 0; i < 8; ++i) vv[i] = 0.f;
            if (r < npg) {
                const float* p = &Asrc[((size_t)(g2 + grow) * npg + r) * CIN + kb + kq];
                #pragma unroll
                for (int q = 0; q < 2; ++q) {
                    float4 v = ((const float4*)p)[q];
                    vv[q * 4 + 0] = v.x; vv[q * 4 + 1] = v.y;
                    vv[q * 4 + 2] = v.z; vv[q * 4 + 3] = v.w;
                }
            }
            bh8 h8, l8;
            #pragma unroll
            for (int i = 0; i < 8; ++i) {
                short a, b;
                splitf(vv[i], a, b);
                h8[i] = a; l8[i] = b;
            }
            *(bh8*)&AsH[row][kq] = h8;
            *(bh8*)&AsL[row][kq] = l8;
        }
        {   // stage B: 256 n x 32 k, hi and lo halves split across thread halves
            int n = tid & 255, half = tid >> 8;
            const short* srcw = half ? Wlo : Whi;
            const uint4* p = (const uint4*)&srcw[(size_t)n * K + k0];
            if (half) {
                #pragma unroll
                for (int q = 0; q < 4; ++q) *(uint4*)&BsL[n][q * 8] = p[q];
            } else {
                #pragma unroll
                for (int q = 0; q < 4; ++q) *(uint4*)&BsH[n][q * 8] = p[q];
            }
        }
        __syncthreads();
        #pragma unroll
        for (int ks = 0; ks < 2; ++ks) {
            int kofs = ks * 16 + lhalf * 8;
            bh8 aH = *(bh8*)&AsH[rt * 32 + lane31][kofs];
            bh8 aL = *(bh8*)&AsL[rt * 32 + lane31][kofs];
            #pragma unroll
            for (int ci = 0; ci < 4; ++ci) {
                bh8 bH = *(bh8*)&BsH[(cb + ci) * 32 + lane31][kofs];
                bh8 bL = *(bh8*)&BsL[(cb + ci) * 32 + lane31][kofs];
                acc[ci] = __builtin_amdgcn_mfma_f32_32x32x16_bf16(aH, bH, acc[ci], 0, 0, 0);
                acc[ci] = __builtin_amdgcn_mfma_f32_32x32x16_bf16(aH, bL, acc[ci], 0, 0, 0);
                acc[ci] = __builtin_amdgcn_mfma_f32_32x32x16_bf16(aL, bH, acc[ci], 0, 0, 0);
            }
        }
        __syncthreads();
    }

    // bias + lrelu + per-wave partial pool over valid rows of its row-tile
    #pragma unroll
    for (int ci = 0; ci < 4; ++ci) {
        int col = (cb + ci) * 32 + lane31;
        float b = bias[col];
        float ls = 0.f, lm = -__builtin_huge_valf();
        #pragma unroll
        for (int r = 0; r < 16; ++r) {
            int crow = (r & 3) + 8 * (r >> 2) + 4 * lhalf;      // 0..31 within tile
            int grow = (rt & 1) * 32 + crow;                    // 0..63 within graph
            if (grow < npg) {
                float v = acc[ci][r] + b;
                v = v > 0.f ? v : v * NEG_SLOPE;
                ls += v;
                lm = fmaxf(lm, v);
            }
        }
        ls += __shfl_xor(ls, 32);
        lm = fmaxf(lm, __shfl_xor(lm, 32));
        if (lhalf == 0) { redS[rt][col] = ls; redM[rt][col] = lm; }
    }
    __syncthreads();
    {   // combine row-tiles: rt {0,1} -> graph g2, {2,3} -> g2+1
        int c = tid & 255, gi = tid >> 8;
        float s = redS[gi * 2][c] + redS[gi * 2 + 1][c];
        float m = fmaxf(redM[gi * 2][c], redM[gi * 2 + 1][c]);
        gout[(size_t)(g2 + gi) * (2 * NCH) + c] = s / (float)npg;
        gout[(size_t)(g2 + gi) * (2 * NCH) + NCH + c] = m;
    }
}

// ------------------------------------------------------- final 64->1 layer
__global__ void final_kernel(const float* __restrict__ c2, const float* __restrict__ Wc3,
                             const float* __restrict__ bc3, float* __restrict__ out, int G) {
    int g = blockIdx.x * (blockDim.x >> 6) + (threadIdx.x >> 6);
    int lane = threadIdx.x & 63;
    if (g >= G) return;
    float v = c2[(size_t)g * 64 + lane] * Wc3[lane];
    #pragma unroll
    for (int o = 32; o > 0; o >>= 1) v += __shfl_down(v, o);
    if (lane == 0) out[g] = v + bc3[0];
}

// ---------------------------------------------------------------- launcher
extern "C" void kernel_launch(void* const* d_in, const int* in_sizes, int n_in,
                              void* d_out, int out_size, void* d_ws, size_t ws_size,
                              hipStream_t stream) {
    const float* x   = (const float*)d_in[0];
    const int* ei    = (const int*)d_in[1];
    const float* W1l = (const float*)d_in[4];
    const float* b1  = (const float*)d_in[5];
    const float* W1r = (const float*)d_in[6];
    const float* W2l = (const float*)d_in[7];
    const float* b2  = (const float*)d_in[8];
    const float* W2r = (const float*)d_in[9];
    const float* W3l = (const float*)d_in[10];
    const float* b3  = (const float*)d_in[11];
    const float* W3r = (const float*)d_in[12];
    const float* Wc1 = (const float*)d_in[13];
    const float* bc1 = (const float*)d_in[14];
    const float* Wc2 = (const float*)d_in[15];
    const float* bc2 = (const float*)d_in[16];
    const float* Wc3 = (const float*)d_in[17];
    const float* bc3 = (const float*)d_in[18];
    float* out = (float*)d_out;

    const int nodes = in_sizes[0] / 5;      // 100000  (< 2^17 for packed pairs)
    const int ne    = in_sizes[1] / 2;      // 1600000
    const int G     = out_size;             // 2000 (even)
    const int npg   = nodes / G;            // 50
    const int nb    = (nodes + 511) >> 9;   // 196 buckets (<=256)

    char* ws = (char*)d_ws;
    size_t pos = 0;
    auto take = [&](size_t bytes) -> char* {
        char* p = ws + pos;
        pos += (bytes + 255) & ~(size_t)255;
        return p;
    };
    int* off     = (int*)take((size_t)(nodes + 1) * 4);
    int* csr     = (int*)take((size_t)ne * 4);
    int* bcnt    = (int*)take(256 * 4);
    int* boff    = (int*)take(257 * 4);
    int* bcur    = (int*)take(256 * 4);
    short* Whi2  = (short*)take((size_t)128 * 128 * 2);
    short* Wlo2  = (short*)take((size_t)128 * 128 * 2);
    short* Whi3  = (short*)take((size_t)256 * 256 * 2);
    short* Wlo3  = (short*)take((size_t)256 * 256 * 2);
    short* WhiC  = (short*)take((size_t)128 * 512 * 2);
    short* WloC  = (short*)take((size_t)128 * 512 * 2);
    float* gbuf  = (float*)take((size_t)G * 512 * 4);
    float* c1    = (float*)take((size_t)G * 128 * 4);
    float* c2    = (float*)take((size_t)G * 64 * 4);
    // reused region: [mean1 | h1] (51.2MB): pairs during CSR build, mean2 after L2 GEMM
    float* mean1 = (float*)take((size_t)nodes * 64 * 4);
    float* h1    = (float*)take((size_t)nodes * 64 * 4);
    float* h2    = (float*)take((size_t)nodes * 128 * 4);
    float* mean2 = mean1;               // 51.2MB alias over dead mean1|h1
    unsigned* pairs = (unsigned*)mean1; // 6.4MB alias, dead before mean1 written

    if (pos > ws_size) {
        sentinel_kernel<<<(G + 255) / 256, 256, 0, stream>>>(out, G);
        return;
    }

    const int* src = ei;
    const int* dst = ei + ne;

    hipMemsetAsync(bcnt, 0, 256 * 4, stream);
    hipMemsetAsync(bcur, 0, 256 * 4, stream);

    // ---- CSR build v3
    bucket_count_kernel<<<(ne + HIST_CH - 1) / HIST_CH, 256, 0, stream>>>(dst, bcnt, ne, nb);
    scan256_kernel<<<1, 256, 0, stream>>>(bcnt, boff, nb);
    bucket_scatter_kernel<<<(ne + SCAT_CH - 1) / SCAT_CH, 256, 0, stream>>>(
        src, dst, boff, bcur, pairs, ne, nb);
    bucket_sort_kernel<<<nb, 512, 0, stream>>>(pairs, boff, off, csr, nodes);

    pack_wsplit_kernel<<<(128 * 128 + 255) / 256, 256, 0, stream>>>(W2l, W2r, Whi2, Wlo2, 128, 128, 64);
    pack_wsplit_kernel<<<(256 * 256 + 255) / 256, 256, 0, stream>>>(W3l, W3r, Whi3, Wlo3, 256, 256, 128);
    pack_wsplit_kernel<<<(128 * 512 + 255) / 256, 256, 0, stream>>>(Wc1, Wc1, WhiC, WloC, 128, 512, 512);

    // ---- layer 1 fused: h1 = lrelu(W1l·mean(x) + W1r·x + b1)
    sage1_kernel<<<(nodes + 3) / 4, 256, 0, stream>>>(x, off, csr, W1l, W1r, b1, h1, nodes);

    // ---- layer 2: [mean(h1)|h1] (K=128) -> 128  (split-bf16 MFMA)
    agg_vec3_kernel<64><<<(nodes + 3) / 4, 256, 0, stream>>>(h1, off, csr, mean1, nodes);
    {
        dim3 g((nodes + 127) / 128, 1);
        gemm_cat_mfma_kernel<<<g, 256, 0, stream>>>(mean1, h1, Whi2, Wlo2, b2, h2,
                                                    nodes, 128, 128, 64);
    }
    // ---- layer 3: [mean(h2)|h2] (K=256) -> 256, fused pool (2 graphs/block)
    agg_vec3_kernel<128><<<(nodes * 2 + 3) / 4, 256, 0, stream>>>(h2, off, csr, mean2, nodes);
    gemm_pool_mfma2_kernel<<<G / 2, 512, 0, stream>>>(mean2, h2, Whi3, Wlo3, b3, gbuf,
                                                      npg, 128, 256);
    // ---- classifier: 512 -> 128 (MFMA) -> 64 (f32) -> 1
    {
        dim3 g((G + 127) / 128, 1);
        gemm_cat_mfma_kernel<<<g, 256, 0, stream>>>(gbuf, gbuf, WhiC, WloC, bc1, c1,
                                                    G, 128, 512, 512);
    }
    {
        dim3 g((G + BM - 1) / BM, 64 / BN);
        gemm_cat_kernel<true><<<g, 256, 0, stream>>>(c1, nullptr, Wc2, bc2, c2, G, 64, 128, 128);
    }
    final_kernel<<<(G + 3) / 4, 256, 0, stream>>>(c2, Wc3, bc3, out, G);
}

// Round 10
// 407.117 us; speedup vs baseline: 2.9702x; 1.1491x over previous
//
#include <hip/hip_runtime.h>
#include <cstdint>
#include <cstddef>

#define NEG_SLOPE 0.2f

typedef __attribute__((ext_vector_type(8))) short bh8;     // 8 bf16 in 4 VGPRs
typedef __attribute__((ext_vector_type(16))) float f32x16; // MFMA 32x32 accumulator

// split f32 -> bf16 hi + bf16 lo (x ~= hi + lo, residual ~2^-17 relative)
__device__ inline void splitf(float x, short& hi, short& lo) {
    uint32_t u = __float_as_uint(x);
    uint32_t rh = (u + 0x7FFFu + ((u >> 16) & 1u)) & 0xFFFF0000u;
    hi = (short)(rh >> 16);
    float rem = x - __uint_as_float(rh);
    uint32_t u2 = __float_as_uint(rem);
    lo = (short)((u2 + 0x7FFFu + ((u2 >> 16) & 1u)) >> 16);
}

__device__ inline unsigned short f2bf(float x) {   // round-to-nearest-even bf16
    uint32_t u = __float_as_uint(x);
    return (unsigned short)((u + 0x7FFFu + ((u >> 16) & 1u)) >> 16);
}

// ---------------------------------------------------------------- sentinel
__global__ void sentinel_kernel(float* __restrict__ out, int n) {
    int i = blockIdx.x * blockDim.x + threadIdx.x;
    if (i < n) out[i] = 12345.0f;
}

// ------------------------------------------------- CSR build v3 (bucketed)
// bucket = dst >> 9 (512 nodes); pair = (dst&511)<<17 | src  (needs nodes<2^17)
#define HIST_CH 8192
__global__ void bucket_count_kernel(const int* __restrict__ dst, int* __restrict__ bcnt,
                                    int ne, int nb) {
    __shared__ int hist[256];
    const int tid = threadIdx.x;
    hist[tid] = 0;
    __syncthreads();
    int e0 = blockIdx.x * HIST_CH;
    for (int i = tid; i < HIST_CH; i += 256) {
        int e = e0 + i;
        if (e < ne) atomicAdd(&hist[dst[e] >> 9], 1);
    }
    __syncthreads();
    if (tid < nb && hist[tid] > 0) atomicAdd(&bcnt[tid], hist[tid]);
}

// scan over <=256 bucket counts; boff[0..n], boff[n]=total
__global__ void scan256_kernel(const int* __restrict__ bcnt, int* __restrict__ boff, int n) {
    const int tid = threadIdx.x, lane = tid & 63, wid = tid >> 6;
    __shared__ int wt[4];
    int v = (tid < n) ? bcnt[tid] : 0;
    int incl = v;
    #pragma unroll
    for (int o = 1; o < 64; o <<= 1) {
        int t = __shfl_up(incl, o);
        if (lane >= o) incl += t;
    }
    if (lane == 63) wt[wid] = incl;
    __syncthreads();
    if (tid < 4) {
        int w = wt[tid], winc = w;
        #pragma unroll
        for (int o = 1; o < 4; o <<= 1) {
            int t = __shfl_up(winc, o);
            if (tid >= o) winc += t;
        }
        wt[tid] = winc - w;
    }
    __syncthreads();
    int excl = wt[wid] + incl - v;
    if (tid < n) boff[tid] = excl;
    if (tid == n - 1) boff[n] = excl + v;
}

#define SCAT_CH 4096
__global__ void bucket_scatter_kernel(const int* __restrict__ src, const int* __restrict__ dst,
                                      const int* __restrict__ boff, int* __restrict__ bcur,
                                      unsigned* __restrict__ pairs, int ne, int nb) {
    __shared__ int hist[256], lcur[256], gbase[256];
    const int tid = threadIdx.x;
    hist[tid] = 0; lcur[tid] = 0;
    __syncthreads();
    int e0 = blockIdx.x * SCAT_CH;
    for (int i = tid; i < SCAT_CH; i += 256) {
        int e = e0 + i;
        if (e < ne) atomicAdd(&hist[dst[e] >> 9], 1);
    }
    __syncthreads();
    if (tid < nb) {
        int h = hist[tid];
        gbase[tid] = (h > 0) ? (boff[tid] + atomicAdd(&bcur[tid], h)) : 0;
    }
    __syncthreads();
    for (int i = tid; i < SCAT_CH; i += 256) {
        int e = e0 + i;
        if (e < ne) {
            int d = dst[e];
            int b = d >> 9;
            int r = atomicAdd(&lcur[b], 1);
            pairs[gbase[b] + r] = ((unsigned)(d & 511) << 17) | (unsigned)src[e];
        }
    }
}

// one block per bucket: LDS counting sort -> writes off[] and exact csr[]
__global__ __launch_bounds__(512) void bucket_sort_kernel(
        const unsigned* __restrict__ pairs, const int* __restrict__ boff,
        int* __restrict__ off, int* __restrict__ csr, int n_nodes) {
    __shared__ int cnt[512], lcur[512];
    __shared__ int wt[8];
    const int b = blockIdx.x;
    const int tid = threadIdx.x, lane = tid & 63, wid = tid >> 6;
    const int s = boff[b], t = boff[b + 1];
    cnt[tid] = 0; lcur[tid] = 0;
    __syncthreads();
    for (int i = s + tid; i < t; i += 512)
        atomicAdd(&cnt[pairs[i] >> 17], 1);
    __syncthreads();
    int v = cnt[tid];
    int incl = v;
    #pragma unroll
    for (int o = 1; o < 64; o <<= 1) {
        int tt = __shfl_up(incl, o);
        if (lane >= o) incl += tt;
    }
    if (lane == 63) wt[wid] = incl;
    __syncthreads();
    if (tid < 8) {
        int w = wt[tid], winc = w;
        #pragma unroll
        for (int o = 1; o < 8; o <<= 1) {
            int tt = __shfl_up(winc, o);
            if (tid >= o) winc += tt;
        }
        wt[tid] = winc - w;
    }
    __syncthreads();
    int excl = wt[wid] + incl - v;
    __syncthreads();
    cnt[tid] = excl;     // reuse as exclusive-offset table
    int node = b * 512 + tid;
    if (node < n_nodes) off[node] = s + excl;
    if (b == 0 && tid == 0) off[n_nodes] = boff[gridDim.x];   // = ne
    __syncthreads();
    for (int i = s + tid; i < t; i += 512) {
        unsigned p = pairs[i];
        int bin = p >> 17;
        int r = atomicAdd(&lcur[bin], 1);
        csr[s + cnt[bin] + r] = (int)(p & 0x1FFFFu);
    }
}

// ------------------------------------------------------- weight packs
__global__ void pack_wsplit_kernel(const float* __restrict__ Wl, const float* __restrict__ Wr,
                                   short* __restrict__ Whi, short* __restrict__ Wlo,
                                   int COUT, int K, int CIN) {
    int i = blockIdx.x * blockDim.x + threadIdx.x;
    if (i >= COUT * K) return;
    int n = i / K, k = i % K;
    float v = (k < CIN) ? Wl[n * CIN + k] : Wr[n * CIN + (k - CIN)];
    short h, l;
    splitf(v, h, l);
    Whi[i] = h; Wlo[i] = l;
}

// ---------------------------------- fused layer 1: gather-mean + 10-wide GEMM
// writes h1 (f32, GEMM self-path) and h1b (bf16 mirror for neighbor gather)
__global__ __launch_bounds__(256) void sage1_kernel(
        const float* __restrict__ x, const int* __restrict__ off,
        const int* __restrict__ csr, const float* __restrict__ W1l,
        const float* __restrict__ W1r, const float* __restrict__ b1,
        float* __restrict__ h1, unsigned short* __restrict__ h1b, int n_nodes) {
    __shared__ float sWl[320], sWr[320], sb[64];
    const int tid = threadIdx.x;
    for (int i = tid; i < 320; i += 256) { sWl[i] = W1l[i]; sWr[i] = W1r[i]; }
    if (tid < 64) sb[tid] = b1[tid];
    __syncthreads();
    int node = blockIdx.x * 4 + (tid >> 6);
    int lane = tid & 63;
    if (node >= n_nodes) return;
    int slot = lane >> 3, cg = lane & 7;
    int e0 = off[node], cnt = off[node + 1] - e0;
    float a0 = 0.f, a1 = 0.f;
    int i = slot;
    for (; i + 8 < cnt; i += 16) {
        int s0 = csr[e0 + i];
        int s1 = csr[e0 + i + 8];
        a0 += (cg < 5) ? x[(size_t)s0 * 5 + cg] : 0.f;
        a1 += (cg < 5) ? x[(size_t)s1 * 5 + cg] : 0.f;
    }
    for (; i < cnt; i += 8) {
        int s = csr[e0 + i];
        a0 += (cg < 5) ? x[(size_t)s * 5 + cg] : 0.f;
    }
    float acc = a0 + a1;
    #pragma unroll
    for (int o = 8; o < 64; o <<= 1) acc += __shfl_xor(acc, o);
    float inv = (cnt > 0) ? 1.f / (float)cnt : 0.f;
    float m = acc * inv;
    float xv = (lane < 5) ? x[(size_t)node * 5 + lane] : 0.f;
    float o = sb[lane];
    #pragma unroll
    for (int c = 0; c < 5; ++c) {
        o += sWl[lane * 5 + c] * __shfl(m, c);
        o += sWr[lane * 5 + c] * __shfl(xv, c);
    }
    o = o > 0.f ? o : o * NEG_SLOPE;
    h1[(size_t)node * 64 + lane] = o;
    h1b[(size_t)node * 64 + lane] = f2bf(o);
}

// --------------------------------------- mean aggregation from bf16 mirrors
// row = CIN bf16; LPR = CIN/8 lanes cover a row (8 bf16 = 16B per lane);
// SLOTS = 64/LPR edges per pass; unroll to 16 chains in flight (vec3 optimum).
template<int CIN>
__global__ void agg_bf16_kernel(const unsigned short* __restrict__ hb,
                                const int* __restrict__ off, const int* __restrict__ csr,
                                float* __restrict__ mean, int n_nodes) {
    constexpr int LPR = CIN / 8;
    constexpr int SLOTS = 64 / LPR;
    constexpr int UN = 16 / SLOTS;
    int node = blockIdx.x * (blockDim.x >> 6) + (threadIdx.x >> 6);
    int lane = threadIdx.x & 63;
    if (node >= n_nodes) return;
    int slot = lane / LPR, cg = lane % LPR;
    int e0 = off[node], cnt = off[node + 1] - e0;
    const unsigned short* base = hb + cg * 8;
    float acc[UN][8];
    #pragma unroll
    for (int u = 0; u < UN; ++u)
        #pragma unroll
        for (int k = 0; k < 8; ++k) acc[u][k] = 0.f;
    int i = slot;
    for (; i + (UN - 1) * SLOTS < cnt; i += UN * SLOTS) {
        int s[UN];
        #pragma unroll
        for (int u = 0; u < UN; ++u) s[u] = csr[e0 + i + u * SLOTS];
        uint4 v[UN];
        #pragma unroll
        for (int u = 0; u < UN; ++u)
            v[u] = *(const uint4*)(base + (size_t)s[u] * CIN);
        #pragma unroll
        for (int u = 0; u < UN; ++u) {
            unsigned w0 = v[u].x, w1 = v[u].y, w2 = v[u].z, w3 = v[u].w;
            acc[u][0] += __uint_as_float(w0 << 16);
            acc[u][1] += __uint_as_float(w0 & 0xFFFF0000u);
            acc[u][2] += __uint_as_float(w1 << 16);
            acc[u][3] += __uint_as_float(w1 & 0xFFFF0000u);
            acc[u][4] += __uint_as_float(w2 << 16);
            acc[u][5] += __uint_as_float(w2 & 0xFFFF0000u);
            acc[u][6] += __uint_as_float(w3 << 16);
            acc[u][7] += __uint_as_float(w3 & 0xFFFF0000u);
        }
    }
    for (; i < cnt; i += SLOTS) {
        uint4 v = *(const uint4*)(base + (size_t)csr[e0 + i] * CIN);
        unsigned w0 = v.x, w1 = v.y, w2 = v.z, w3 = v.w;
        acc[0][0] += __uint_as_float(w0 << 16);
        acc[0][1] += __uint_as_float(w0 & 0xFFFF0000u);
        acc[0][2] += __uint_as_float(w1 << 16);
        acc[0][3] += __uint_as_float(w1 & 0xFFFF0000u);
        acc[0][4] += __uint_as_float(w2 << 16);
        acc[0][5] += __uint_as_float(w2 & 0xFFFF0000u);
        acc[0][6] += __uint_as_float(w3 << 16);
        acc[0][7] += __uint_as_float(w3 & 0xFFFF0000u);
    }
    float r[8];
    #pragma unroll
    for (int k = 0; k < 8; ++k) {
        float s = acc[0][k];
        #pragma unroll
        for (int u = 1; u < UN; ++u) s += acc[u][k];
        r[k] = s;
    }
    #pragma unroll
    for (int o = LPR; o < 64; o <<= 1)
        #pragma unroll
        for (int k = 0; k < 8; ++k) r[k] += __shfl_xor(r[k], o);
    if (slot == 0) {
        float inv = (cnt > 0) ? 1.f / (float)cnt : 0.f;
        float4 lo = {r[0] * inv, r[1] * inv, r[2] * inv, r[3] * inv};
        float4 hi = {r[4] * inv, r[5] * inv, r[6] * inv, r[7] * inv};
        float* mp = mean + (size_t)node * CIN + cg * 8;
        *(float4*)mp = lo;
        *(float4*)(mp + 4) = hi;
    }
}

// ------------------------------------------------------------ f32 cat-GEMM (small)
#define BM 128
#define BN 64
#define BK 16

template<bool RELU>
__global__ __launch_bounds__(256) void gemm_cat_kernel(
        const float* __restrict__ AL, const float* __restrict__ AR,
        const float* __restrict__ W, const float* __restrict__ bias,
        float* __restrict__ C, int M, int N, int K, int CIN) {
    __shared__ float As[BK][BM + 4];
    __shared__ float Bs[BK][BN + 4];
    const int row0 = blockIdx.x * BM;
    const int col0 = blockIdx.y * BN;
    const int tid = threadIdx.x;
    const int ttm = tid & 15, ttn = tid >> 4;

    float acc[8][4];
    #pragma unroll
    for (int i = 0; i < 8; ++i)
        #pragma unroll
        for (int j = 0; j < 4; ++j) acc[i][j] = 0.f;

    for (int k0 = 0; k0 < K; k0 += BK) {
        for (int i = tid; i < BM * BK; i += 256) {
            int m = i >> 4, k = i & 15;
            int r = row0 + m, kk = k0 + k;
            float v = 0.f;
            if (r < M && kk < K)
                v = (kk < CIN) ? AL[(size_t)r * CIN + kk]
                               : AR[(size_t)r * CIN + (kk - CIN)];
            As[k][m] = v;
        }
        for (int i = tid; i < BN * BK; i += 256) {
            int n = i >> 4, k = i & 15;
            int c = col0 + n, kk = k0 + k;
            Bs[k][n] = (c < N && kk < K) ? W[(size_t)c * K + kk] : 0.f;
        }
        __syncthreads();
        #pragma unroll
        for (int k = 0; k < BK; ++k) {
            float4 a0 = *(const float4*)&As[k][ttm * 8];
            float4 a1 = *(const float4*)&As[k][ttm * 8 + 4];
            float4 b0 = *(const float4*)&Bs[k][ttn * 4];
            float av[8] = {a0.x, a0.y, a0.z, a0.w, a1.x, a1.y, a1.z, a1.w};
            float bv[4] = {b0.x, b0.y, b0.z, b0.w};
            #pragma unroll
            for (int i = 0; i < 8; ++i)
                #pragma unroll
                for (int j = 0; j < 4; ++j)
                    acc[i][j] += av[i] * bv[j];
        }
        __syncthreads();
    }

    float bv[4];
    #pragma unroll
    for (int j = 0; j < 4; ++j) bv[j] = bias[col0 + ttn * 4 + j];
    #pragma unroll
    for (int i = 0; i < 8; ++i) {
        int r = row0 + ttm * 8 + i;
        if (r < M) {
            float t0 = acc[i][0] + bv[0];
            float t1 = acc[i][1] + bv[1];
            float t2 = acc[i][2] + bv[2];
            float t3 = acc[i][3] + bv[3];
            if (RELU) {
                t0 = t0 > 0.f ? t0 : t0 * NEG_SLOPE;
                t1 = t1 > 0.f ? t1 : t1 * NEG_SLOPE;
                t2 = t2 > 0.f ? t2 : t2 * NEG_SLOPE;
                t3 = t3 > 0.f ? t3 : t3 * NEG_SLOPE;
            }
            float4 v; v.x = t0; v.y = t1; v.z = t2; v.w = t3;
            *(float4*)&C[(size_t)r * N + col0 + ttn * 4] = v;
        }
    }
}

// ------------------------------------- split-bf16 MFMA cat-GEMM (N=128/block)
// optional Cb16: bf16 mirror of C for downstream neighbor gathers
__global__ __launch_bounds__(256) void gemm_cat_mfma_kernel(
        const float* __restrict__ AL, const float* __restrict__ AR,
        const short* __restrict__ Whi, const short* __restrict__ Wlo,
        const float* __restrict__ bias, float* __restrict__ C,
        unsigned short* __restrict__ Cb16,
        int M, int N, int K, int CIN) {
    __shared__ short AsH[128][40], AsL[128][40];
    __shared__ short BsH[128][40], BsL[128][40];
    const int row0 = blockIdx.x * 128;
    const int n0 = blockIdx.y * 128;
    const int tid = threadIdx.x;
    const int w = tid >> 6;
    const int lane31 = tid & 31, lhalf = (tid & 63) >> 5;

    f32x16 acc[4];
    #pragma unroll
    for (int ci = 0; ci < 4; ++ci)
        #pragma unroll
        for (int r = 0; r < 16; ++r) acc[ci][r] = 0.f;

    for (int k0 = 0; k0 < K; k0 += 32) {
        const float* Asrc = (k0 < CIN) ? AL : AR;
        const int kb = (k0 < CIN) ? k0 : k0 - CIN;
        {
            int row = tid >> 1, kq = (tid & 1) * 16;
            int r = row0 + row;
            float vv[16];
            #pragma unroll
            for (int i = 0; i < 16; ++i) vv[i] = 0.f;
            if (r < M) {
                const float* p = &Asrc[(size_t)r * CIN + kb + kq];
                #pragma unroll
                for (int q = 0; q < 4; ++q) {
                    float4 v = ((const float4*)p)[q];
                    vv[q * 4 + 0] = v.x; vv[q * 4 + 1] = v.y;
                    vv[q * 4 + 2] = v.z; vv[q * 4 + 3] = v.w;
                }
            }
            #pragma unroll
            for (int half = 0; half < 2; ++half) {
                bh8 h8, l8;
                #pragma unroll
                for (int i = 0; i < 8; ++i) {
                    short a, b;
                    splitf(vv[half * 8 + i], a, b);
                    h8[i] = a; l8[i] = b;
                }
                *(bh8*)&AsH[row][kq + half * 8] = h8;
                *(bh8*)&AsL[row][kq + half * 8] = l8;
            }
        }
        {
            int n = tid & 127, half = tid >> 7;
            const short* src = half ? Wlo : Whi;
            const uint4* p = (const uint4*)&src[(size_t)(n0 + n) * K + k0];
            if (half) {
                #pragma unroll
                for (int q = 0; q < 4; ++q) *(uint4*)&BsL[n][q * 8] = p[q];
            } else {
                #pragma unroll
                for (int q = 0; q < 4; ++q) *(uint4*)&BsH[n][q * 8] = p[q];
            }
        }
        __syncthreads();
        #pragma unroll
        for (int ks = 0; ks < 2; ++ks) {
            int kofs = ks * 16 + lhalf * 8;
            bh8 aH = *(bh8*)&AsH[w * 32 + lane31][kofs];
            bh8 aL = *(bh8*)&AsL[w * 32 + lane31][kofs];
            #pragma unroll
            for (int ci = 0; ci < 4; ++ci) {
                bh8 bH = *(bh8*)&BsH[ci * 32 + lane31][kofs];
                bh8 bL = *(bh8*)&BsL[ci * 32 + lane31][kofs];
                acc[ci] = __builtin_amdgcn_mfma_f32_32x32x16_bf16(aH, bH, acc[ci], 0, 0, 0);
                acc[ci] = __builtin_amdgcn_mfma_f32_32x32x16_bf16(aH, bL, acc[ci], 0, 0, 0);
                acc[ci] = __builtin_amdgcn_mfma_f32_32x32x16_bf16(aL, bH, acc[ci], 0, 0, 0);
            }
        }
        __syncthreads();
    }

    #pragma unroll
    for (int ci = 0; ci < 4; ++ci) {
        int col = n0 + ci * 32 + lane31;
        float b = bias[col];
        #pragma unroll
        for (int r = 0; r < 16; ++r) {
            int row = row0 + w * 32 + (r & 3) + 8 * (r >> 2) + 4 * lhalf;
            if (row < M) {
                float v = acc[ci][r] + b;
                v = v > 0.f ? v : v * NEG_SLOPE;
                C[(size_t)row * N + col] = v;
                if (Cb16) Cb16[(size_t)row * N + col] = f2bf(v);
            }
        }
    }
}

// ------------- split-bf16 MFMA fused layer-3 GEMM + pool, 2 graphs per block
__global__ __launch_bounds__(512) void gemm_pool_mfma2_kernel(
        const float* __restrict__ AL, const float* __restrict__ AR,
        const short* __restrict__ Whi, const short* __restrict__ Wlo,
        const float* __restrict__ bias, float* __restrict__ gout,
        int npg, int CIN, int NCH) {
    __shared__ short AsH[128][40], AsL[128][40];
    __shared__ short BsH[256][40], BsL[256][40];
    __shared__ float redS[4][258], redM[4][258];
    const int g2 = blockIdx.x * 2;
    const int K = 2 * CIN;
    const int tid = threadIdx.x;
    const int w = tid >> 6;
    const int lane31 = tid & 31, lhalf = (tid & 63) >> 5;
    const int rt = w & 3, cb = (w >> 2) * 4;

    f32x16 acc[4];
    #pragma unroll
    for (int ci = 0; ci < 4; ++ci)
        #pragma unroll
        for (int r = 0; r < 16; ++r) acc[ci][r] = 0.f;

    for (int k0 = 0; k0 < K; k0 += 32) {
        const float* Asrc = (k0 < CIN) ? AL : AR;
        const int kb = (k0 < CIN) ? k0 : k0 - CIN;
        {
            int row = tid >> 2, kq = (tid & 3) * 8;
            int grow = row >> 6, r = row & 63;
            float vv[8];
            #pragma unroll
            for (int i = 0; i < 8; ++i) vv[i] = 0.f;
            if (r < npg) {
                const float* p = &Asrc[((size_t)(g2 + grow) * npg + r) * CIN + kb + kq];
                #pragma unroll
                for (int q = 0; q < 2; ++q) {
                    float4 v = ((const float4*)p)[q];
                    vv[q * 4 + 0] = v.x; vv[q * 4 + 1] = v.y;
                    vv[q * 4 + 2] = v.z; vv[q * 4 + 3] = v.w;
                }
            }
            bh8 h8, l8;
            #pragma unroll
            for (int i = 0; i < 8; ++i) {
                short a, b;
                splitf(vv[i], a, b);
                h8[i] = a; l8[i] = b;
            }
            *(bh8*)&AsH[row][kq] = h8;
            *(bh8*)&AsL[row][kq] = l8;
        }
        {
            int n = tid & 255, half = tid >> 8;
            const short* srcw = half ? Wlo : Whi;
            const uint4* p = (const uint4*)&srcw[(size_t)n * K + k0];
            if (half) {
                #pragma unroll
                for (int q = 0; q < 4; ++q) *(uint4*)&BsL[n][q * 8] = p[q];
            } else {
                #pragma unroll
                for (int q = 0; q < 4; ++q) *(uint4*)&BsH[n][q * 8] = p[q];
            }
        }
        __syncthreads();
        #pragma unroll
        for (int ks = 0; ks < 2; ++ks) {
            int kofs = ks * 16 + lhalf * 8;
            bh8 aH = *(bh8*)&AsH[rt * 32 + lane31][kofs];
            bh8 aL = *(bh8*)&AsL[rt * 32 + lane31][kofs];
            #pragma unroll
            for (int ci = 0; ci < 4; ++ci) {
                bh8 bH = *(bh8*)&BsH[(cb + ci) * 32 + lane31][kofs];
                bh8 bL = *(bh8*)&BsL[(cb + ci) * 32 + lane31][kofs];
                acc[ci] = __builtin_amdgcn_mfma_f32_32x32x16_bf16(aH, bH, acc[ci], 0, 0, 0);
                acc[ci] = __builtin_amdgcn_mfma_f32_32x32x16_bf16(aH, bL, acc[ci], 0, 0, 0);
                acc[ci] = __builtin_amdgcn_mfma_f32_32x32x16_bf16(aL, bH, acc[ci], 0, 0, 0);
            }
        }
        __syncthreads();
    }

    #pragma unroll
    for (int ci = 0; ci < 4; ++ci) {
        int col = (cb + ci) * 32 + lane31;
        float b = bias[col];
        float ls = 0.f, lm = -__builtin_huge_valf();
        #pragma unroll
        for (int r = 0; r < 16; ++r) {
            int crow = (r & 3) + 8 * (r >> 2) + 4 * lhalf;
            int grow = (rt & 1) * 32 + crow;
            if (grow < npg) {
                float v = acc[ci][r] + b;
                v = v > 0.f ? v : v * NEG_SLOPE;
                ls += v;
                lm = fmaxf(lm, v);
            }
        }
        ls += __shfl_xor(ls, 32);
        lm = fmaxf(lm, __shfl_xor(lm, 32));
        if (lhalf == 0) { redS[rt][col] = ls; redM[rt][col] = lm; }
    }
    __syncthreads();
    {
        int c = tid & 255, gi = tid >> 8;
        float s = redS[gi * 2][c] + redS[gi * 2 + 1][c];
        float m = fmaxf(redM[gi * 2][c], redM[gi * 2 + 1][c]);
        gout[(size_t)(g2 + gi) * (2 * NCH) + c] = s / (float)npg;
        gout[(size_t)(g2 + gi) * (2 * NCH) + NCH + c] = m;
    }
}

// ------------------------------------------------------- final 64->1 layer
__global__ void final_kernel(const float* __restrict__ c2, const float* __restrict__ Wc3,
                             const float* __restrict__ bc3, float* __restrict__ out, int G) {
    int g = blockIdx.x * (blockDim.x >> 6) + (threadIdx.x >> 6);
    int lane = threadIdx.x & 63;
    if (g >= G) return;
    float v = c2[(size_t)g * 64 + lane] * Wc3[lane];
    #pragma unroll
    for (int o = 32; o > 0; o >>= 1) v += __shfl_down(v, o);
    if (lane == 0) out[g] = v + bc3[0];
}

// ---------------------------------------------------------------- launcher
extern "C" void kernel_launch(void* const* d_in, const int* in_sizes, int n_in,
                              void* d_out, int out_size, void* d_ws, size_t ws_size,
                              hipStream_t stream) {
    const float* x   = (const float*)d_in[0];
    const int* ei    = (const int*)d_in[1];
    const float* W1l = (const float*)d_in[4];
    const float* b1  = (const float*)d_in[5];
    const float* W1r = (const float*)d_in[6];
    const float* W2l = (const float*)d_in[7];
    const float* b2  = (const float*)d_in[8];
    const float* W2r = (const float*)d_in[9];
    const float* W3l = (const float*)d_in[10];
    const float* b3  = (const float*)d_in[11];
    const float* W3r = (const float*)d_in[12];
    const float* Wc1 = (const float*)d_in[13];
    const float* bc1 = (const float*)d_in[14];
    const float* Wc2 = (const float*)d_in[15];
    const float* bc2 = (const float*)d_in[16];
    const float* Wc3 = (const float*)d_in[17];
    const float* bc3 = (const float*)d_in[18];
    float* out = (float*)d_out;

    const int nodes = in_sizes[0] / 5;      // 100000  (< 2^17 for packed pairs)
    const int ne    = in_sizes[1] / 2;      // 1600000
    const int G     = out_size;             // 2000 (even)
    const int npg   = nodes / G;            // 50
    const int nb    = (nodes + 511) >> 9;   // 196 buckets (<=256)

    char* ws = (char*)d_ws;
    size_t pos = 0;
    auto take = [&](size_t bytes) -> char* {
        char* p = ws + pos;
        pos += (bytes + 255) & ~(size_t)255;
        return p;
    };
    int* off     = (int*)take((size_t)(nodes + 1) * 4);
    int* csr     = (int*)take((size_t)ne * 4);
    int* bcnt    = (int*)take(256 * 4);
    int* bcur    = (int*)take(256 * 4);
    int* boff    = (int*)take(257 * 4);
    short* Whi2  = (short*)take((size_t)128 * 128 * 2);
    short* Wlo2  = (short*)take((size_t)128 * 128 * 2);
    short* Whi3  = (short*)take((size_t)256 * 256 * 2);
    short* Wlo3  = (short*)take((size_t)256 * 256 * 2);
    short* WhiC  = (short*)take((size_t)128 * 512 * 2);
    short* WloC  = (short*)take((size_t)128 * 512 * 2);
    float* gbuf  = (float*)take((size_t)G * 512 * 4);
    float* c1    = (float*)take((size_t)G * 128 * 4);
    float* c2    = (float*)take((size_t)G * 64 * 4);
    // reused region: [mean1 | h1] (51.2MB): pairs during CSR build, mean2 after L2 GEMM
    float* mean1 = (float*)take((size_t)nodes * 64 * 4);
    float* h1    = (float*)take((size_t)nodes * 64 * 4);
    float* h2    = (float*)take((size_t)nodes * 128 * 4);
    // bf16 mirror region R (25.6MB): h1b (12.8MB, dead before h2b written), then h2b
    char* R      = take((size_t)nodes * 128 * 2);
    unsigned short* h1b = (unsigned short*)R;
    unsigned short* h2b = (unsigned short*)R;
    float* mean2 = mean1;               // 51.2MB alias over dead mean1|h1
    unsigned* pairs = (unsigned*)mean1; // 6.4MB alias, dead before mean1 written

    if (pos > ws_size) {
        sentinel_kernel<<<(G + 255) / 256, 256, 0, stream>>>(out, G);
        return;
    }

    const int* src = ei;
    const int* dst = ei + ne;

    hipMemsetAsync(bcnt, 0, 512 * 4, stream);   // bcnt + bcur (adjacent)

    // ---- CSR build v3
    bucket_count_kernel<<<(ne + HIST_CH - 1) / HIST_CH, 256, 0, stream>>>(dst, bcnt, ne, nb);
    scan256_kernel<<<1, 256, 0, stream>>>(bcnt, boff, nb);
    bucket_scatter_kernel<<<(ne + SCAT_CH - 1) / SCAT_CH, 256, 0, stream>>>(
        src, dst, boff, bcur, pairs, ne, nb);
    bucket_sort_kernel<<<nb, 512, 0, stream>>>(pairs, boff, off, csr, nodes);

    pack_wsplit_kernel<<<(128 * 128 + 255) / 256, 256, 0, stream>>>(W2l, W2r, Whi2, Wlo2, 128, 128, 64);
    pack_wsplit_kernel<<<(256 * 256 + 255) / 256, 256, 0, stream>>>(W3l, W3r, Whi3, Wlo3, 256, 256, 128);
    pack_wsplit_kernel<<<(128 * 512 + 255) / 256, 256, 0, stream>>>(Wc1, Wc1, WhiC, WloC, 128, 512, 512);

    // ---- layer 1 fused: h1 = lrelu(W1l·mean(x) + W1r·x + b1), + bf16 mirror
    sage1_kernel<<<(nodes + 3) / 4, 256, 0, stream>>>(x, off, csr, W1l, W1r, b1, h1, h1b, nodes);

    // ---- layer 2: [mean(h1)|h1] (K=128) -> 128  (split-bf16 MFMA, + h2 bf16 mirror)
    agg_bf16_kernel<64><<<(nodes + 3) / 4, 256, 0, stream>>>(h1b, off, csr, mean1, nodes);
    {
        dim3 g((nodes + 127) / 128, 1);
        gemm_cat_mfma_kernel<<<g, 256, 0, stream>>>(mean1, h1, Whi2, Wlo2, b2, h2, h2b,
                                                    nodes, 128, 128, 64);
    }
    // ---- layer 3: [mean(h2)|h2] (K=256) -> 256, fused pool (2 graphs/block)
    agg_bf16_kernel<128><<<(nodes + 3) / 4, 256, 0, stream>>>(h2b, off, csr, mean2, nodes);
    gemm_pool_mfma2_kernel<<<G / 2, 512, 0, stream>>>(mean2, h2, Whi3, Wlo3, b3, gbuf,
                                                      npg, 128, 256);
    // ---- classifier: 512 -> 128 (MFMA) -> 64 (f32) -> 1
    {
        dim3 g((G + 127) / 128, 1);
        gemm_cat_mfma_kernel<<<g, 256, 0, stream>>>(gbuf, gbuf, WhiC, WloC, bc1, c1, nullptr,
                                                    G, 128, 512, 512);
    }
    {
        dim3 g((G + BM - 1) / BM, 64 / BN);
        gemm_cat_kernel<true><<<g, 256, 0, stream>>>(c1, nullptr, Wc2, bc2, c2, G, 64, 128, 128);
    }
    final_kernel<<<(G + 3) / 4, 256, 0, stream>>>(c2, Wc3, bc3, out, G);
}